// Round 1
// baseline (421.693 us; speedup 1.0000x reference)
//
#include <hip/hip_runtime.h>
#include <hip/hip_bf16.h>

// MetaLA fused pipeline, round 1.
// Stages:
//  K0 prep_w      : transpose+convert Wq/Wk/Wv -> Wt[3][512][1024] bf16, Wo -> Wot[1024][512] bf16
//  K1 gemm128<f32A,bf16out> : q,k,v = x@W + b   (z=0,1,2), bf16 outputs
//  K2 attn_kernel : attn[t,h] = softmax_h(q_t.k_t / 8)
//  K3 scan_phase1 : per-chunk local scan end states
//  K4 scan_phase2 : cross-chunk carry scan (decay^L)
//  K5 scan_phase3 : recompute states with carry, fuse out_pre = q*state + sigmoid(q*aug) -> bf16
//  K6 gemm128<bf16A,f32out> : out = out_pre @ Wo + bo -> d_out fp32
//  K7 ln_kernel   : in-place LayerNorm on d_out

#define HIDDEN 1024
#define HEADS 8
#define HDIM 64
#define INNER 512
#define BATCH 4
#define SEQ 8192
#define ROWS (BATCH*SEQ)
#define NCHUNK 128
#define CHLEN 64

typedef unsigned short u16;
typedef unsigned int u32;
typedef __attribute__((ext_vector_type(8))) short bf16x8;
typedef __attribute__((ext_vector_type(4))) float f32x4;

__device__ __forceinline__ float b2f(u16 u) { return __uint_as_float(((u32)u) << 16); }
__device__ __forceinline__ u16 f2b(float f) {
  u32 u = __float_as_uint(f);
  u32 r = u + 0x7fffu + ((u >> 16) & 1u);  // RNE
  return (u16)(r >> 16);
}
__device__ __forceinline__ u32 pack2(float a, float b) {
  return (u32)f2b(a) | ((u32)f2b(b) << 16);
}

// ---------------- K0: weight transpose/convert ----------------
__global__ __launch_bounds__(256) void prep_w(
    const float* __restrict__ Wq, const float* __restrict__ Wk,
    const float* __restrict__ Wv, const float* __restrict__ Wo,
    u16* __restrict__ Wt, u16* __restrict__ Wot) {
  const int WELEM = HIDDEN * INNER;  // 524288
  int idx = blockIdx.x * 256 + threadIdx.x;
  if (idx < 3 * WELEM) {
    int z = idx / WELEM;
    int rem = idx - z * WELEM;          // n*1024 + k
    int n = rem >> 10;
    int k = rem & 1023;
    const float* W = (z == 0) ? Wq : (z == 1) ? Wk : Wv;
    Wt[idx] = f2b(W[k * INNER + n]);
  } else {
    int rem = idx - 3 * WELEM;          // n*512 + k
    int n = rem >> 9;
    int k = rem & 511;
    Wot[rem] = f2b(Wo[k * HIDDEN + n]);
  }
}

// ---------------- K1/K6: 128x128 tiled MFMA GEMM ----------------
// A: [M][K] (fp32 or bf16), Bt: [N][K] bf16 (z-strided), out = A@Bt^T + bias
template <bool A_BF16, bool OUT_F32>
__global__ __launch_bounds__(256) void gemm128(
    const void* __restrict__ Aany, const u16* __restrict__ BtBase,
    const float* __restrict__ bias0, const float* __restrict__ bias1,
    const float* __restrict__ bias2,
    void* __restrict__ out0, void* __restrict__ out1, void* __restrict__ out2,
    int K) {
  __shared__ u16 As[128 * 32];
  __shared__ u16 Bs[128 * 32];

  const int N = gridDim.x * 128;
  const int z = blockIdx.z;
  const u16* Bt = BtBase + (size_t)z * N * K;
  const float* bias = (z == 0) ? bias0 : (z == 1) ? bias1 : bias2;
  void* Out = (z == 0) ? out0 : (z == 1) ? out1 : out2;

  const int tid = threadIdx.x;
  const int m0 = blockIdx.y * 128;
  const int n0 = blockIdx.x * 128;
  const int lane = tid & 63;
  const int wid = tid >> 6;
  const int wm = wid >> 1, wn = wid & 1;
  const int r16 = lane & 15, kq = lane >> 4;
  const int r = tid >> 1;     // staging row 0..127
  const int half = tid & 1;   // staging k-half

  f32x4 acc[4][4] = {};

  for (int k0 = 0; k0 < K; k0 += 32) {
    __syncthreads();
    // stage A tile (128x32) as bf16
    if (A_BF16) {
      const u16* Ab = (const u16*)Aany;
      const int4* src = (const int4*)(Ab + (size_t)(m0 + r) * K + k0 + half * 16);
      int4 v0 = src[0];
      int4 v1 = src[1];
      *(int4*)&As[r * 32 + half * 16] = v0;
      *(int4*)&As[r * 32 + half * 16 + 8] = v1;
    } else {
      const float* Af = (const float*)Aany;
      const float4* src = (const float4*)(Af + (size_t)(m0 + r) * K + k0 + half * 16);
      float4 f0 = src[0], f1 = src[1], f2 = src[2], f3 = src[3];
      uint4 w0 = {pack2(f0.x, f0.y), pack2(f0.z, f0.w), pack2(f1.x, f1.y), pack2(f1.z, f1.w)};
      uint4 w1 = {pack2(f2.x, f2.y), pack2(f2.z, f2.w), pack2(f3.x, f3.y), pack2(f3.z, f3.w)};
      *(uint4*)&As[r * 32 + half * 16] = w0;
      *(uint4*)&As[r * 32 + half * 16 + 8] = w1;
    }
    // stage B tile (128x32)
    {
      const int4* src = (const int4*)(Bt + (size_t)(n0 + r) * K + k0 + half * 16);
      int4 v0 = src[0];
      int4 v1 = src[1];
      *(int4*)&Bs[r * 32 + half * 16] = v0;
      *(int4*)&Bs[r * 32 + half * 16 + 8] = v1;
    }
    __syncthreads();

    bf16x8 a[4], b[4];
#pragma unroll
    for (int i = 0; i < 4; i++)
      a[i] = *(const bf16x8*)&As[(wm * 64 + i * 16 + r16) * 32 + kq * 8];
#pragma unroll
    for (int j = 0; j < 4; j++)
      b[j] = *(const bf16x8*)&Bs[(wn * 64 + j * 16 + r16) * 32 + kq * 8];
#pragma unroll
    for (int i = 0; i < 4; i++)
#pragma unroll
      for (int j = 0; j < 4; j++)
        acc[i][j] = __builtin_amdgcn_mfma_f32_16x16x32_bf16(a[i], b[j], acc[i][j], 0, 0, 0);
  }

  // epilogue: C/D layout col=lane&15, row=(lane>>4)*4+reg  [m89/m91 verified]
#pragma unroll
  for (int j = 0; j < 4; j++) {
    int col = n0 + wn * 64 + j * 16 + r16;
    float bv = bias[col];
#pragma unroll
    for (int i = 0; i < 4; i++) {
#pragma unroll
      for (int q = 0; q < 4; q++) {
        int row = m0 + wm * 64 + i * 16 + kq * 4 + q;
        float v = acc[i][j][q] + bv;
        if (OUT_F32)
          ((float*)Out)[(size_t)row * N + col] = v;
        else
          ((u16*)Out)[(size_t)row * N + col] = f2b(v);
      }
    }
  }
}

// ---------------- K2: per-row softmax over heads ----------------
__global__ __launch_bounds__(256) void attn_kernel(
    const u16* __restrict__ qb, const u16* __restrict__ kb,
    float* __restrict__ attn) {
  int lane = threadIdx.x & 63;
  int wid = threadIdx.x >> 6;
  size_t t = (size_t)blockIdx.x * 4 + wid;
  int4 qv = *(const int4*)(qb + t * INNER + lane * 8);
  int4 kv = *(const int4*)(kb + t * INNER + lane * 8);
  const u16* qu = (const u16*)&qv;
  const u16* ku = (const u16*)&kv;
  float s = 0.f;
#pragma unroll
  for (int j = 0; j < 8; j++) s += b2f(qu[j]) * b2f(ku[j]);
  // reduce over the 8 lanes of this head
  s += __shfl_xor(s, 1);
  s += __shfl_xor(s, 2);
  s += __shfl_xor(s, 4);
  s *= 0.125f;  // HDIM^-0.5
  // softmax across 8 heads (lane groups)
  float mx = s;
  mx = fmaxf(mx, __shfl_xor(mx, 8));
  mx = fmaxf(mx, __shfl_xor(mx, 16));
  mx = fmaxf(mx, __shfl_xor(mx, 32));
  float e = __expf(s - mx);
  float sm = e;
  sm += __shfl_xor(sm, 8);
  sm += __shfl_xor(sm, 16);
  sm += __shfl_xor(sm, 32);
  float a = e / sm;
  if ((lane & 7) == 0) attn[t * HEADS + (lane >> 3)] = a;
}

// ---------------- K3: per-chunk local scan (end states) ----------------
__global__ __launch_bounds__(512) void scan_phase1(
    const u16* __restrict__ vb, const float* __restrict__ attn,
    const float* __restrict__ alpha, float* __restrict__ ends) {
  int hd = threadIdx.x;
  int h = hd >> 6;
  int c = blockIdx.x, b = blockIdx.y;
  float decay = 1.f / (1.f + __expf(-alpha[hd]));
  float om = 1.f - decay;
  size_t base = (size_t)b * SEQ + (size_t)c * CHLEN;
  float st = 0.f;
#pragma unroll 8
  for (int i = 0; i < CHLEN; i++) {
    size_t t = base + i;
    float a = attn[t * HEADS + h];
    float v = b2f(vb[t * INNER + hd]);
    st = decay * st + om * a * v;
  }
  ends[((size_t)b * NCHUNK + c) * INNER + hd] = st;
}

// ---------------- K4: cross-chunk carry scan ----------------
__global__ __launch_bounds__(512) void scan_phase2(
    const float* __restrict__ ends, const float* __restrict__ alpha,
    float* __restrict__ carries) {
  int hd = threadIdx.x;
  int b = blockIdx.x;
  float decay = 1.f / (1.f + __expf(-alpha[hd]));
  float dL = __powf(decay, (float)CHLEN);
  float carry = 0.f;
  for (int c = 0; c < NCHUNK; c++) {
    size_t idx = ((size_t)b * NCHUNK + c) * INNER + hd;
    carries[idx] = carry;
    carry = dL * carry + ends[idx];
  }
}

// ---------------- K5: recompute with carry, fuse out_pre ----------------
__global__ __launch_bounds__(512) void scan_phase3(
    const u16* __restrict__ qb, const u16* __restrict__ vb,
    const float* __restrict__ attn, const float* __restrict__ alpha,
    const float* __restrict__ augp, const float* __restrict__ carries,
    u16* __restrict__ outpre) {
  int hd = threadIdx.x;
  int h = hd >> 6;
  int c = blockIdx.x, b = blockIdx.y;
  float decay = 1.f / (1.f + __expf(-alpha[hd]));
  float om = 1.f - decay;
  float ap = augp[hd];
  float st = carries[((size_t)b * NCHUNK + c) * INNER + hd];
  size_t base = (size_t)b * SEQ + (size_t)c * CHLEN;
#pragma unroll 4
  for (int i = 0; i < CHLEN; i++) {
    size_t t = base + i;
    float a = attn[t * HEADS + h];
    float v = b2f(vb[t * INNER + hd]);
    st = decay * st + om * a * v;
    float q = b2f(qb[t * INNER + hd]);
    float aug = 1.f / (1.f + __expf(-q * ap));
    outpre[t * INNER + hd] = f2b(q * st + aug);
  }
}

// ---------------- K7: in-place LayerNorm ----------------
__global__ __launch_bounds__(256) void ln_kernel(
    float* __restrict__ out, const float* __restrict__ lns,
    const float* __restrict__ lnb) {
  size_t row = blockIdx.x;
  int tid = threadIdx.x;
  float4 v = *(float4*)(out + row * HIDDEN + tid * 4);
  float s = v.x + v.y + v.z + v.w;
  float ss = v.x * v.x + v.y * v.y + v.z * v.z + v.w * v.w;
#pragma unroll
  for (int m = 1; m < 64; m <<= 1) {
    s += __shfl_xor(s, m);
    ss += __shfl_xor(ss, m);
  }
  __shared__ float sb[4], ssb[4];
  int lane = tid & 63, wid = tid >> 6;
  if (lane == 0) {
    sb[wid] = s;
    ssb[wid] = ss;
  }
  __syncthreads();
  s = sb[0] + sb[1] + sb[2] + sb[3];
  ss = ssb[0] + ssb[1] + ssb[2] + ssb[3];
  float mean = s * (1.f / HIDDEN);
  float var = ss * (1.f / HIDDEN) - mean * mean;
  float rstd = rsqrtf(var + 1e-6f);
  float4 sc = *(const float4*)(lns + tid * 4);
  float4 bi = *(const float4*)(lnb + tid * 4);
  v.x = (v.x - mean) * rstd * sc.x + bi.x;
  v.y = (v.y - mean) * rstd * sc.y + bi.y;
  v.z = (v.z - mean) * rstd * sc.z + bi.z;
  v.w = (v.w - mean) * rstd * sc.w + bi.w;
  *(float4*)(out + row * HIDDEN + tid * 4) = v;
}

extern "C" void kernel_launch(void* const* d_in, const int* in_sizes, int n_in,
                              void* d_out, int out_size, void* d_ws, size_t ws_size,
                              hipStream_t stream) {
  const float* x = (const float*)d_in[0];
  const float* Wq = (const float*)d_in[1];
  const float* bq = (const float*)d_in[2];
  const float* Wk = (const float*)d_in[3];
  const float* bk = (const float*)d_in[4];
  const float* Wv = (const float*)d_in[5];
  const float* bv = (const float*)d_in[6];
  const float* Wo = (const float*)d_in[7];
  const float* bo = (const float*)d_in[8];
  const float* alpha = (const float*)d_in[9];
  const float* augp = (const float*)d_in[10];
  const float* lns = (const float*)d_in[11];
  const float* lnb = (const float*)d_in[12];

  char* ws = (char*)d_ws;
  u16* qb = (u16*)(ws + 0);            // 33.5 MB
  u16* kb = (u16*)(ws + 33554432);     // 33.5 MB (reused as out_pre)
  u16* vb = (u16*)(ws + 67108864);     // 33.5 MB
  u16* Wt = (u16*)(ws + 100663296);    // 3 MB
  u16* Wot = (u16*)(ws + 103809024);   // 1 MB
  float* attn = (float*)(ws + 104857600);  // 1 MB
  float* ends = (float*)(ws + 105906176); // 1 MB
  float* car = (float*)(ws + 106954752);  // 1 MB
  u16* outpre = kb;  // k dead after attn_kernel

  prep_w<<<8192, 256, 0, stream>>>(Wq, Wk, Wv, Wo, Wt, Wot);

  gemm128<false, false><<<dim3(4, 256, 3), 256, 0, stream>>>(
      x, Wt, bq, bk, bv, qb, kb, vb, HIDDEN);

  attn_kernel<<<ROWS / 4, 256, 0, stream>>>(qb, kb, attn);

  scan_phase1<<<dim3(NCHUNK, BATCH), 512, 0, stream>>>(vb, attn, alpha, ends);
  scan_phase2<<<BATCH, 512, 0, stream>>>(ends, alpha, car);
  scan_phase3<<<dim3(NCHUNK, BATCH), 512, 0, stream>>>(qb, vb, attn, alpha, augp, car, outpre);

  gemm128<true, true><<<dim3(8, 256, 1), 256, 0, stream>>>(
      outpre, Wot, bo, bo, bo, d_out, d_out, d_out, INNER);

  ln_kernel<<<ROWS, 256, 0, stream>>>((float*)d_out, lns, lnb);
}

// Round 2
// 384.496 us; speedup vs baseline: 1.0967x; 1.0967x over previous
//
#include <hip/hip_runtime.h>
#include <hip/hip_bf16.h>

// MetaLA fused pipeline, round 2.
//  prep_x  : x fp32 -> xb bf16 (67 MB)
//  prep_w  : Wq/Wk/Wv -> Wt[1536][1024] bf16 (N-major), Wo -> Wot[1024][512], bias concat
//  gemm_glds<SPLIT3>: fused QKV gemm, m97 structure (global_load_lds 16B, [128][32] LDS,
//                     ds_read_b128 frags, XCD-chunked swizzle)
//  attn_kernel, scan_phase1/2/3 (chunked linear recurrence), gemm_glds (out proj), ln_kernel
// Fallback (small ws): round-1 fp32-staging QKV gemm.

#define HIDDEN 1024
#define HEADS 8
#define HDIM 64
#define INNER 512
#define BATCH 4
#define SEQ 8192
#define ROWS (BATCH*SEQ)
#define NCHUNK 128
#define CHLEN 64

typedef unsigned short u16;
typedef unsigned int u32;
typedef __attribute__((ext_vector_type(8))) short bf16x8;
typedef __attribute__((ext_vector_type(4))) float f32x4;

__device__ __forceinline__ float b2f(u16 u) { return __uint_as_float(((u32)u) << 16); }
__device__ __forceinline__ u16 f2b(float f) {
  u32 u = __float_as_uint(f);
  u32 r = u + 0x7fffu + ((u >> 16) & 1u);  // RNE
  return (u16)(r >> 16);
}
__device__ __forceinline__ u32 pack2(float a, float b) {
  return (u32)f2b(a) | ((u32)f2b(b) << 16);
}

#define GLOAD_LDS16(gp, lp)                                                  \
  __builtin_amdgcn_global_load_lds(                                          \
      (const __attribute__((address_space(1))) u32*)(gp),                    \
      (__attribute__((address_space(3))) u32*)(lp), 16, 0, 0)

// ---------------- prep_x: fp32 -> bf16 ----------------
__global__ __launch_bounds__(256) void prep_x(const float* __restrict__ x,
                                              u16* __restrict__ xb) {
  size_t i = ((size_t)blockIdx.x * 256 + threadIdx.x) * 8;
  float4 a = *(const float4*)(x + i);
  float4 b = *(const float4*)(x + i + 4);
  uint4 w = {pack2(a.x, a.y), pack2(a.z, a.w), pack2(b.x, b.y), pack2(b.z, b.w)};
  *(uint4*)(xb + i) = w;
}

// ---------------- prep_w: weight transpose/convert + bias concat ----------------
__global__ __launch_bounds__(256) void prep_w(
    const float* __restrict__ Wq, const float* __restrict__ Wk,
    const float* __restrict__ Wv, const float* __restrict__ Wo,
    const float* __restrict__ bq, const float* __restrict__ bk,
    const float* __restrict__ bv,
    u16* __restrict__ Wt, u16* __restrict__ Wot, float* __restrict__ bcat) {
  const int WELEM = HIDDEN * INNER;  // 524288
  int idx = blockIdx.x * 256 + threadIdx.x;
  if (idx < 3 * WELEM) {
    int z = idx / WELEM;
    int rem = idx - z * WELEM;  // n*1024 + k
    int n = rem >> 10;
    int k = rem & 1023;
    const float* W = (z == 0) ? Wq : (z == 1) ? Wk : Wv;
    Wt[idx] = f2b(W[k * INNER + n]);
  } else {
    int rem = idx - 3 * WELEM;  // n*512 + k
    int n = rem >> 9;
    int k = rem & 511;
    Wot[rem] = f2b(Wo[k * HIDDEN + n]);
  }
  if (idx < 3 * INNER) {
    int z = idx >> 9;
    int n = idx & 511;
    bcat[idx] = (z == 0) ? bq[n] : (z == 1) ? bk[n] : bv[n];
  }
}

// ---------------- m97-structure GEMM ----------------
// A: [M][K] bf16, Bt: [N][K] bf16, out = A@Bt^T + bias. 128x128 tile, BK=32.
// SPLIT3: N=1536, route cols to out0/1/2 (each [M][512] bf16). Else out0 (fp32, [M][N]).
template <bool OUT_F32, bool SPLIT3>
__global__ __launch_bounds__(256) void gemm_glds(
    const u16* __restrict__ A, const u16* __restrict__ Bt,
    const float* __restrict__ bias,
    void* __restrict__ out0, void* __restrict__ out1, void* __restrict__ out2,
    int K, int nTilesN) {
  __shared__ u16 As[128 * 32];
  __shared__ u16 Bs[128 * 32];

  // bijective XCD-chunked swizzle (nwg % 8 == 0)
  const int nwg = gridDim.x;
  const int chunk = nwg >> 3;
  const int bid = blockIdx.x;
  const int lin = (bid & 7) * chunk + (bid >> 3);
  const int nt = lin % nTilesN;
  const int mt = lin / nTilesN;
  const int m0 = mt * 128, n0 = nt * 128;
  const int N = nTilesN * 128;

  const int tid = threadIdx.x;
  const int lane = tid & 63;
  const int w = tid >> 6;
  const int wm = w >> 1, wn = w & 1;
  const int r16 = lane & 15, kq = lane >> 4;

  // staging: wave w issue i covers rows [32w+16i, +16), lane -> row 32w+16i+lane/4,
  // col elems (lane&3)*8. LDS dest linear: (w*2+i)*512 + lane*8 (u16).
  const int rA = w * 32 + (lane >> 2);
  const int ce = (lane & 3) * 8;
  const u16* Ag0 = A + (size_t)(m0 + rA) * K + ce;
  const u16* Ag1 = A + (size_t)(m0 + rA + 16) * K + ce;
  const u16* Bg0 = Bt + (size_t)(n0 + rA) * K + ce;
  const u16* Bg1 = Bt + (size_t)(n0 + rA + 16) * K + ce;
  u16* AsW0 = &As[(w * 2 + 0) * 512];
  u16* AsW1 = &As[(w * 2 + 1) * 512];
  u16* BsW0 = &Bs[(w * 2 + 0) * 512];
  u16* BsW1 = &Bs[(w * 2 + 1) * 512];

  f32x4 acc[4][4] = {};

  for (int k0 = 0; k0 < K; k0 += 32) {
    __syncthreads();  // all waves done reading previous tile
    GLOAD_LDS16(Ag0 + k0, AsW0);
    GLOAD_LDS16(Ag1 + k0, AsW1);
    GLOAD_LDS16(Bg0 + k0, BsW0);
    GLOAD_LDS16(Bg1 + k0, BsW1);
    __syncthreads();  // vmcnt(0) drain: tile ready

    bf16x8 a[4], b[4];
#pragma unroll
    for (int i = 0; i < 4; i++)
      a[i] = *(const bf16x8*)&As[(wm * 64 + i * 16 + r16) * 32 + kq * 8];
#pragma unroll
    for (int j = 0; j < 4; j++)
      b[j] = *(const bf16x8*)&Bs[(wn * 64 + j * 16 + r16) * 32 + kq * 8];
#pragma unroll
    for (int i = 0; i < 4; i++)
#pragma unroll
      for (int j = 0; j < 4; j++)
        acc[i][j] = __builtin_amdgcn_mfma_f32_16x16x32_bf16(a[i], b[j], acc[i][j], 0, 0, 0);
  }

  // epilogue: C/D layout col=lane&15, row=(lane>>4)*4+reg  [m89/m91]
#pragma unroll
  for (int j = 0; j < 4; j++) {
    int col = n0 + wn * 64 + j * 16 + r16;
    float bv = bias[col];
#pragma unroll
    for (int i = 0; i < 4; i++) {
#pragma unroll
      for (int q = 0; q < 4; q++) {
        int row = m0 + wm * 64 + i * 16 + kq * 4 + q;
        float v = acc[i][j][q] + bv;
        if (OUT_F32) {
          ((float*)out0)[(size_t)row * N + col] = v;
        } else if (SPLIT3) {
          int z = col >> 9;
          u16* o = (z == 0) ? (u16*)out0 : (z == 1) ? (u16*)out1 : (u16*)out2;
          o[(size_t)row * INNER + (col & 511)] = f2b(v);
        } else {
          ((u16*)out0)[(size_t)row * N + col] = f2b(v);
        }
      }
    }
  }
}

// ---------------- legacy GEMM (round-1, fp32 A staging) — ws fallback ----------------
template <bool A_BF16, bool OUT_F32>
__global__ __launch_bounds__(256) void gemm128(
    const void* __restrict__ Aany, const u16* __restrict__ BtBase,
    const float* __restrict__ bias0, const float* __restrict__ bias1,
    const float* __restrict__ bias2,
    void* __restrict__ out0, void* __restrict__ out1, void* __restrict__ out2,
    int K) {
  __shared__ u16 As[128 * 32];
  __shared__ u16 Bs[128 * 32];
  const int N = gridDim.x * 128;
  const int z = blockIdx.z;
  const u16* Bt = BtBase + (size_t)z * N * K;
  const float* bias = (z == 0) ? bias0 : (z == 1) ? bias1 : bias2;
  void* Out = (z == 0) ? out0 : (z == 1) ? out1 : out2;
  const int tid = threadIdx.x;
  const int m0 = blockIdx.y * 128;
  const int n0 = blockIdx.x * 128;
  const int lane = tid & 63;
  const int wid = tid >> 6;
  const int wm = wid >> 1, wn = wid & 1;
  const int r16 = lane & 15, kq = lane >> 4;
  const int r = tid >> 1;
  const int half = tid & 1;
  f32x4 acc[4][4] = {};
  for (int k0 = 0; k0 < K; k0 += 32) {
    __syncthreads();
    if (A_BF16) {
      const u16* Ab = (const u16*)Aany;
      const int4* src = (const int4*)(Ab + (size_t)(m0 + r) * K + k0 + half * 16);
      int4 v0 = src[0];
      int4 v1 = src[1];
      *(int4*)&As[r * 32 + half * 16] = v0;
      *(int4*)&As[r * 32 + half * 16 + 8] = v1;
    } else {
      const float* Af = (const float*)Aany;
      const float4* src = (const float4*)(Af + (size_t)(m0 + r) * K + k0 + half * 16);
      float4 f0 = src[0], f1 = src[1], f2 = src[2], f3 = src[3];
      uint4 w0 = {pack2(f0.x, f0.y), pack2(f0.z, f0.w), pack2(f1.x, f1.y), pack2(f1.z, f1.w)};
      uint4 w1 = {pack2(f2.x, f2.y), pack2(f2.z, f2.w), pack2(f3.x, f3.y), pack2(f3.z, f3.w)};
      *(uint4*)&As[r * 32 + half * 16] = w0;
      *(uint4*)&As[r * 32 + half * 16 + 8] = w1;
    }
    {
      const int4* src = (const int4*)(Bt + (size_t)(n0 + r) * K + k0 + half * 16);
      int4 v0 = src[0];
      int4 v1 = src[1];
      *(int4*)&Bs[r * 32 + half * 16] = v0;
      *(int4*)&Bs[r * 32 + half * 16 + 8] = v1;
    }
    __syncthreads();
    bf16x8 a[4], b[4];
#pragma unroll
    for (int i = 0; i < 4; i++)
      a[i] = *(const bf16x8*)&As[(wm * 64 + i * 16 + r16) * 32 + kq * 8];
#pragma unroll
    for (int j = 0; j < 4; j++)
      b[j] = *(const bf16x8*)&Bs[(wn * 64 + j * 16 + r16) * 32 + kq * 8];
#pragma unroll
    for (int i = 0; i < 4; i++)
#pragma unroll
      for (int j = 0; j < 4; j++)
        acc[i][j] = __builtin_amdgcn_mfma_f32_16x16x32_bf16(a[i], b[j], acc[i][j], 0, 0, 0);
  }
#pragma unroll
  for (int j = 0; j < 4; j++) {
    int col = n0 + wn * 64 + j * 16 + r16;
    float bv = bias[col];
#pragma unroll
    for (int i = 0; i < 4; i++) {
#pragma unroll
      for (int q = 0; q < 4; q++) {
        int row = m0 + wm * 64 + i * 16 + kq * 4 + q;
        float v = acc[i][j][q] + bv;
        if (OUT_F32)
          ((float*)Out)[(size_t)row * N + col] = v;
        else
          ((u16*)Out)[(size_t)row * N + col] = f2b(v);
      }
    }
  }
}

// ---------------- attn: softmax over heads of (q.k)/8 ----------------
__global__ __launch_bounds__(256) void attn_kernel(
    const u16* __restrict__ qb, const u16* __restrict__ kb,
    float* __restrict__ attn) {
  int lane = threadIdx.x & 63;
  int wid = threadIdx.x >> 6;
  size_t t = (size_t)blockIdx.x * 4 + wid;
  int4 qv = *(const int4*)(qb + t * INNER + lane * 8);
  int4 kv = *(const int4*)(kb + t * INNER + lane * 8);
  const u16* qu = (const u16*)&qv;
  const u16* ku = (const u16*)&kv;
  float s = 0.f;
#pragma unroll
  for (int j = 0; j < 8; j++) s += b2f(qu[j]) * b2f(ku[j]);
  s += __shfl_xor(s, 1);
  s += __shfl_xor(s, 2);
  s += __shfl_xor(s, 4);
  s *= 0.125f;
  float mx = s;
  mx = fmaxf(mx, __shfl_xor(mx, 8));
  mx = fmaxf(mx, __shfl_xor(mx, 16));
  mx = fmaxf(mx, __shfl_xor(mx, 32));
  float e = __expf(s - mx);
  float sm = e;
  sm += __shfl_xor(sm, 8);
  sm += __shfl_xor(sm, 16);
  sm += __shfl_xor(sm, 32);
  float a = e / sm;
  if ((lane & 7) == 0) attn[t * HEADS + (lane >> 3)] = a;
}

// ---------------- scan ----------------
__global__ __launch_bounds__(512) void scan_phase1(
    const u16* __restrict__ vb, const float* __restrict__ attn,
    const float* __restrict__ alpha, float* __restrict__ ends) {
  int hd = threadIdx.x;
  int h = hd >> 6;
  int c = blockIdx.x, b = blockIdx.y;
  float decay = 1.f / (1.f + __expf(-alpha[hd]));
  float om = 1.f - decay;
  size_t base = (size_t)b * SEQ + (size_t)c * CHLEN;
  float st = 0.f;
#pragma unroll 8
  for (int i = 0; i < CHLEN; i++) {
    size_t t = base + i;
    float a = attn[t * HEADS + h];
    float v = b2f(vb[t * INNER + hd]);
    st = decay * st + om * a * v;
  }
  ends[((size_t)b * NCHUNK + c) * INNER + hd] = st;
}

__global__ __launch_bounds__(512) void scan_phase2(
    const float* __restrict__ ends, const float* __restrict__ alpha,
    float* __restrict__ carries) {
  int hd = threadIdx.x;
  int b = blockIdx.x;
  float decay = 1.f / (1.f + __expf(-alpha[hd]));
  float dL = __powf(decay, (float)CHLEN);
  float carry = 0.f;
  for (int c = 0; c < NCHUNK; c++) {
    size_t idx = ((size_t)b * NCHUNK + c) * INNER + hd;
    carries[idx] = carry;
    carry = dL * carry + ends[idx];
  }
}

__global__ __launch_bounds__(512) void scan_phase3(
    const u16* __restrict__ qb, const u16* __restrict__ vb,
    const float* __restrict__ attn, const float* __restrict__ alpha,
    const float* __restrict__ augp, const float* __restrict__ carries,
    u16* __restrict__ outpre) {
  int hd = threadIdx.x;
  int h = hd >> 6;
  int c = blockIdx.x, b = blockIdx.y;
  float decay = 1.f / (1.f + __expf(-alpha[hd]));
  float om = 1.f - decay;
  float ap = augp[hd];
  float st = carries[((size_t)b * NCHUNK + c) * INNER + hd];
  size_t base = (size_t)b * SEQ + (size_t)c * CHLEN;
#pragma unroll 4
  for (int i = 0; i < CHLEN; i++) {
    size_t t = base + i;
    float a = attn[t * HEADS + h];
    float v = b2f(vb[t * INNER + hd]);
    st = decay * st + om * a * v;
    float q = b2f(qb[t * INNER + hd]);
    float aug = 1.f / (1.f + __expf(-q * ap));
    outpre[t * INNER + hd] = f2b(q * st + aug);
  }
}

// ---------------- LayerNorm (in place) ----------------
__global__ __launch_bounds__(256) void ln_kernel(
    float* __restrict__ out, const float* __restrict__ lns,
    const float* __restrict__ lnb) {
  size_t row = blockIdx.x;
  int tid = threadIdx.x;
  float4 v = *(float4*)(out + row * HIDDEN + tid * 4);
  float s = v.x + v.y + v.z + v.w;
  float ss = v.x * v.x + v.y * v.y + v.z * v.z + v.w * v.w;
#pragma unroll
  for (int m = 1; m < 64; m <<= 1) {
    s += __shfl_xor(s, m);
    ss += __shfl_xor(ss, m);
  }
  __shared__ float sb[4], ssb[4];
  int lane = tid & 63, wid = tid >> 6;
  if (lane == 0) {
    sb[wid] = s;
    ssb[wid] = ss;
  }
  __syncthreads();
  s = sb[0] + sb[1] + sb[2] + sb[3];
  ss = ssb[0] + ssb[1] + ssb[2] + ssb[3];
  float mean = s * (1.f / HIDDEN);
  float var = ss * (1.f / HIDDEN) - mean * mean;
  float rstd = rsqrtf(var + 1e-6f);
  float4 sc = *(const float4*)(lns + tid * 4);
  float4 bi = *(const float4*)(lnb + tid * 4);
  v.x = (v.x - mean) * rstd * sc.x + bi.x;
  v.y = (v.y - mean) * rstd * sc.y + bi.y;
  v.z = (v.z - mean) * rstd * sc.z + bi.z;
  v.w = (v.w - mean) * rstd * sc.w + bi.w;
  *(float4*)(out + row * HIDDEN + tid * 4) = v;
}

extern "C" void kernel_launch(void* const* d_in, const int* in_sizes, int n_in,
                              void* d_out, int out_size, void* d_ws, size_t ws_size,
                              hipStream_t stream) {
  const float* x = (const float*)d_in[0];
  const float* Wq = (const float*)d_in[1];
  const float* bq = (const float*)d_in[2];
  const float* Wk = (const float*)d_in[3];
  const float* bk = (const float*)d_in[4];
  const float* Wv = (const float*)d_in[5];
  const float* bv = (const float*)d_in[6];
  const float* Wo = (const float*)d_in[7];
  const float* bo = (const float*)d_in[8];
  const float* alpha = (const float*)d_in[9];
  const float* augp = (const float*)d_in[10];
  const float* lns = (const float*)d_in[11];
  const float* lnb = (const float*)d_in[12];

  char* ws = (char*)d_ws;
  const bool fast = ws_size >= 175118336ull;

  if (fast) {
    u16* xb = (u16*)(ws + 0);                 // 67.1 MB
    u16* qb = (u16*)(ws + 67108864);          // 33.5 MB
    u16* kb = (u16*)(ws + 100663296);         // 33.5 MB (reused as outpre)
    u16* vb = (u16*)(ws + 134217728);         // 33.5 MB
    u16* Wt = (u16*)(ws + 167772160);         // 3 MB, [1536][1024]
    u16* Wot = (u16*)(ws + 170917888);        // 1 MB, [1024][512]
    float* bcat = (float*)(ws + 171966464);   // 6 KB
    float* attn = (float*)(ws + 171972608);   // 1 MB
    float* ends = (float*)(ws + 173021184);   // 1 MB
    float* car = (float*)(ws + 174069760);    // 1 MB
    u16* outpre = kb;

    prep_x<<<ROWS * HIDDEN / 8 / 256, 256, 0, stream>>>(x, xb);
    prep_w<<<8192, 256, 0, stream>>>(Wq, Wk, Wv, Wo, bq, bk, bv, Wt, Wot, bcat);

    // QKV: M=32768, N=1536, K=1024 -> 256*12 = 3072 blocks
    gemm_glds<false, true><<<3072, 256, 0, stream>>>(
        xb, Wt, bcat, qb, kb, vb, HIDDEN, 12);

    attn_kernel<<<ROWS / 4, 256, 0, stream>>>(qb, kb, attn);
    scan_phase1<<<dim3(NCHUNK, BATCH), 512, 0, stream>>>(vb, attn, alpha, ends);
    scan_phase2<<<BATCH, 512, 0, stream>>>(ends, alpha, car);
    scan_phase3<<<dim3(NCHUNK, BATCH), 512, 0, stream>>>(qb, vb, attn, alpha, augp, car, outpre);

    // out: M=32768, N=1024, K=512 -> 256*8 = 2048 blocks
    gemm_glds<true, false><<<2048, 256, 0, stream>>>(
        outpre, Wot, bo, d_out, d_out, d_out, INNER, 8);

    ln_kernel<<<ROWS, 256, 0, stream>>>((float*)d_out, lns, lnb);
  } else {
    // round-1 proven layout (108 MB)
    u16* qb = (u16*)(ws + 0);
    u16* kb = (u16*)(ws + 33554432);
    u16* vb = (u16*)(ws + 67108864);
    u16* Wt = (u16*)(ws + 100663296);
    u16* Wot = (u16*)(ws + 103809024);
    float* bcat = (float*)(ws + 104845312);  // 6 KB (before attn)
    float* attn = (float*)(ws + 104857600);
    float* ends = (float*)(ws + 105906176);
    float* car = (float*)(ws + 106954752);
    u16* outpre = kb;

    prep_w<<<8192, 256, 0, stream>>>(Wq, Wk, Wv, Wo, bq, bk, bv, Wt, Wot, bcat);
    gemm128<false, false><<<dim3(4, 256, 3), 256, 0, stream>>>(
        x, Wt, bq, bk, bv, qb, kb, vb, HIDDEN);
    attn_kernel<<<ROWS / 4, 256, 0, stream>>>(qb, kb, attn);
    scan_phase1<<<dim3(NCHUNK, BATCH), 512, 0, stream>>>(vb, attn, alpha, ends);
    scan_phase2<<<BATCH, 512, 0, stream>>>(ends, alpha, car);
    scan_phase3<<<dim3(NCHUNK, BATCH), 512, 0, stream>>>(qb, vb, attn, alpha, augp, car, outpre);
    gemm_glds<true, false><<<2048, 256, 0, stream>>>(
        outpre, Wot, bo, d_out, d_out, d_out, INNER, 8);
    ln_kernel<<<ROWS, 256, 0, stream>>>((float*)d_out, lns, lnb);
  }
}

// Round 3
// 358.397 us; speedup vs baseline: 1.1766x; 1.0728x over previous
//
#include <hip/hip_runtime.h>
#include <hip/hip_bf16.h>

// MetaLA fused pipeline, round 3.
//  prep_x  : x fp32 -> xb bf16
//  prep_w  : Wq/Wk/Wv -> Wt[1536][1024] bf16 (N-major), Wo -> Wot[1024][512], bias concat
//  gemm_2ph: 128x128 MFMA GEMM, double-buffered LDS, T3-minimum 2-phase prefetch
//            (stage t+1 -> ds_read t -> MFMA -> vmcnt(0)+barrier), XCD-chunked swizzle
//  attn_kernel, scan_phase1/2/3 (chunked linear recurrence), gemm_2ph (out proj), ln_kernel

#define HIDDEN 1024
#define HEADS 8
#define HDIM 64
#define INNER 512
#define BATCH 4
#define SEQ 8192
#define ROWS (BATCH*SEQ)
#define NCHUNK 128
#define CHLEN 64

typedef unsigned short u16;
typedef unsigned int u32;
typedef __attribute__((ext_vector_type(8))) short bf16x8;
typedef __attribute__((ext_vector_type(4))) float f32x4;

__device__ __forceinline__ float b2f(u16 u) { return __uint_as_float(((u32)u) << 16); }
__device__ __forceinline__ u16 f2b(float f) {
  u32 u = __float_as_uint(f);
  u32 r = u + 0x7fffu + ((u >> 16) & 1u);  // RNE
  return (u16)(r >> 16);
}
__device__ __forceinline__ u32 pack2(float a, float b) {
  return (u32)f2b(a) | ((u32)f2b(b) << 16);
}

#define GLOAD_LDS16(gp, lp)                                                  \
  __builtin_amdgcn_global_load_lds(                                          \
      (const __attribute__((address_space(1))) u32*)(gp),                    \
      (__attribute__((address_space(3))) u32*)(lp), 16, 0, 0)

// ---------------- prep_x: fp32 -> bf16 ----------------
__global__ __launch_bounds__(256) void prep_x(const float* __restrict__ x,
                                              u16* __restrict__ xb) {
  size_t i = ((size_t)blockIdx.x * 256 + threadIdx.x) * 8;
  float4 a = *(const float4*)(x + i);
  float4 b = *(const float4*)(x + i + 4);
  uint4 w = {pack2(a.x, a.y), pack2(a.z, a.w), pack2(b.x, b.y), pack2(b.z, b.w)};
  *(uint4*)(xb + i) = w;
}

// ---------------- prep_w: weight transpose/convert + bias concat ----------------
__global__ __launch_bounds__(256) void prep_w(
    const float* __restrict__ Wq, const float* __restrict__ Wk,
    const float* __restrict__ Wv, const float* __restrict__ Wo,
    const float* __restrict__ bq, const float* __restrict__ bk,
    const float* __restrict__ bv,
    u16* __restrict__ Wt, u16* __restrict__ Wot, float* __restrict__ bcat) {
  const int WELEM = HIDDEN * INNER;  // 524288
  int idx = blockIdx.x * 256 + threadIdx.x;
  if (idx < 3 * WELEM) {
    int z = idx / WELEM;
    int rem = idx - z * WELEM;  // n*1024 + k
    int n = rem >> 10;
    int k = rem & 1023;
    const float* W = (z == 0) ? Wq : (z == 1) ? Wk : Wv;
    Wt[idx] = f2b(W[k * INNER + n]);
  } else {
    int rem = idx - 3 * WELEM;  // n*512 + k
    int n = rem >> 9;
    int k = rem & 511;
    Wot[rem] = f2b(Wo[k * HIDDEN + n]);
  }
  if (idx < 3 * INNER) {
    int z = idx >> 9;
    int n = idx & 511;
    bcat[idx] = (z == 0) ? bq[n] : (z == 1) ? bk[n] : bv[n];
  }
}

// ---------------- gemm_2ph: 128x128 tile, BK=32, double-buffered prefetch ----------------
// A: [M][K] bf16, Bt: [N][K] bf16, out = A@Bt^T + bias.
// SPLIT3: N=1536, route cols to out0/1/2 (each [M][512] bf16). Else out0 (fp32 [M][N]).
template <bool OUT_F32, bool SPLIT3>
__global__ __launch_bounds__(256) void gemm_2ph(
    const u16* __restrict__ A, const u16* __restrict__ Bt,
    const float* __restrict__ bias,
    void* __restrict__ out0, void* __restrict__ out1, void* __restrict__ out2,
    int K, int nTilesN) {
  __shared__ u16 As0[128 * 32];
  __shared__ u16 Bs0[128 * 32];
  __shared__ u16 As1[128 * 32];
  __shared__ u16 Bs1[128 * 32];

  // bijective XCD-chunked swizzle (nwg % 8 == 0); consecutive lin share an A-panel
  const int nwg = gridDim.x;
  const int chunk = nwg >> 3;
  const int bid = blockIdx.x;
  const int lin = (bid & 7) * chunk + (bid >> 3);
  const int nt = lin % nTilesN;
  const int mt = lin / nTilesN;
  const int m0 = mt * 128, n0 = nt * 128;
  const int N = nTilesN * 128;

  const int tid = threadIdx.x;
  const int lane = tid & 63;
  const int w = tid >> 6;
  const int wm = w >> 1, wn = w & 1;
  const int r16 = lane & 15, kq = lane >> 4;

  // staging: wave w issue i covers rows [32w+16i, +16); lane -> row 32w+16i+lane/4,
  // col elems (lane&3)*8. LDS dest linear: (w*2+i)*512 + lane*8 (u16).
  const int rA = w * 32 + (lane >> 2);
  const int ce = (lane & 3) * 8;
  const u16* Ag0 = A + (size_t)(m0 + rA) * K + ce;
  const u16* Ag1 = A + (size_t)(m0 + rA + 16) * K + ce;
  const u16* Bg0 = Bt + (size_t)(n0 + rA) * K + ce;
  const u16* Bg1 = Bt + (size_t)(n0 + rA + 16) * K + ce;
  const int ldsOff = (w * 2) * 512;  // + lane*8 handled by HW (lane x 16B)
  u16* A0W0 = &As0[ldsOff];
  u16* A0W1 = &As0[ldsOff + 512];
  u16* B0W0 = &Bs0[ldsOff];
  u16* B0W1 = &Bs0[ldsOff + 512];
  u16* A1W0 = &As1[ldsOff];
  u16* A1W1 = &As1[ldsOff + 512];
  u16* B1W0 = &Bs1[ldsOff];
  u16* B1W1 = &Bs1[ldsOff + 512];

  f32x4 acc[4][4] = {};

#define GEMM_STEP(AsR, BsR, AW0, AW1, BW0, BW1, kOff)                          \
  {                                                                            \
    GLOAD_LDS16(Ag0 + (kOff), AW0);                                            \
    GLOAD_LDS16(Ag1 + (kOff), AW1);                                            \
    GLOAD_LDS16(Bg0 + (kOff), BW0);                                            \
    GLOAD_LDS16(Bg1 + (kOff), BW1);                                            \
    bf16x8 a[4], b[4];                                                         \
    _Pragma("unroll") for (int i = 0; i < 4; i++)                              \
        a[i] = *(const bf16x8*)&AsR[(wm * 64 + i * 16 + r16) * 32 + kq * 8];   \
    _Pragma("unroll") for (int j = 0; j < 4; j++)                              \
        b[j] = *(const bf16x8*)&BsR[(wn * 64 + j * 16 + r16) * 32 + kq * 8];   \
    _Pragma("unroll") for (int i = 0; i < 4; i++)                              \
        _Pragma("unroll") for (int j = 0; j < 4; j++)                          \
            acc[i][j] =                                                        \
        __builtin_amdgcn_mfma_f32_16x16x32_bf16(a[i], b[j], acc[i][j], 0, 0, 0); \
    __syncthreads();                                                           \
  }

  // prologue: stage tile 0 -> buf0, drain, barrier (syncthreads emits vmcnt(0))
  GLOAD_LDS16(Ag0, A0W0);
  GLOAD_LDS16(Ag1, A0W1);
  GLOAD_LDS16(Bg0, B0W0);
  GLOAD_LDS16(Bg1, B0W1);
  __syncthreads();

  const int nIter = K >> 5;  // even (32 or 16)
  int t = 0;
  for (; t + 2 <= nIter - 1; t += 2) {
    GEMM_STEP(As0, Bs0, A1W0, A1W1, B1W0, B1W1, (size_t)(t + 1) * 32);
    GEMM_STEP(As1, Bs1, A0W0, A0W1, B0W0, B0W1, (size_t)(t + 2) * 32);
  }
  // t == nIter-2: single step reading buf0 (tile nIter-2), staging last tile -> buf1
  GEMM_STEP(As0, Bs0, A1W0, A1W1, B1W0, B1W1, (size_t)(nIter - 1) * 32);
  // epilogue compute: tile nIter-1 in buf1, no staging
  {
    bf16x8 a[4], b[4];
#pragma unroll
    for (int i = 0; i < 4; i++)
      a[i] = *(const bf16x8*)&As1[(wm * 64 + i * 16 + r16) * 32 + kq * 8];
#pragma unroll
    for (int j = 0; j < 4; j++)
      b[j] = *(const bf16x8*)&Bs1[(wn * 64 + j * 16 + r16) * 32 + kq * 8];
#pragma unroll
    for (int i = 0; i < 4; i++)
#pragma unroll
      for (int j = 0; j < 4; j++)
        acc[i][j] = __builtin_amdgcn_mfma_f32_16x16x32_bf16(a[i], b[j], acc[i][j], 0, 0, 0);
  }
#undef GEMM_STEP

  // epilogue: C/D layout col=lane&15, row=(lane>>4)*4+reg  [m89/m91]
#pragma unroll
  for (int j = 0; j < 4; j++) {
    int col = n0 + wn * 64 + j * 16 + r16;
    float bv = bias[col];
#pragma unroll
    for (int i = 0; i < 4; i++) {
#pragma unroll
      for (int q = 0; q < 4; q++) {
        int row = m0 + wm * 64 + i * 16 + kq * 4 + q;
        float v = acc[i][j][q] + bv;
        if (OUT_F32) {
          ((float*)out0)[(size_t)row * N + col] = v;
        } else if (SPLIT3) {
          int z = col >> 9;
          u16* o = (z == 0) ? (u16*)out0 : (z == 1) ? (u16*)out1 : (u16*)out2;
          o[(size_t)row * INNER + (col & 511)] = f2b(v);
        } else {
          ((u16*)out0)[(size_t)row * N + col] = f2b(v);
        }
      }
    }
  }
}

// ---------------- legacy GEMM (fp32 A staging) — small-ws fallback ----------------
template <bool A_BF16, bool OUT_F32>
__global__ __launch_bounds__(256) void gemm128(
    const void* __restrict__ Aany, const u16* __restrict__ BtBase,
    const float* __restrict__ bias0, const float* __restrict__ bias1,
    const float* __restrict__ bias2,
    void* __restrict__ out0, void* __restrict__ out1, void* __restrict__ out2,
    int K) {
  __shared__ u16 As[128 * 32];
  __shared__ u16 Bs[128 * 32];
  const int N = gridDim.x * 128;
  const int z = blockIdx.z;
  const u16* Bt = BtBase + (size_t)z * N * K;
  const float* bias = (z == 0) ? bias0 : (z == 1) ? bias1 : bias2;
  void* Out = (z == 0) ? out0 : (z == 1) ? out1 : out2;
  const int tid = threadIdx.x;
  const int m0 = blockIdx.y * 128;
  const int n0 = blockIdx.x * 128;
  const int lane = tid & 63;
  const int wid = tid >> 6;
  const int wm = wid >> 1, wn = wid & 1;
  const int r16 = lane & 15, kq = lane >> 4;
  const int r = tid >> 1;
  const int half = tid & 1;
  f32x4 acc[4][4] = {};
  for (int k0 = 0; k0 < K; k0 += 32) {
    __syncthreads();
    if (A_BF16) {
      const u16* Ab = (const u16*)Aany;
      const int4* src = (const int4*)(Ab + (size_t)(m0 + r) * K + k0 + half * 16);
      int4 v0 = src[0];
      int4 v1 = src[1];
      *(int4*)&As[r * 32 + half * 16] = v0;
      *(int4*)&As[r * 32 + half * 16 + 8] = v1;
    } else {
      const float* Af = (const float*)Aany;
      const float4* src = (const float4*)(Af + (size_t)(m0 + r) * K + k0 + half * 16);
      float4 f0 = src[0], f1 = src[1], f2 = src[2], f3 = src[3];
      uint4 w0 = {pack2(f0.x, f0.y), pack2(f0.z, f0.w), pack2(f1.x, f1.y), pack2(f1.z, f1.w)};
      uint4 w1 = {pack2(f2.x, f2.y), pack2(f2.z, f2.w), pack2(f3.x, f3.y), pack2(f3.z, f3.w)};
      *(uint4*)&As[r * 32 + half * 16] = w0;
      *(uint4*)&As[r * 32 + half * 16 + 8] = w1;
    }
    {
      const int4* src = (const int4*)(Bt + (size_t)(n0 + r) * K + k0 + half * 16);
      int4 v0 = src[0];
      int4 v1 = src[1];
      *(int4*)&Bs[r * 32 + half * 16] = v0;
      *(int4*)&Bs[r * 32 + half * 16 + 8] = v1;
    }
    __syncthreads();
    bf16x8 a[4], b[4];
#pragma unroll
    for (int i = 0; i < 4; i++)
      a[i] = *(const bf16x8*)&As[(wm * 64 + i * 16 + r16) * 32 + kq * 8];
#pragma unroll
    for (int j = 0; j < 4; j++)
      b[j] = *(const bf16x8*)&Bs[(wn * 64 + j * 16 + r16) * 32 + kq * 8];
#pragma unroll
    for (int i = 0; i < 4; i++)
#pragma unroll
      for (int j = 0; j < 4; j++)
        acc[i][j] = __builtin_amdgcn_mfma_f32_16x16x32_bf16(a[i], b[j], acc[i][j], 0, 0, 0);
  }
#pragma unroll
  for (int j = 0; j < 4; j++) {
    int col = n0 + wn * 64 + j * 16 + r16;
    float bv = bias[col];
#pragma unroll
    for (int i = 0; i < 4; i++) {
#pragma unroll
      for (int q = 0; q < 4; q++) {
        int row = m0 + wm * 64 + i * 16 + kq * 4 + q;
        float v = acc[i][j][q] + bv;
        if (OUT_F32)
          ((float*)Out)[(size_t)row * N + col] = v;
        else
          ((u16*)Out)[(size_t)row * N + col] = f2b(v);
      }
    }
  }
}

// ---------------- attn: softmax over heads of (q.k)/8 ----------------
__global__ __launch_bounds__(256) void attn_kernel(
    const u16* __restrict__ qb, const u16* __restrict__ kb,
    float* __restrict__ attn) {
  int lane = threadIdx.x & 63;
  int wid = threadIdx.x >> 6;
  size_t t = (size_t)blockIdx.x * 4 + wid;
  int4 qv = *(const int4*)(qb + t * INNER + lane * 8);
  int4 kv = *(const int4*)(kb + t * INNER + lane * 8);
  const u16* qu = (const u16*)&qv;
  const u16* ku = (const u16*)&kv;
  float s = 0.f;
#pragma unroll
  for (int j = 0; j < 8; j++) s += b2f(qu[j]) * b2f(ku[j]);
  s += __shfl_xor(s, 1);
  s += __shfl_xor(s, 2);
  s += __shfl_xor(s, 4);
  s *= 0.125f;
  float mx = s;
  mx = fmaxf(mx, __shfl_xor(mx, 8));
  mx = fmaxf(mx, __shfl_xor(mx, 16));
  mx = fmaxf(mx, __shfl_xor(mx, 32));
  float e = __expf(s - mx);
  float sm = e;
  sm += __shfl_xor(sm, 8);
  sm += __shfl_xor(sm, 16);
  sm += __shfl_xor(sm, 32);
  float a = e / sm;
  if ((lane & 7) == 0) attn[t * HEADS + (lane >> 3)] = a;
}

// ---------------- scan ----------------
__global__ __launch_bounds__(512) void scan_phase1(
    const u16* __restrict__ vb, const float* __restrict__ attn,
    const float* __restrict__ alpha, float* __restrict__ ends) {
  int hd = threadIdx.x;
  int h = hd >> 6;
  int c = blockIdx.x, b = blockIdx.y;
  float decay = 1.f / (1.f + __expf(-alpha[hd]));
  float om = 1.f - decay;
  size_t base = (size_t)b * SEQ + (size_t)c * CHLEN;
  float st = 0.f;
#pragma unroll 8
  for (int i = 0; i < CHLEN; i++) {
    size_t t = base + i;
    float a = attn[t * HEADS + h];
    float v = b2f(vb[t * INNER + hd]);
    st = decay * st + om * a * v;
  }
  ends[((size_t)b * NCHUNK + c) * INNER + hd] = st;
}

__global__ __launch_bounds__(512) void scan_phase2(
    const float* __restrict__ ends, const float* __restrict__ alpha,
    float* __restrict__ carries) {
  int hd = threadIdx.x;
  int b = blockIdx.x;
  float decay = 1.f / (1.f + __expf(-alpha[hd]));
  float dL = __powf(decay, (float)CHLEN);
  float carry = 0.f;
#pragma unroll 8
  for (int c = 0; c < NCHUNK; c++) {
    size_t idx = ((size_t)b * NCHUNK + c) * INNER + hd;
    carries[idx] = carry;
    carry = dL * carry + ends[idx];
  }
}

__global__ __launch_bounds__(512) void scan_phase3(
    const u16* __restrict__ qb, const u16* __restrict__ vb,
    const float* __restrict__ attn, const float* __restrict__ alpha,
    const float* __restrict__ augp, const float* __restrict__ carries,
    u16* __restrict__ outpre) {
  int hd = threadIdx.x;
  int h = hd >> 6;
  int c = blockIdx.x, b = blockIdx.y;
  float decay = 1.f / (1.f + __expf(-alpha[hd]));
  float om = 1.f - decay;
  float ap = augp[hd];
  float st = carries[((size_t)b * NCHUNK + c) * INNER + hd];
  size_t base = (size_t)b * SEQ + (size_t)c * CHLEN;
#pragma unroll 4
  for (int i = 0; i < CHLEN; i++) {
    size_t t = base + i;
    float a = attn[t * HEADS + h];
    float v = b2f(vb[t * INNER + hd]);
    st = decay * st + om * a * v;
    float q = b2f(qb[t * INNER + hd]);
    float aug = 1.f / (1.f + __expf(-q * ap));
    outpre[t * INNER + hd] = f2b(q * st + aug);
  }
}

// ---------------- LayerNorm (in place) ----------------
__global__ __launch_bounds__(256) void ln_kernel(
    float* __restrict__ out, const float* __restrict__ lns,
    const float* __restrict__ lnb) {
  size_t row = blockIdx.x;
  int tid = threadIdx.x;
  float4 v = *(float4*)(out + row * HIDDEN + tid * 4);
  float s = v.x + v.y + v.z + v.w;
  float ss = v.x * v.x + v.y * v.y + v.z * v.z + v.w * v.w;
#pragma unroll
  for (int m = 1; m < 64; m <<= 1) {
    s += __shfl_xor(s, m);
    ss += __shfl_xor(ss, m);
  }
  __shared__ float sb[4], ssb[4];
  int lane = tid & 63, wid = tid >> 6;
  if (lane == 0) {
    sb[wid] = s;
    ssb[wid] = ss;
  }
  __syncthreads();
  s = sb[0] + sb[1] + sb[2] + sb[3];
  ss = ssb[0] + ssb[1] + ssb[2] + ssb[3];
  float mean = s * (1.f / HIDDEN);
  float var = ss * (1.f / HIDDEN) - mean * mean;
  float rstd = rsqrtf(var + 1e-6f);
  float4 sc = *(const float4*)(lns + tid * 4);
  float4 bi = *(const float4*)(lnb + tid * 4);
  v.x = (v.x - mean) * rstd * sc.x + bi.x;
  v.y = (v.y - mean) * rstd * sc.y + bi.y;
  v.z = (v.z - mean) * rstd * sc.z + bi.z;
  v.w = (v.w - mean) * rstd * sc.w + bi.w;
  *(float4*)(out + row * HIDDEN + tid * 4) = v;
}

extern "C" void kernel_launch(void* const* d_in, const int* in_sizes, int n_in,
                              void* d_out, int out_size, void* d_ws, size_t ws_size,
                              hipStream_t stream) {
  const float* x = (const float*)d_in[0];
  const float* Wq = (const float*)d_in[1];
  const float* bq = (const float*)d_in[2];
  const float* Wk = (const float*)d_in[3];
  const float* bk = (const float*)d_in[4];
  const float* Wv = (const float*)d_in[5];
  const float* bv = (const float*)d_in[6];
  const float* Wo = (const float*)d_in[7];
  const float* bo = (const float*)d_in[8];
  const float* alpha = (const float*)d_in[9];
  const float* augp = (const float*)d_in[10];
  const float* lns = (const float*)d_in[11];
  const float* lnb = (const float*)d_in[12];

  char* ws = (char*)d_ws;
  const bool fast = ws_size >= 175118336ull;

  if (fast) {
    u16* xb = (u16*)(ws + 0);                 // 67.1 MB
    u16* qb = (u16*)(ws + 67108864);          // 33.5 MB
    u16* kb = (u16*)(ws + 100663296);         // 33.5 MB (reused as outpre)
    u16* vb = (u16*)(ws + 134217728);         // 33.5 MB
    u16* Wt = (u16*)(ws + 167772160);         // 3 MB, [1536][1024]
    u16* Wot = (u16*)(ws + 170917888);        // 1 MB, [1024][512]
    float* bcat = (float*)(ws + 171966464);   // 6 KB
    float* attn = (float*)(ws + 171972608);   // 1 MB
    float* ends = (float*)(ws + 173021184);   // 1 MB
    float* car = (float*)(ws + 174069760);    // 1 MB
    u16* outpre = kb;

    prep_x<<<ROWS * HIDDEN / 8 / 256, 256, 0, stream>>>(x, xb);
    prep_w<<<8192, 256, 0, stream>>>(Wq, Wk, Wv, Wo, bq, bk, bv, Wt, Wot, bcat);

    // QKV: M=32768, N=1536, K=1024 -> 256*12 = 3072 blocks
    gemm_2ph<false, true><<<3072, 256, 0, stream>>>(
        xb, Wt, bcat, qb, kb, vb, HIDDEN, 12);

    attn_kernel<<<ROWS / 4, 256, 0, stream>>>(qb, kb, attn);
    scan_phase1<<<dim3(NCHUNK, BATCH), 512, 0, stream>>>(vb, attn, alpha, ends);
    scan_phase2<<<BATCH, 512, 0, stream>>>(ends, alpha, car);
    scan_phase3<<<dim3(NCHUNK, BATCH), 512, 0, stream>>>(qb, vb, attn, alpha, augp, car, outpre);

    // out: M=32768, N=1024, K=512 -> 256*8 = 2048 blocks
    gemm_2ph<true, false><<<2048, 256, 0, stream>>>(
        outpre, Wot, bo, d_out, d_out, d_out, INNER, 8);

    ln_kernel<<<ROWS, 256, 0, stream>>>((float*)d_out, lns, lnb);
  } else {
    // round-1 proven layout (108 MB)
    u16* qb = (u16*)(ws + 0);
    u16* kb = (u16*)(ws + 33554432);
    u16* vb = (u16*)(ws + 67108864);
    u16* Wt = (u16*)(ws + 100663296);
    u16* Wot = (u16*)(ws + 103809024);
    float* bcat = (float*)(ws + 104845312);
    float* attn = (float*)(ws + 104857600);
    float* ends = (float*)(ws + 105906176);
    float* car = (float*)(ws + 106954752);
    u16* outpre = kb;

    prep_w<<<8192, 256, 0, stream>>>(Wq, Wk, Wv, Wo, bq, bk, bv, Wt, Wot, bcat);
    gemm128<false, false><<<dim3(4, 256, 3), 256, 0, stream>>>(
        x, Wt, bq, bk, bv, qb, kb, vb, HIDDEN);
    attn_kernel<<<ROWS / 4, 256, 0, stream>>>(qb, kb, attn);
    scan_phase1<<<dim3(NCHUNK, BATCH), 512, 0, stream>>>(vb, attn, alpha, ends);
    scan_phase2<<<BATCH, 512, 0, stream>>>(ends, alpha, car);
    scan_phase3<<<dim3(NCHUNK, BATCH), 512, 0, stream>>>(qb, vb, attn, alpha, augp, car, outpre);
    gemm_2ph<true, false><<<2048, 256, 0, stream>>>(
        outpre, Wot, bo, d_out, d_out, d_out, INNER, 8);
    ln_kernel<<<ROWS, 256, 0, stream>>>((float*)d_out, lns, lnb);
  }
}

// Round 4
// 327.135 us; speedup vs baseline: 1.2891x; 1.0956x over previous
//
#include <hip/hip_runtime.h>
#include <hip/hip_bf16.h>

// MetaLA fused pipeline, round 4.
//  prep_x  : x fp32 -> xb bf16
//  prep_w  : Wq/Wk/Wv -> Wt[1536][1024] bf16 (N-major), Wo -> Wot[1024][512], bias concat
//  gemm256 : 256x256 tile, BK=64, 8 waves (2Mx4N), 128KB double-buffered LDS,
//            counted vmcnt(8) across raw s_barriers (never drain-0 in steady state),
//            XOR-swizzled LDS (col ^= (row&7)<<3) via pre-swizzled global source,
//            XCD-chunked bijective block swizzle.
//  attn_kernel, scan_phase1/2/3 (chunked linear recurrence), gemm256 (out proj), ln_kernel

#define HIDDEN 1024
#define HEADS 8
#define HDIM 64
#define INNER 512
#define BATCH 4
#define SEQ 8192
#define ROWS (BATCH*SEQ)
#define NCHUNK 128
#define CHLEN 64

typedef unsigned short u16;
typedef unsigned int u32;
typedef __attribute__((ext_vector_type(8))) short bf16x8;
typedef __attribute__((ext_vector_type(4))) float f32x4;

__device__ __forceinline__ float b2f(u16 u) { return __uint_as_float(((u32)u) << 16); }
__device__ __forceinline__ u16 f2b(float f) {
  u32 u = __float_as_uint(f);
  u32 r = u + 0x7fffu + ((u >> 16) & 1u);  // RNE
  return (u16)(r >> 16);
}
__device__ __forceinline__ u32 pack2(float a, float b) {
  return (u32)f2b(a) | ((u32)f2b(b) << 16);
}

#define GLOAD_LDS16(gp, lp)                                                  \
  __builtin_amdgcn_global_load_lds(                                          \
      (const __attribute__((address_space(1))) u32*)(gp),                    \
      (__attribute__((address_space(3))) u32*)(lp), 16, 0, 0)

// ---------------- prep_x: fp32 -> bf16 ----------------
__global__ __launch_bounds__(256) void prep_x(const float* __restrict__ x,
                                              u16* __restrict__ xb) {
  size_t i = ((size_t)blockIdx.x * 256 + threadIdx.x) * 8;
  float4 a = *(const float4*)(x + i);
  float4 b = *(const float4*)(x + i + 4);
  uint4 w = {pack2(a.x, a.y), pack2(a.z, a.w), pack2(b.x, b.y), pack2(b.z, b.w)};
  *(uint4*)(xb + i) = w;
}

// ---------------- prep_w: weight transpose/convert + bias concat ----------------
__global__ __launch_bounds__(256) void prep_w(
    const float* __restrict__ Wq, const float* __restrict__ Wk,
    const float* __restrict__ Wv, const float* __restrict__ Wo,
    const float* __restrict__ bq, const float* __restrict__ bk,
    const float* __restrict__ bv,
    u16* __restrict__ Wt, u16* __restrict__ Wot, float* __restrict__ bcat) {
  const int WELEM = HIDDEN * INNER;  // 524288
  int idx = blockIdx.x * 256 + threadIdx.x;
  if (idx < 3 * WELEM) {
    int z = idx / WELEM;
    int rem = idx - z * WELEM;  // n*1024 + k
    int n = rem >> 10;
    int k = rem & 1023;
    const float* W = (z == 0) ? Wq : (z == 1) ? Wk : Wv;
    Wt[idx] = f2b(W[k * INNER + n]);
  } else {
    int rem = idx - 3 * WELEM;  // n*512 + k
    int n = rem >> 9;
    int k = rem & 511;
    Wot[rem] = f2b(Wo[k * HIDDEN + n]);
  }
  if (idx < 3 * INNER) {
    int z = idx >> 9;
    int n = idx & 511;
    bcat[idx] = (z == 0) ? bq[n] : (z == 1) ? bk[n] : bv[n];
  }
}

// ---------------- gemm256: 256x256 tile, BK=64, counted-vmcnt pipeline ----------------
// A: [M][K] bf16, Bt: [N][K] bf16 (row n = output col), out = A@Bt^T + bias.
// SPLIT3: N=1536, route 512-col groups to out0/1/2 (bf16 [M][512]); else out0 fp32 [M][N].
template <int K, bool OUT_F32, bool SPLIT3>
__global__ __launch_bounds__(512, 2) void gemm256(
    const u16* __restrict__ A, const u16* __restrict__ Bt,
    const float* __restrict__ bias,
    void* __restrict__ out0, void* __restrict__ out1, void* __restrict__ out2,
    int nTilesN) {
  constexpr int NT = K / 64;  // K-tiles (16 or 8), even
  // [buf][ A: 256x64 swizzled (16384 u16) | B: 256x64 swizzled (16384 u16) ]
  __shared__ u16 lds[2][32768];

  // bijective XCD-chunked swizzle (nwg % 8 == 0); consecutive lin share A-panel
  const int nwg = gridDim.x;
  const int chunk = nwg >> 3;
  const int bid = blockIdx.x;
  const int lin = (bid & 7) * chunk + (bid >> 3);
  const int nt = lin % nTilesN;
  const int mt = lin / nTilesN;
  const int m0 = mt * 256, n0 = nt * 256;
  const int N = nTilesN * 256;

  const int tid = threadIdx.x;
  const int lane = tid & 63;
  const int w = tid >> 6;   // 0..7
  const int wm = w >> 2;    // 0..1  (M half)
  const int wn = w & 3;     // 0..3  (N quarter)
  const int r16 = lane & 15, kq = lane >> 4;

  // ---- staging geometry (pre-swizzled global source, linear LDS dest) ----
  // round r covers LDS u16 [r*4096, +4096) = rows [r*64, +64), thread t covers
  // L = r*4096 + t*8 -> row = r*64 + t/8, col' = (t&7)*8. Stored element must be
  // global (row, col' ^ ((row&7)<<3)).
  const int rt = tid >> 3;                         // row within round
  const int cg = (((tid & 7) ^ (rt & 7)) << 3);    // pre-swizzled global col
  const u16* Ag = A + (size_t)(m0 + rt) * K + cg;
  const u16* Bg = Bt + (size_t)(n0 + rt) * K + cg;
  const int ldst = w * 512;  // wave-uniform within-round base; HW adds lane*16B

#define STAGE(buf, kt)                                                          \
  {                                                                             \
    const u16* ga = Ag + (size_t)(kt) * 64;                                     \
    const u16* gb = Bg + (size_t)(kt) * 64;                                     \
    _Pragma("unroll") for (int r = 0; r < 4; r++)                               \
        GLOAD_LDS16(ga + (size_t)r * 64 * K, &lds[buf][r * 4096 + ldst]);       \
    _Pragma("unroll") for (int r = 0; r < 4; r++)                               \
        GLOAD_LDS16(gb + (size_t)r * 64 * K, &lds[buf][16384 + r * 4096 + ldst]); \
  }

  // ---- read-side addresses (swizzled) ----
  // element (row, c) lives at u16 addr row*64 + (c ^ ((row&7)<<3)); row&7 == r16&7
  int colx[2];
#pragma unroll
  for (int ks = 0; ks < 2; ks++)
    colx[ks] = (((ks << 5) | (kq << 3)) ^ ((r16 & 7) << 3));
  const int aBase = (wm * 128 + r16) * 64;         // + i*1024 + colx[ks]
  const int bBase = 16384 + (wn * 64 + r16) * 64;  // + j*1024 + colx[ks]

  f32x4 acc[8][4] = {};

#define COMPUTE(buf)                                                           \
  {                                                                            \
    bf16x8 bfr[4][2];                                                          \
    _Pragma("unroll") for (int j = 0; j < 4; j++)                              \
        _Pragma("unroll") for (int ks = 0; ks < 2; ks++)                       \
            bfr[j][ks] = *(const bf16x8*)&lds[buf][bBase + j * 1024 + colx[ks]]; \
    _Pragma("unroll") for (int i = 0; i < 8; i++) {                            \
      bf16x8 a0 = *(const bf16x8*)&lds[buf][aBase + i * 1024 + colx[0]];       \
      bf16x8 a1 = *(const bf16x8*)&lds[buf][aBase + i * 1024 + colx[1]];       \
      _Pragma("unroll") for (int j = 0; j < 4; j++)                            \
          acc[i][j] =                                                          \
          __builtin_amdgcn_mfma_f32_16x16x32_bf16(a0, bfr[j][0], acc[i][j], 0, 0, 0); \
      _Pragma("unroll") for (int j = 0; j < 4; j++)                            \
          acc[i][j] =                                                          \
          __builtin_amdgcn_mfma_f32_16x16x32_bf16(a1, bfr[j][1], acc[i][j], 0, 0, 0); \
    }                                                                          \
  }

  // ---- prologue: stage tiles 0,1; wait tile0; barrier ----
  STAGE(0, 0);
  STAGE(1, 1);
  asm volatile("s_waitcnt vmcnt(8)" ::: "memory");
  __builtin_amdgcn_sched_barrier(0);
  __builtin_amdgcn_s_barrier();

  for (int t = 0; t < NT; t += 2) {
    COMPUTE(0);  // tile t
    asm volatile("s_waitcnt lgkmcnt(0)" ::: "memory");
    __builtin_amdgcn_sched_barrier(0);
    __builtin_amdgcn_s_barrier();  // all waves done reading buf0
    if (t + 2 < NT) {
      STAGE(0, t + 2);
      asm volatile("s_waitcnt vmcnt(8)" ::: "memory");  // tile t+1 landed
    } else {
      asm volatile("s_waitcnt vmcnt(0)" ::: "memory");
    }
    __builtin_amdgcn_sched_barrier(0);
    __builtin_amdgcn_s_barrier();  // tile t+1 visible to all

    COMPUTE(1);  // tile t+1
    asm volatile("s_waitcnt lgkmcnt(0)" ::: "memory");
    __builtin_amdgcn_sched_barrier(0);
    __builtin_amdgcn_s_barrier();  // all waves done reading buf1
    if (t + 3 < NT) {
      STAGE(1, t + 3);
      asm volatile("s_waitcnt vmcnt(8)" ::: "memory");  // tile t+2 landed
    } else {
      asm volatile("s_waitcnt vmcnt(0)" ::: "memory");
    }
    __builtin_amdgcn_sched_barrier(0);
    __builtin_amdgcn_s_barrier();
  }
#undef STAGE
#undef COMPUTE

  // ---- epilogue: C/D layout col=lane&15, row=(lane>>4)*4+reg  [m89/m91] ----
  const int zsel = SPLIT3 ? ((n0 + wn * 64) >> 9) : 0;
  u16* ob16 = (u16*)((zsel == 0) ? out0 : (zsel == 1) ? out1 : out2);
#pragma unroll
  for (int j = 0; j < 4; j++) {
    int col = n0 + wn * 64 + j * 16 + r16;
    float bv = bias[col];
    int colm = SPLIT3 ? (col & 511) : col;
#pragma unroll
    for (int i = 0; i < 8; i++) {
#pragma unroll
      for (int q = 0; q < 4; q++) {
        int row = m0 + wm * 128 + i * 16 + kq * 4 + q;
        float v = acc[i][j][q] + bv;
        if (OUT_F32)
          ((float*)out0)[(size_t)row * N + col] = v;
        else
          ob16[(size_t)row * INNER + colm] = f2b(v);
      }
    }
  }
}

// ---------------- legacy 128^2 GEMM (fp32 A staging) — small-ws fallback ----------------
template <bool A_BF16, bool OUT_F32>
__global__ __launch_bounds__(256) void gemm128(
    const void* __restrict__ Aany, const u16* __restrict__ BtBase,
    const float* __restrict__ bias0, const float* __restrict__ bias1,
    const float* __restrict__ bias2,
    void* __restrict__ out0, void* __restrict__ out1, void* __restrict__ out2,
    int K) {
  __shared__ u16 As[128 * 32];
  __shared__ u16 Bs[128 * 32];
  const int N = gridDim.x * 128;
  const int z = blockIdx.z;
  const u16* Bt = BtBase + (size_t)z * N * K;
  const float* bias = (z == 0) ? bias0 : (z == 1) ? bias1 : bias2;
  void* Out = (z == 0) ? out0 : (z == 1) ? out1 : out2;
  const int tid = threadIdx.x;
  const int m0 = blockIdx.y * 128;
  const int n0 = blockIdx.x * 128;
  const int lane = tid & 63;
  const int wid = tid >> 6;
  const int wm = wid >> 1, wn = wid & 1;
  const int r16 = lane & 15, kq = lane >> 4;
  const int r = tid >> 1;
  const int half = tid & 1;
  f32x4 acc[4][4] = {};
  for (int k0 = 0; k0 < K; k0 += 32) {
    __syncthreads();
    if (A_BF16) {
      const u16* Ab = (const u16*)Aany;
      const int4* src = (const int4*)(Ab + (size_t)(m0 + r) * K + k0 + half * 16);
      int4 v0 = src[0];
      int4 v1 = src[1];
      *(int4*)&As[r * 32 + half * 16] = v0;
      *(int4*)&As[r * 32 + half * 16 + 8] = v1;
    } else {
      const float* Af = (const float*)Aany;
      const float4* src = (const float4*)(Af + (size_t)(m0 + r) * K + k0 + half * 16);
      float4 f0 = src[0], f1 = src[1], f2 = src[2], f3 = src[3];
      uint4 w0 = {pack2(f0.x, f0.y), pack2(f0.z, f0.w), pack2(f1.x, f1.y), pack2(f1.z, f1.w)};
      uint4 w1 = {pack2(f2.x, f2.y), pack2(f2.z, f2.w), pack2(f3.x, f3.y), pack2(f3.z, f3.w)};
      *(uint4*)&As[r * 32 + half * 16] = w0;
      *(uint4*)&As[r * 32 + half * 16 + 8] = w1;
    }
    {
      const int4* src = (const int4*)(Bt + (size_t)(n0 + r) * K + k0 + half * 16);
      int4 v0 = src[0];
      int4 v1 = src[1];
      *(int4*)&Bs[r * 32 + half * 16] = v0;
      *(int4*)&Bs[r * 32 + half * 16 + 8] = v1;
    }
    __syncthreads();
    bf16x8 a[4], b[4];
#pragma unroll
    for (int i = 0; i < 4; i++)
      a[i] = *(const bf16x8*)&As[(wm * 64 + i * 16 + r16) * 32 + kq * 8];
#pragma unroll
    for (int j = 0; j < 4; j++)
      b[j] = *(const bf16x8*)&Bs[(wn * 64 + j * 16 + r16) * 32 + kq * 8];
#pragma unroll
    for (int i = 0; i < 4; i++)
#pragma unroll
      for (int j = 0; j < 4; j++)
        acc[i][j] = __builtin_amdgcn_mfma_f32_16x16x32_bf16(a[i], b[j], acc[i][j], 0, 0, 0);
  }
#pragma unroll
  for (int j = 0; j < 4; j++) {
    int col = n0 + wn * 64 + j * 16 + r16;
    float bv = bias[col];
#pragma unroll
    for (int i = 0; i < 4; i++) {
#pragma unroll
      for (int q = 0; q < 4; q++) {
        int row = m0 + wm * 64 + i * 16 + kq * 4 + q;
        float v = acc[i][j][q] + bv;
        if (OUT_F32)
          ((float*)Out)[(size_t)row * N + col] = v;
        else
          ((u16*)Out)[(size_t)row * N + col] = f2b(v);
      }
    }
  }
}

// ---------------- attn: softmax over heads of (q.k)/8 ----------------
__global__ __launch_bounds__(256) void attn_kernel(
    const u16* __restrict__ qb, const u16* __restrict__ kb,
    float* __restrict__ attn) {
  int lane = threadIdx.x & 63;
  int wid = threadIdx.x >> 6;
  size_t t = (size_t)blockIdx.x * 4 + wid;
  int4 qv = *(const int4*)(qb + t * INNER + lane * 8);
  int4 kv = *(const int4*)(kb + t * INNER + lane * 8);
  const u16* qu = (const u16*)&qv;
  const u16* ku = (const u16*)&kv;
  float s = 0.f;
#pragma unroll
  for (int j = 0; j < 8; j++) s += b2f(qu[j]) * b2f(ku[j]);
  s += __shfl_xor(s, 1);
  s += __shfl_xor(s, 2);
  s += __shfl_xor(s, 4);
  s *= 0.125f;
  float mx = s;
  mx = fmaxf(mx, __shfl_xor(mx, 8));
  mx = fmaxf(mx, __shfl_xor(mx, 16));
  mx = fmaxf(mx, __shfl_xor(mx, 32));
  float e = __expf(s - mx);
  float sm = e;
  sm += __shfl_xor(sm, 8);
  sm += __shfl_xor(sm, 16);
  sm += __shfl_xor(sm, 32);
  float a = e / sm;
  if ((lane & 7) == 0) attn[t * HEADS + (lane >> 3)] = a;
}

// ---------------- scan ----------------
__global__ __launch_bounds__(512) void scan_phase1(
    const u16* __restrict__ vb, const float* __restrict__ attn,
    const float* __restrict__ alpha, float* __restrict__ ends) {
  int hd = threadIdx.x;
  int h = hd >> 6;
  int c = blockIdx.x, b = blockIdx.y;
  float decay = 1.f / (1.f + __expf(-alpha[hd]));
  float om = 1.f - decay;
  size_t base = (size_t)b * SEQ + (size_t)c * CHLEN;
  float st = 0.f;
#pragma unroll 8
  for (int i = 0; i < CHLEN; i++) {
    size_t t = base + i;
    float a = attn[t * HEADS + h];
    float v = b2f(vb[t * INNER + hd]);
    st = decay * st + om * a * v;
  }
  ends[((size_t)b * NCHUNK + c) * INNER + hd] = st;
}

__global__ __launch_bounds__(512) void scan_phase2(
    const float* __restrict__ ends, const float* __restrict__ alpha,
    float* __restrict__ carries) {
  int hd = threadIdx.x;
  int b = blockIdx.x;
  float decay = 1.f / (1.f + __expf(-alpha[hd]));
  float dL = __powf(decay, (float)CHLEN);
  float carry = 0.f;
#pragma unroll 8
  for (int c = 0; c < NCHUNK; c++) {
    size_t idx = ((size_t)b * NCHUNK + c) * INNER + hd;
    carries[idx] = carry;
    carry = dL * carry + ends[idx];
  }
}

__global__ __launch_bounds__(512) void scan_phase3(
    const u16* __restrict__ qb, const u16* __restrict__ vb,
    const float* __restrict__ attn, const float* __restrict__ alpha,
    const float* __restrict__ augp, const float* __restrict__ carries,
    u16* __restrict__ outpre) {
  int hd = threadIdx.x;
  int h = hd >> 6;
  int c = blockIdx.x, b = blockIdx.y;
  float decay = 1.f / (1.f + __expf(-alpha[hd]));
  float om = 1.f - decay;
  float ap = augp[hd];
  float st = carries[((size_t)b * NCHUNK + c) * INNER + hd];
  size_t base = (size_t)b * SEQ + (size_t)c * CHLEN;
#pragma unroll 4
  for (int i = 0; i < CHLEN; i++) {
    size_t t = base + i;
    float a = attn[t * HEADS + h];
    float v = b2f(vb[t * INNER + hd]);
    st = decay * st + om * a * v;
    float q = b2f(qb[t * INNER + hd]);
    float aug = 1.f / (1.f + __expf(-q * ap));
    outpre[t * INNER + hd] = f2b(q * st + aug);
  }
}

// ---------------- LayerNorm (in place) ----------------
__global__ __launch_bounds__(256) void ln_kernel(
    float* __restrict__ out, const float* __restrict__ lns,
    const float* __restrict__ lnb) {
  size_t row = blockIdx.x;
  int tid = threadIdx.x;
  float4 v = *(float4*)(out + row * HIDDEN + tid * 4);
  float s = v.x + v.y + v.z + v.w;
  float ss = v.x * v.x + v.y * v.y + v.z * v.z + v.w * v.w;
#pragma unroll
  for (int m = 1; m < 64; m <<= 1) {
    s += __shfl_xor(s, m);
    ss += __shfl_xor(ss, m);
  }
  __shared__ float sb[4], ssb[4];
  int lane = tid & 63, wid = tid >> 6;
  if (lane == 0) {
    sb[wid] = s;
    ssb[wid] = ss;
  }
  __syncthreads();
  s = sb[0] + sb[1] + sb[2] + sb[3];
  ss = ssb[0] + ssb[1] + ssb[2] + ssb[3];
  float mean = s * (1.f / HIDDEN);
  float var = ss * (1.f / HIDDEN) - mean * mean;
  float rstd = rsqrtf(var + 1e-6f);
  float4 sc = *(const float4*)(lns + tid * 4);
  float4 bi = *(const float4*)(lnb + tid * 4);
  v.x = (v.x - mean) * rstd * sc.x + bi.x;
  v.y = (v.y - mean) * rstd * sc.y + bi.y;
  v.z = (v.z - mean) * rstd * sc.z + bi.z;
  v.w = (v.w - mean) * rstd * sc.w + bi.w;
  *(float4*)(out + row * HIDDEN + tid * 4) = v;
}

extern "C" void kernel_launch(void* const* d_in, const int* in_sizes, int n_in,
                              void* d_out, int out_size, void* d_ws, size_t ws_size,
                              hipStream_t stream) {
  const float* x = (const float*)d_in[0];
  const float* Wq = (const float*)d_in[1];
  const float* bq = (const float*)d_in[2];
  const float* Wk = (const float*)d_in[3];
  const float* bk = (const float*)d_in[4];
  const float* Wv = (const float*)d_in[5];
  const float* bv = (const float*)d_in[6];
  const float* Wo = (const float*)d_in[7];
  const float* bo = (const float*)d_in[8];
  const float* alpha = (const float*)d_in[9];
  const float* augp = (const float*)d_in[10];
  const float* lns = (const float*)d_in[11];
  const float* lnb = (const float*)d_in[12];

  char* ws = (char*)d_ws;
  const bool fast = ws_size >= 175118336ull;

  if (fast) {
    u16* xb = (u16*)(ws + 0);                 // 67.1 MB
    u16* qb = (u16*)(ws + 67108864);          // 33.5 MB
    u16* kb = (u16*)(ws + 100663296);         // 33.5 MB (reused as outpre)
    u16* vb = (u16*)(ws + 134217728);         // 33.5 MB
    u16* Wt = (u16*)(ws + 167772160);         // 3 MB, [1536][1024]
    u16* Wot = (u16*)(ws + 170917888);        // 1 MB, [1024][512]
    float* bcat = (float*)(ws + 171966464);   // 6 KB
    float* attn = (float*)(ws + 171972608);   // 1 MB
    float* ends = (float*)(ws + 173021184);   // 1 MB
    float* car = (float*)(ws + 174069760);    // 1 MB
    u16* outpre = kb;

    prep_x<<<ROWS * HIDDEN / 8 / 256, 256, 0, stream>>>(x, xb);
    prep_w<<<8192, 256, 0, stream>>>(Wq, Wk, Wv, Wo, bq, bk, bv, Wt, Wot, bcat);

    // QKV: M=32768, N=1536 -> 128*6 = 768 blocks of 512 thr
    gemm256<HIDDEN, false, true><<<768, 512, 0, stream>>>(
        xb, Wt, bcat, qb, kb, vb, 6);

    attn_kernel<<<ROWS / 4, 256, 0, stream>>>(qb, kb, attn);
    scan_phase1<<<dim3(NCHUNK, BATCH), 512, 0, stream>>>(vb, attn, alpha, ends);
    scan_phase2<<<BATCH, 512, 0, stream>>>(ends, alpha, car);
    scan_phase3<<<dim3(NCHUNK, BATCH), 512, 0, stream>>>(qb, vb, attn, alpha, augp, car, outpre);

    // out: M=32768, N=1024 -> 128*4 = 512 blocks
    gemm256<INNER, true, false><<<512, 512, 0, stream>>>(
        outpre, Wot, bo, d_out, d_out, d_out, 4);

    ln_kernel<<<ROWS, 256, 0, stream>>>((float*)d_out, lns, lnb);
  } else {
    // round-1 proven layout (108 MB)
    u16* qb = (u16*)(ws + 0);
    u16* kb = (u16*)(ws + 33554432);
    u16* vb = (u16*)(ws + 67108864);
    u16* Wt = (u16*)(ws + 100663296);
    u16* Wot = (u16*)(ws + 103809024);
    float* bcat = (float*)(ws + 104845312);
    float* attn = (float*)(ws + 104857600);
    float* ends = (float*)(ws + 105906176);
    float* car = (float*)(ws + 106954752);
    u16* outpre = kb;

    prep_w<<<8192, 256, 0, stream>>>(Wq, Wk, Wv, Wo, bq, bk, bv, Wt, Wot, bcat);
    gemm128<false, false><<<dim3(4, 256, 3), 256, 0, stream>>>(
        x, Wt, bq, bk, bv, qb, kb, vb, HIDDEN);
    attn_kernel<<<ROWS / 4, 256, 0, stream>>>(qb, kb, attn);
    scan_phase1<<<dim3(NCHUNK, BATCH), 512, 0, stream>>>(vb, attn, alpha, ends);
    scan_phase2<<<BATCH, 512, 0, stream>>>(ends, alpha, car);
    scan_phase3<<<dim3(NCHUNK, BATCH), 512, 0, stream>>>(qb, vb, attn, alpha, augp, car, outpre);
    gemm256<INNER, true, false><<<512, 512, 0, stream>>>(
        outpre, Wot, bo, d_out, d_out, d_out, 4);
    ln_kernel<<<ROWS, 256, 0, stream>>>((float*)d_out, lns, lnb);
  }
}

// Round 5
// 324.126 us; speedup vs baseline: 1.3010x; 1.0093x over previous
//
#include <hip/hip_runtime.h>
#include <hip/hip_bf16.h>

// MetaLA fused pipeline, round 5.
//  prep_x  : x fp32 -> xb bf16
//  prep_w  : Wq/Wk/Wv -> Wt[1536][1024] bf16 (N-major), Wo -> Wot[1024][512], bias concat
//  gemm_ring: 256x256 tile, BK=32, 8 waves (2Mx4N), 4-slot LDS ring (4x32KB),
//            prefetch depth 3, counted s_waitcnt vmcnt(12) (never drains in steady
//            state), raw s_barriers, XOR-swizzled LDS (col ^= (row&3)<<3) via
//            pre-swizzled global source, XCD-chunked bijective block swizzle.
//  attn_kernel, scan_phase1/2/3 (chunked linear recurrence), gemm_ring (out proj), ln_kernel

#define HIDDEN 1024
#define HEADS 8
#define HDIM 64
#define INNER 512
#define BATCH 4
#define SEQ 8192
#define ROWS (BATCH*SEQ)
#define NCHUNK 128
#define CHLEN 64

typedef unsigned short u16;
typedef unsigned int u32;
typedef __attribute__((ext_vector_type(8))) short bf16x8;
typedef __attribute__((ext_vector_type(4))) float f32x4;

__device__ __forceinline__ float b2f(u16 u) { return __uint_as_float(((u32)u) << 16); }
__device__ __forceinline__ u16 f2b(float f) {
  u32 u = __float_as_uint(f);
  u32 r = u + 0x7fffu + ((u >> 16) & 1u);  // RNE
  return (u16)(r >> 16);
}
__device__ __forceinline__ u32 pack2(float a, float b) {
  return (u32)f2b(a) | ((u32)f2b(b) << 16);
}

#define GLOAD_LDS16(gp, lp)                                                  \
  __builtin_amdgcn_global_load_lds(                                          \
      (const __attribute__((address_space(1))) u32*)(gp),                    \
      (__attribute__((address_space(3))) u32*)(lp), 16, 0, 0)

// ---------------- prep_x: fp32 -> bf16 ----------------
__global__ __launch_bounds__(256) void prep_x(const float* __restrict__ x,
                                              u16* __restrict__ xb) {
  size_t i = ((size_t)blockIdx.x * 256 + threadIdx.x) * 8;
  float4 a = *(const float4*)(x + i);
  float4 b = *(const float4*)(x + i + 4);
  uint4 w = {pack2(a.x, a.y), pack2(a.z, a.w), pack2(b.x, b.y), pack2(b.z, b.w)};
  *(uint4*)(xb + i) = w;
}

// ---------------- prep_w: weight transpose/convert + bias concat ----------------
__global__ __launch_bounds__(256) void prep_w(
    const float* __restrict__ Wq, const float* __restrict__ Wk,
    const float* __restrict__ Wv, const float* __restrict__ Wo,
    const float* __restrict__ bq, const float* __restrict__ bk,
    const float* __restrict__ bv,
    u16* __restrict__ Wt, u16* __restrict__ Wot, float* __restrict__ bcat) {
  const int WELEM = HIDDEN * INNER;  // 524288
  int idx = blockIdx.x * 256 + threadIdx.x;
  if (idx < 3 * WELEM) {
    int z = idx / WELEM;
    int rem = idx - z * WELEM;  // n*1024 + k
    int n = rem >> 10;
    int k = rem & 1023;
    const float* W = (z == 0) ? Wq : (z == 1) ? Wk : Wv;
    Wt[idx] = f2b(W[k * INNER + n]);
  } else {
    int rem = idx - 3 * WELEM;  // n*512 + k
    int n = rem >> 9;
    int k = rem & 511;
    Wot[rem] = f2b(Wo[k * HIDDEN + n]);
  }
  if (idx < 3 * INNER) {
    int z = idx >> 9;
    int n = idx & 511;
    bcat[idx] = (z == 0) ? bq[n] : (z == 1) ? bk[n] : bv[n];
  }
}

// ---------------- gemm_ring: 256x256 tile, BK=32, 4-slot ring, counted vmcnt ----------------
// A: [M][K] bf16, Bt: [N][K] bf16 (row n = output col), out = A@Bt^T + bias.
// SPLIT3: N=1536, route 512-col groups to out0/1/2 (bf16 [M][512]); else out0 fp32 [M][N].
template <int K, bool OUT_F32, bool SPLIT3>
__global__ __launch_bounds__(512, 2) void gemm_ring(
    const u16* __restrict__ A, const u16* __restrict__ Bt,
    const float* __restrict__ bias,
    void* __restrict__ out0, void* __restrict__ out1, void* __restrict__ out2,
    int nTilesN) {
  constexpr int NT = K / 32;  // K-tiles; >= 4
  // slot: A 256x32 swizzled (8192 u16) | B 256x32 swizzled (8192 u16) = 32KB
  __shared__ u16 lds[4][16384];

  // bijective XCD-chunked swizzle (nwg % 8 == 0); consecutive lin share A-panel
  const int nwg = gridDim.x;
  const int chunk = nwg >> 3;
  const int bid = blockIdx.x;
  const int lin = (bid & 7) * chunk + (bid >> 3);
  const int nt = lin % nTilesN;
  const int mt = lin / nTilesN;
  const int m0 = mt * 256, n0 = nt * 256;
  const int N = nTilesN * 256;

  const int tid = threadIdx.x;
  const int lane = tid & 63;
  const int w = tid >> 6;   // 0..7
  const int wm = w >> 2;    // 0..1  (M half: 128 rows)
  const int wn = w & 3;     // 0..3  (N quarter: 64 cols)
  const int r16 = lane & 15, kq = lane >> 4;

  // ---- staging geometry (pre-swizzled global source, linear LDS dest) ----
  // round r covers rows [r*128,+128): thread t -> linear u16 = r*4096 + t*8
  // -> row = r*128 + t/4, col' = (t&3)*8; stored elem = global (row, col'^((row&3)<<3)).
  const int rt = tid >> 2;
  const int cg = (((tid & 3) ^ (rt & 3)) << 3);
  const u16* Ag = A + (size_t)(m0 + rt) * K + cg;
  const u16* Bg = Bt + (size_t)(n0 + rt) * K + cg;
  const int ldst = w * 512;  // wave-uniform; HW adds lane*16B

#define STAGE(slot, kt)                                                       \
  {                                                                           \
    const u16* ga = Ag + (size_t)(kt) * 32;                                   \
    const u16* gb = Bg + (size_t)(kt) * 32;                                   \
    GLOAD_LDS16(ga, &lds[slot][ldst]);                                        \
    GLOAD_LDS16(ga + (size_t)128 * K, &lds[slot][4096 + ldst]);               \
    GLOAD_LDS16(gb, &lds[slot][8192 + ldst]);                                 \
    GLOAD_LDS16(gb + (size_t)128 * K, &lds[slot][12288 + ldst]);              \
  }

  // ---- read-side swizzled offsets: elem (row,c) at row*32 + (c ^ ((row&3)<<3)) ----
  const int xr = (r16 & 3) << 3;
  const int aO = (wm * 128 + r16) * 32 + ((kq << 3) ^ xr);         // + i*512
  const int bO = 8192 + (wn * 64 + r16) * 32 + ((kq << 3) ^ xr);   // + j*512

  f32x4 acc[8][4] = {};

#define COMPUTE(slot)                                                          \
  {                                                                            \
    const u16* sl = &lds[slot][0];                                             \
    bf16x8 af[8], bfv[4];                                                      \
    _Pragma("unroll") for (int j = 0; j < 4; j++)                              \
        bfv[j] = *(const bf16x8*)&sl[bO + j * 512];                            \
    _Pragma("unroll") for (int i = 0; i < 8; i++)                              \
        af[i] = *(const bf16x8*)&sl[aO + i * 512];                             \
    _Pragma("unroll") for (int i = 0; i < 8; i++)                              \
        _Pragma("unroll") for (int j = 0; j < 4; j++)                          \
            acc[i][j] =                                                        \
        __builtin_amdgcn_mfma_f32_16x16x32_bf16(af[i], bfv[j], acc[i][j], 0, 0, 0); \
  }

#define SYNCB                                                                  \
  {                                                                            \
    __builtin_amdgcn_sched_barrier(0);                                         \
    __builtin_amdgcn_s_barrier();                                              \
    __builtin_amdgcn_sched_barrier(0);                                         \
  }

  // prologue: fill 3 slots (12 loads in flight)
  STAGE(0, 0);
  STAGE(1, 1);
  STAGE(2, 2);

  // steady state: stage t+3 into just-freed slot, wait tile t (12 newer in flight)
  for (int t = 0; t < NT - 3; ++t) {
    STAGE((t + 3) & 3, t + 3);
    asm volatile("s_waitcnt vmcnt(12)" ::: "memory");
    SYNCB;
    COMPUTE(t & 3);
    SYNCB;
  }
  asm volatile("s_waitcnt vmcnt(8)" ::: "memory");
  SYNCB;
  COMPUTE((NT - 3) & 3);
  SYNCB;
  asm volatile("s_waitcnt vmcnt(4)" ::: "memory");
  SYNCB;
  COMPUTE((NT - 2) & 3);
  SYNCB;
  asm volatile("s_waitcnt vmcnt(0)" ::: "memory");
  SYNCB;
  COMPUTE((NT - 1) & 3);
#undef STAGE
#undef COMPUTE
#undef SYNCB

  // ---- epilogue: C/D layout col=lane&15, row=(lane>>4)*4+reg  [m89/m91] ----
  const int zsel = SPLIT3 ? ((n0 + wn * 64) >> 9) : 0;
  u16* ob16 = (u16*)((zsel == 0) ? out0 : (zsel == 1) ? out1 : out2);
#pragma unroll
  for (int j = 0; j < 4; j++) {
    int col = n0 + wn * 64 + j * 16 + r16;
    float bv = bias[col];
    int colm = SPLIT3 ? (col & 511) : col;
#pragma unroll
    for (int i = 0; i < 8; i++) {
#pragma unroll
      for (int q = 0; q < 4; q++) {
        int row = m0 + wm * 128 + i * 16 + kq * 4 + q;
        float v = acc[i][j][q] + bv;
        if (OUT_F32)
          ((float*)out0)[(size_t)row * N + col] = v;
        else
          ob16[(size_t)row * INNER + colm] = f2b(v);
      }
    }
  }
}

// ---------------- legacy 128^2 GEMM (fp32 A staging) — small-ws fallback ----------------
template <bool A_BF16, bool OUT_F32>
__global__ __launch_bounds__(256) void gemm128(
    const void* __restrict__ Aany, const u16* __restrict__ BtBase,
    const float* __restrict__ bias0, const float* __restrict__ bias1,
    const float* __restrict__ bias2,
    void* __restrict__ out0, void* __restrict__ out1, void* __restrict__ out2,
    int K) {
  __shared__ u16 As[128 * 32];
  __shared__ u16 Bs[128 * 32];
  const int N = gridDim.x * 128;
  const int z = blockIdx.z;
  const u16* Bt = BtBase + (size_t)z * N * K;
  const float* bias = (z == 0) ? bias0 : (z == 1) ? bias1 : bias2;
  void* Out = (z == 0) ? out0 : (z == 1) ? out1 : out2;
  const int tid = threadIdx.x;
  const int m0 = blockIdx.y * 128;
  const int n0 = blockIdx.x * 128;
  const int lane = tid & 63;
  const int wid = tid >> 6;
  const int wm = wid >> 1, wn = wid & 1;
  const int r16 = lane & 15, kq = lane >> 4;
  const int r = tid >> 1;
  const int half = tid & 1;
  f32x4 acc[4][4] = {};
  for (int k0 = 0; k0 < K; k0 += 32) {
    __syncthreads();
    if (A_BF16) {
      const u16* Ab = (const u16*)Aany;
      const int4* src = (const int4*)(Ab + (size_t)(m0 + r) * K + k0 + half * 16);
      int4 v0 = src[0];
      int4 v1 = src[1];
      *(int4*)&As[r * 32 + half * 16] = v0;
      *(int4*)&As[r * 32 + half * 16 + 8] = v1;
    } else {
      const float* Af = (const float*)Aany;
      const float4* src = (const float4*)(Af + (size_t)(m0 + r) * K + k0 + half * 16);
      float4 f0 = src[0], f1 = src[1], f2 = src[2], f3 = src[3];
      uint4 w0 = {pack2(f0.x, f0.y), pack2(f0.z, f0.w), pack2(f1.x, f1.y), pack2(f1.z, f1.w)};
      uint4 w1 = {pack2(f2.x, f2.y), pack2(f2.z, f2.w), pack2(f3.x, f3.y), pack2(f3.z, f3.w)};
      *(uint4*)&As[r * 32 + half * 16] = w0;
      *(uint4*)&As[r * 32 + half * 16 + 8] = w1;
    }
    {
      const int4* src = (const int4*)(Bt + (size_t)(n0 + r) * K + k0 + half * 16);
      int4 v0 = src[0];
      int4 v1 = src[1];
      *(int4*)&Bs[r * 32 + half * 16] = v0;
      *(int4*)&Bs[r * 32 + half * 16 + 8] = v1;
    }
    __syncthreads();
    bf16x8 a[4], b[4];
#pragma unroll
    for (int i = 0; i < 4; i++)
      a[i] = *(const bf16x8*)&As[(wm * 64 + i * 16 + r16) * 32 + kq * 8];
#pragma unroll
    for (int j = 0; j < 4; j++)
      b[j] = *(const bf16x8*)&Bs[(wn * 64 + j * 16 + r16) * 32 + kq * 8];
#pragma unroll
    for (int i = 0; i < 4; i++)
#pragma unroll
      for (int j = 0; j < 4; j++)
        acc[i][j] = __builtin_amdgcn_mfma_f32_16x16x32_bf16(a[i], b[j], acc[i][j], 0, 0, 0);
  }
#pragma unroll
  for (int j = 0; j < 4; j++) {
    int col = n0 + wn * 64 + j * 16 + r16;
    float bv = bias[col];
#pragma unroll
    for (int i = 0; i < 4; i++) {
#pragma unroll
      for (int q = 0; q < 4; q++) {
        int row = m0 + wm * 64 + i * 16 + kq * 4 + q;
        float v = acc[i][j][q] + bv;
        if (OUT_F32)
          ((float*)Out)[(size_t)row * N + col] = v;
        else
          ((u16*)Out)[(size_t)row * N + col] = f2b(v);
      }
    }
  }
}

// ---------------- attn: softmax over heads of (q.k)/8 ----------------
__global__ __launch_bounds__(256) void attn_kernel(
    const u16* __restrict__ qb, const u16* __restrict__ kb,
    float* __restrict__ attn) {
  int lane = threadIdx.x & 63;
  int wid = threadIdx.x >> 6;
  size_t t = (size_t)blockIdx.x * 4 + wid;
  int4 qv = *(const int4*)(qb + t * INNER + lane * 8);
  int4 kv = *(const int4*)(kb + t * INNER + lane * 8);
  const u16* qu = (const u16*)&qv;
  const u16* ku = (const u16*)&kv;
  float s = 0.f;
#pragma unroll
  for (int j = 0; j < 8; j++) s += b2f(qu[j]) * b2f(ku[j]);
  s += __shfl_xor(s, 1);
  s += __shfl_xor(s, 2);
  s += __shfl_xor(s, 4);
  s *= 0.125f;
  float mx = s;
  mx = fmaxf(mx, __shfl_xor(mx, 8));
  mx = fmaxf(mx, __shfl_xor(mx, 16));
  mx = fmaxf(mx, __shfl_xor(mx, 32));
  float e = __expf(s - mx);
  float sm = e;
  sm += __shfl_xor(sm, 8);
  sm += __shfl_xor(sm, 16);
  sm += __shfl_xor(sm, 32);
  float a = e / sm;
  if ((lane & 7) == 0) attn[t * HEADS + (lane >> 3)] = a;
}

// ---------------- scan ----------------
__global__ __launch_bounds__(512) void scan_phase1(
    const u16* __restrict__ vb, const float* __restrict__ attn,
    const float* __restrict__ alpha, float* __restrict__ ends) {
  int hd = threadIdx.x;
  int h = hd >> 6;
  int c = blockIdx.x, b = blockIdx.y;
  float decay = 1.f / (1.f + __expf(-alpha[hd]));
  float om = 1.f - decay;
  size_t base = (size_t)b * SEQ + (size_t)c * CHLEN;
  float st = 0.f;
#pragma unroll 8
  for (int i = 0; i < CHLEN; i++) {
    size_t t = base + i;
    float a = attn[t * HEADS + h];
    float v = b2f(vb[t * INNER + hd]);
    st = decay * st + om * a * v;
  }
  ends[((size_t)b * NCHUNK + c) * INNER + hd] = st;
}

__global__ __launch_bounds__(512) void scan_phase2(
    const float* __restrict__ ends, const float* __restrict__ alpha,
    float* __restrict__ carries) {
  int hd = threadIdx.x;
  int b = blockIdx.x;
  float decay = 1.f / (1.f + __expf(-alpha[hd]));
  float dL = __powf(decay, (float)CHLEN);
  float carry = 0.f;
#pragma unroll 8
  for (int c = 0; c < NCHUNK; c++) {
    size_t idx = ((size_t)b * NCHUNK + c) * INNER + hd;
    carries[idx] = carry;
    carry = dL * carry + ends[idx];
  }
}

__global__ __launch_bounds__(512) void scan_phase3(
    const u16* __restrict__ qb, const u16* __restrict__ vb,
    const float* __restrict__ attn, const float* __restrict__ alpha,
    const float* __restrict__ augp, const float* __restrict__ carries,
    u16* __restrict__ outpre) {
  int hd = threadIdx.x;
  int h = hd >> 6;
  int c = blockIdx.x, b = blockIdx.y;
  float decay = 1.f / (1.f + __expf(-alpha[hd]));
  float om = 1.f - decay;
  float ap = augp[hd];
  float st = carries[((size_t)b * NCHUNK + c) * INNER + hd];
  size_t base = (size_t)b * SEQ + (size_t)c * CHLEN;
#pragma unroll 4
  for (int i = 0; i < CHLEN; i++) {
    size_t t = base + i;
    float a = attn[t * HEADS + h];
    float v = b2f(vb[t * INNER + hd]);
    st = decay * st + om * a * v;
    float q = b2f(qb[t * INNER + hd]);
    float aug = 1.f / (1.f + __expf(-q * ap));
    outpre[t * INNER + hd] = f2b(q * st + aug);
  }
}

// ---------------- LayerNorm (in place) ----------------
__global__ __launch_bounds__(256) void ln_kernel(
    float* __restrict__ out, const float* __restrict__ lns,
    const float* __restrict__ lnb) {
  size_t row = blockIdx.x;
  int tid = threadIdx.x;
  float4 v = *(float4*)(out + row * HIDDEN + tid * 4);
  float s = v.x + v.y + v.z + v.w;
  float ss = v.x * v.x + v.y * v.y + v.z * v.z + v.w * v.w;
#pragma unroll
  for (int m = 1; m < 64; m <<= 1) {
    s += __shfl_xor(s, m);
    ss += __shfl_xor(ss, m);
  }
  __shared__ float sb[4], ssb[4];
  int lane = tid & 63, wid = tid >> 6;
  if (lane == 0) {
    sb[wid] = s;
    ssb[wid] = ss;
  }
  __syncthreads();
  s = sb[0] + sb[1] + sb[2] + sb[3];
  ss = ssb[0] + ssb[1] + ssb[2] + ssb[3];
  float mean = s * (1.f / HIDDEN);
  float var = ss * (1.f / HIDDEN) - mean * mean;
  float rstd = rsqrtf(var + 1e-6f);
  float4 sc = *(const float4*)(lns + tid * 4);
  float4 bi = *(const float4*)(lnb + tid * 4);
  v.x = (v.x - mean) * rstd * sc.x + bi.x;
  v.y = (v.y - mean) * rstd * sc.y + bi.y;
  v.z = (v.z - mean) * rstd * sc.z + bi.z;
  v.w = (v.w - mean) * rstd * sc.w + bi.w;
  *(float4*)(out + row * HIDDEN + tid * 4) = v;
}

extern "C" void kernel_launch(void* const* d_in, const int* in_sizes, int n_in,
                              void* d_out, int out_size, void* d_ws, size_t ws_size,
                              hipStream_t stream) {
  const float* x = (const float*)d_in[0];
  const float* Wq = (const float*)d_in[1];
  const float* bq = (const float*)d_in[2];
  const float* Wk = (const float*)d_in[3];
  const float* bk = (const float*)d_in[4];
  const float* Wv = (const float*)d_in[5];
  const float* bv = (const float*)d_in[6];
  const float* Wo = (const float*)d_in[7];
  const float* bo = (const float*)d_in[8];
  const float* alpha = (const float*)d_in[9];
  const float* augp = (const float*)d_in[10];
  const float* lns = (const float*)d_in[11];
  const float* lnb = (const float*)d_in[12];

  char* ws = (char*)d_ws;
  const bool fast = ws_size >= 175118336ull;

  if (fast) {
    u16* xb = (u16*)(ws + 0);                 // 67.1 MB
    u16* qb = (u16*)(ws + 67108864);          // 33.5 MB
    u16* kb = (u16*)(ws + 100663296);         // 33.5 MB (reused as outpre)
    u16* vb = (u16*)(ws + 134217728);         // 33.5 MB
    u16* Wt = (u16*)(ws + 167772160);         // 3 MB, [1536][1024]
    u16* Wot = (u16*)(ws + 170917888);        // 1 MB, [1024][512]
    float* bcat = (float*)(ws + 171966464);   // 6 KB
    float* attn = (float*)(ws + 171972608);   // 1 MB
    float* ends = (float*)(ws + 173021184);   // 1 MB
    float* car = (float*)(ws + 174069760);    // 1 MB
    u16* outpre = kb;

    prep_x<<<ROWS * HIDDEN / 8 / 256, 256, 0, stream>>>(x, xb);
    prep_w<<<8192, 256, 0, stream>>>(Wq, Wk, Wv, Wo, bq, bk, bv, Wt, Wot, bcat);

    // QKV: M=32768, N=1536 -> 128*6 = 768 blocks of 512 thr
    gemm_ring<HIDDEN, false, true><<<768, 512, 0, stream>>>(
        xb, Wt, bcat, qb, kb, vb, 6);

    attn_kernel<<<ROWS / 4, 256, 0, stream>>>(qb, kb, attn);
    scan_phase1<<<dim3(NCHUNK, BATCH), 512, 0, stream>>>(vb, attn, alpha, ends);
    scan_phase2<<<BATCH, 512, 0, stream>>>(ends, alpha, car);
    scan_phase3<<<dim3(NCHUNK, BATCH), 512, 0, stream>>>(qb, vb, attn, alpha, augp, car, outpre);

    // out: M=32768, N=1024 -> 128*4 = 512 blocks
    gemm_ring<INNER, true, false><<<512, 512, 0, stream>>>(
        outpre, Wot, bo, d_out, d_out, d_out, 4);

    ln_kernel<<<ROWS, 256, 0, stream>>>((float*)d_out, lns, lnb);
  } else {
    // round-1 proven layout (108 MB)
    u16* qb = (u16*)(ws + 0);
    u16* kb = (u16*)(ws + 33554432);
    u16* vb = (u16*)(ws + 67108864);
    u16* Wt = (u16*)(ws + 100663296);
    u16* Wot = (u16*)(ws + 103809024);
    float* bcat = (float*)(ws + 104845312);
    float* attn = (float*)(ws + 104857600);
    float* ends = (float*)(ws + 105906176);
    float* car = (float*)(ws + 106954752);
    u16* outpre = kb;

    prep_w<<<8192, 256, 0, stream>>>(Wq, Wk, Wv, Wo, bq, bk, bv, Wt, Wot, bcat);
    gemm128<false, false><<<dim3(4, 256, 3), 256, 0, stream>>>(
        x, Wt, bq, bk, bv, qb, kb, vb, HIDDEN);
    attn_kernel<<<ROWS / 4, 256, 0, stream>>>(qb, kb, attn);
    scan_phase1<<<dim3(NCHUNK, BATCH), 512, 0, stream>>>(vb, attn, alpha, ends);
    scan_phase2<<<BATCH, 512, 0, stream>>>(ends, alpha, car);
    scan_phase3<<<dim3(NCHUNK, BATCH), 512, 0, stream>>>(qb, vb, attn, alpha, augp, car, outpre);
    gemm_ring<INNER, true, false><<<512, 512, 0, stream>>>(
        outpre, Wot, bo, d_out, d_out, d_out, 4);
    ln_kernel<<<ROWS, 256, 0, stream>>>((float*)d_out, lns, lnb);
  }
}

// Round 6
// 320.343 us; speedup vs baseline: 1.3164x; 1.0118x over previous
//
#include <hip/hip_runtime.h>
#include <hip/hip_bf16.h>

// MetaLA fused pipeline, round 6.
//  gemm_8ph: 256x256 tile, BK=32, 8 waves (2Mx4N), 4-slot LDS ring (4x32KB),
//            fine-grained 2-phase-per-tile schedule (m201-style):
//            per phase {ds_read frag subset || 2 global_load_lds of tile t+3}
//            -> barrier -> lgkmcnt(0) -> setprio(1) 16 MFMA setprio(0) -> barrier.
//            vmcnt for tile t+1 sits in tile t's last phase (counted 8/4/0, never
//            drains in steady state). 2-way-free XOR swizzle chunk^=(row>>1)&3.
//  prep_x/prep_w/attn/scan/ln unchanged.

#define HIDDEN 1024
#define HEADS 8
#define HDIM 64
#define INNER 512
#define BATCH 4
#define SEQ 8192
#define ROWS (BATCH*SEQ)
#define NCHUNK 128
#define CHLEN 64

typedef unsigned short u16;
typedef unsigned int u32;
typedef __attribute__((ext_vector_type(8))) short bf16x8;
typedef __attribute__((ext_vector_type(4))) float f32x4;

__device__ __forceinline__ float b2f(u16 u) { return __uint_as_float(((u32)u) << 16); }
__device__ __forceinline__ u16 f2b(float f) {
  u32 u = __float_as_uint(f);
  u32 r = u + 0x7fffu + ((u >> 16) & 1u);  // RNE
  return (u16)(r >> 16);
}
__device__ __forceinline__ u32 pack2(float a, float b) {
  return (u32)f2b(a) | ((u32)f2b(b) << 16);
}

#define GLOAD_LDS16(gp, lp)                                                  \
  __builtin_amdgcn_global_load_lds(                                          \
      (const __attribute__((address_space(1))) u32*)(gp),                    \
      (__attribute__((address_space(3))) u32*)(lp), 16, 0, 0)

// ---------------- prep_x: fp32 -> bf16 ----------------
__global__ __launch_bounds__(256) void prep_x(const float* __restrict__ x,
                                              u16* __restrict__ xb) {
  size_t i = ((size_t)blockIdx.x * 256 + threadIdx.x) * 8;
  float4 a = *(const float4*)(x + i);
  float4 b = *(const float4*)(x + i + 4);
  uint4 w = {pack2(a.x, a.y), pack2(a.z, a.w), pack2(b.x, b.y), pack2(b.z, b.w)};
  *(uint4*)(xb + i) = w;
}

// ---------------- prep_w: weight transpose/convert + bias concat ----------------
__global__ __launch_bounds__(256) void prep_w(
    const float* __restrict__ Wq, const float* __restrict__ Wk,
    const float* __restrict__ Wv, const float* __restrict__ Wo,
    const float* __restrict__ bq, const float* __restrict__ bk,
    const float* __restrict__ bv,
    u16* __restrict__ Wt, u16* __restrict__ Wot, float* __restrict__ bcat) {
  const int WELEM = HIDDEN * INNER;  // 524288
  int idx = blockIdx.x * 256 + threadIdx.x;
  if (idx < 3 * WELEM) {
    int z = idx / WELEM;
    int rem = idx - z * WELEM;  // n*1024 + k
    int n = rem >> 10;
    int k = rem & 1023;
    const float* W = (z == 0) ? Wq : (z == 1) ? Wk : Wv;
    Wt[idx] = f2b(W[k * INNER + n]);
  } else {
    int rem = idx - 3 * WELEM;  // n*512 + k
    int n = rem >> 9;
    int k = rem & 511;
    Wot[rem] = f2b(Wo[k * HIDDEN + n]);
  }
  if (idx < 3 * INNER) {
    int z = idx >> 9;
    int n = idx & 511;
    bcat[idx] = (z == 0) ? bq[n] : (z == 1) ? bk[n] : bv[n];
  }
}

// ---------------- gemm_8ph: 256x256, BK=32, 4-slot ring, fine phases ----------------
// A: [M][K] bf16, Bt: [N][K] bf16 (row n = output col), out = A@Bt^T + bias.
// SPLIT3: N=1536, route 512-col groups to out0/1/2 (bf16 [M][512]); else out0 fp32 [M][N].
template <int K, bool OUT_F32, bool SPLIT3>
__global__ __launch_bounds__(512, 2) void gemm_8ph(
    const u16* __restrict__ A, const u16* __restrict__ Bt,
    const float* __restrict__ bias,
    void* __restrict__ out0, void* __restrict__ out1, void* __restrict__ out2,
    int nTilesN) {
  constexpr int NT = K / 32;  // K-tiles; >= 4
  // slot: A 256x32 swizzled (8192 u16) | B 256x32 swizzled (8192 u16) = 32KB
  __shared__ u16 lds[4][16384];

  // bijective XCD-chunked swizzle (nwg % 8 == 0); consecutive lin share A-panel
  const int nwg = gridDim.x;
  const int chunk = nwg >> 3;
  const int bid = blockIdx.x;
  const int lin = (bid & 7) * chunk + (bid >> 3);
  const int nt = lin % nTilesN;
  const int mt = lin / nTilesN;
  const int m0 = mt * 256, n0 = nt * 256;
  const int N = nTilesN * 256;

  const int tid = threadIdx.x;
  const int lane = tid & 63;
  const int w = tid >> 6;   // 0..7
  const int wm = w >> 2;    // 0..1  (M half: 128 rows)
  const int wn = w & 3;     // 0..3  (N quarter: 64 cols)
  const int r16 = lane & 15, kq = lane >> 4;

  // ---- staging geometry (pre-swizzled global source, linear LDS dest) ----
  // round r covers rows [r*128,+128): thread t -> linear u16 = r*4096 + t*8
  // -> row = r*128 + t/4, chunk = t&3; stored elem = global (row, (chunk^((row>>1)&3))*8).
  const int rt = tid >> 2;                            // row within round
  const int cg = (((tid & 3) << 3)) ^ (((rt >> 1) & 3) << 3);
  const u16* Ag = A + (size_t)(m0 + rt) * K + cg;
  const u16* Bg = Bt + (size_t)(n0 + rt) * K + cg;
  const int ldst = w * 512;  // wave-uniform; HW adds lane*16B

#define STAGE_A(slot, kt)                                                     \
  {                                                                           \
    GLOAD_LDS16(Ag + (size_t)(kt) * 32, &lds[slot][ldst]);                    \
    GLOAD_LDS16(Ag + (size_t)(kt) * 32 + (size_t)128 * K,                     \
                &lds[slot][4096 + ldst]);                                     \
  }
#define STAGE_B(slot, kt)                                                     \
  {                                                                           \
    GLOAD_LDS16(Bg + (size_t)(kt) * 32, &lds[slot][8192 + ldst]);             \
    GLOAD_LDS16(Bg + (size_t)(kt) * 32 + (size_t)128 * K,                     \
                &lds[slot][12288 + ldst]);                                    \
  }

  // ---- read-side swizzled offsets: elem (row,c) at row*32 + (c ^ (((row>>1)&3)<<3)) ----
  const int xk = (kq << 3) ^ (((r16 >> 1) & 3) << 3);
  const int aO = (wm * 128 + r16) * 32 + xk;          // + i*512
  const int bO = 8192 + (wn * 64 + r16) * 32 + xk;    // + j*512

  f32x4 acc[8][4] = {};
  bf16x8 af[4], bfv[4];

  // phase 0 of tile t: read A frags 0-3 + all B frags; stage A-half of t+3; MFMA i=0..3
#define PH0(t_, STG)                                                           \
  {                                                                            \
    const u16* sl = &lds[(t_) & 3][0];                                         \
    _Pragma("unroll") for (int i = 0; i < 4; i++)                              \
        af[i] = *(const bf16x8*)&sl[aO + i * 512];                             \
    _Pragma("unroll") for (int j = 0; j < 4; j++)                              \
        bfv[j] = *(const bf16x8*)&sl[bO + j * 512];                            \
    STG;                                                                       \
    __builtin_amdgcn_sched_barrier(0);                                         \
    __builtin_amdgcn_s_barrier();                                              \
    asm volatile("s_waitcnt lgkmcnt(0)" ::: "memory");                         \
    __builtin_amdgcn_sched_barrier(0);                                         \
    __builtin_amdgcn_s_setprio(1);                                             \
    _Pragma("unroll") for (int i = 0; i < 4; i++)                              \
        _Pragma("unroll") for (int j = 0; j < 4; j++)                          \
            acc[i][j] =                                                        \
        __builtin_amdgcn_mfma_f32_16x16x32_bf16(af[i], bfv[j], acc[i][j], 0, 0, 0); \
    __builtin_amdgcn_s_setprio(0);                                             \
    __builtin_amdgcn_sched_barrier(0);                                         \
    __builtin_amdgcn_s_barrier();                                              \
  }

  // phase 1 of tile t: read A frags 4-7 (B reused from regs); stage B-half of t+3;
  // vmcnt(VM) guarantees tile t+1 landed before the barrier; MFMA i=4..7
#define PH1(t_, STG, VM)                                                       \
  {                                                                            \
    const u16* sl = &lds[(t_) & 3][0];                                         \
    _Pragma("unroll") for (int i = 0; i < 4; i++)                              \
        af[i] = *(const bf16x8*)&sl[aO + (i + 4) * 512];                       \
    STG;                                                                       \
    asm volatile("s_waitcnt vmcnt(" #VM ")" ::: "memory");                     \
    __builtin_amdgcn_sched_barrier(0);                                         \
    __builtin_amdgcn_s_barrier();                                              \
    asm volatile("s_waitcnt lgkmcnt(0)" ::: "memory");                         \
    __builtin_amdgcn_sched_barrier(0);                                         \
    __builtin_amdgcn_s_setprio(1);                                             \
    _Pragma("unroll") for (int i = 0; i < 4; i++)                              \
        _Pragma("unroll") for (int j = 0; j < 4; j++)                          \
            acc[i + 4][j] =                                                    \
        __builtin_amdgcn_mfma_f32_16x16x32_bf16(af[i], bfv[j], acc[i + 4][j], 0, 0, 0); \
    __builtin_amdgcn_s_setprio(0);                                             \
    __builtin_amdgcn_sched_barrier(0);                                         \
    __builtin_amdgcn_s_barrier();                                              \
  }

#define NOSTG ((void)0)

  // prologue: stage tiles 0,1,2 (12 loads); ensure tile 0 landed (8 newest remain)
  STAGE_A(0, 0); STAGE_B(0, 0);
  STAGE_A(1, 1); STAGE_B(1, 1);
  STAGE_A(2, 2); STAGE_B(2, 2);
  asm volatile("s_waitcnt vmcnt(8)" ::: "memory");
  __builtin_amdgcn_sched_barrier(0);
  __builtin_amdgcn_s_barrier();

  // steady state: stage tile t+3 (A in ph0, B in ph1); vmcnt(8) drains tile t+1
  for (int t = 0; t < NT - 3; ++t) {
    PH0(t, STAGE_A((t + 3) & 3, t + 3));
    PH1(t, STAGE_B((t + 3) & 3, t + 3), 8);
  }
  // tail: tiles NT-3, NT-2, NT-1 (no staging; counted drains 4 -> 0)
  PH0(NT - 3, NOSTG);
  PH1(NT - 3, NOSTG, 4);
  PH0(NT - 2, NOSTG);
  PH1(NT - 2, NOSTG, 0);
  PH0(NT - 1, NOSTG);
  PH1(NT - 1, NOSTG, 0);
#undef PH0
#undef PH1
#undef NOSTG
#undef STAGE_A
#undef STAGE_B

  // ---- epilogue: C/D layout col=lane&15, row=(lane>>4)*4+reg  [m89/m91] ----
  const int zsel = SPLIT3 ? ((n0 + wn * 64) >> 9) : 0;
  u16* ob16 = (u16*)((zsel == 0) ? out0 : (zsel == 1) ? out1 : out2);
#pragma unroll
  for (int j = 0; j < 4; j++) {
    int col = n0 + wn * 64 + j * 16 + r16;
    float bv = bias[col];
    int colm = SPLIT3 ? (col & 511) : col;
#pragma unroll
    for (int i = 0; i < 8; i++) {
#pragma unroll
      for (int q = 0; q < 4; q++) {
        int row = m0 + wm * 128 + i * 16 + kq * 4 + q;
        float v = acc[i][j][q] + bv;
        if (OUT_F32)
          ((float*)out0)[(size_t)row * N + col] = v;
        else
          ob16[(size_t)row * INNER + colm] = f2b(v);
      }
    }
  }
}

// ---------------- legacy 128^2 GEMM (fp32 A staging) — small-ws fallback ----------------
template <bool A_BF16, bool OUT_F32>
__global__ __launch_bounds__(256) void gemm128(
    const void* __restrict__ Aany, const u16* __restrict__ BtBase,
    const float* __restrict__ bias0, const float* __restrict__ bias1,
    const float* __restrict__ bias2,
    void* __restrict__ out0, void* __restrict__ out1, void* __restrict__ out2,
    int K) {
  __shared__ u16 As[128 * 32];
  __shared__ u16 Bs[128 * 32];
  const int N = gridDim.x * 128;
  const int z = blockIdx.z;
  const u16* Bt = BtBase + (size_t)z * N * K;
  const float* bias = (z == 0) ? bias0 : (z == 1) ? bias1 : bias2;
  void* Out = (z == 0) ? out0 : (z == 1) ? out1 : out2;
  const int tid = threadIdx.x;
  const int m0 = blockIdx.y * 128;
  const int n0 = blockIdx.x * 128;
  const int lane = tid & 63;
  const int wid = tid >> 6;
  const int wm = wid >> 1, wn = wid & 1;
  const int r16 = lane & 15, kq = lane >> 4;
  const int r = tid >> 1;
  const int half = tid & 1;
  f32x4 acc[4][4] = {};
  for (int k0 = 0; k0 < K; k0 += 32) {
    __syncthreads();
    if (A_BF16) {
      const u16* Ab = (const u16*)Aany;
      const int4* src = (const int4*)(Ab + (size_t)(m0 + r) * K + k0 + half * 16);
      int4 v0 = src[0];
      int4 v1 = src[1];
      *(int4*)&As[r * 32 + half * 16] = v0;
      *(int4*)&As[r * 32 + half * 16 + 8] = v1;
    } else {
      const float* Af = (const float*)Aany;
      const float4* src = (const float4*)(Af + (size_t)(m0 + r) * K + k0 + half * 16);
      float4 f0 = src[0], f1 = src[1], f2 = src[2], f3 = src[3];
      uint4 w0 = {pack2(f0.x, f0.y), pack2(f0.z, f0.w), pack2(f1.x, f1.y), pack2(f1.z, f1.w)};
      uint4 w1 = {pack2(f2.x, f2.y), pack2(f2.z, f2.w), pack2(f3.x, f3.y), pack2(f3.z, f3.w)};
      *(uint4*)&As[r * 32 + half * 16] = w0;
      *(uint4*)&As[r * 32 + half * 16 + 8] = w1;
    }
    {
      const int4* src = (const int4*)(Bt + (size_t)(n0 + r) * K + k0 + half * 16);
      int4 v0 = src[0];
      int4 v1 = src[1];
      *(int4*)&Bs[r * 32 + half * 16] = v0;
      *(int4*)&Bs[r * 32 + half * 16 + 8] = v1;
    }
    __syncthreads();
    bf16x8 a[4], b[4];
#pragma unroll
    for (int i = 0; i < 4; i++)
      a[i] = *(const bf16x8*)&As[(wm * 64 + i * 16 + r16) * 32 + kq * 8];
#pragma unroll
    for (int j = 0; j < 4; j++)
      b[j] = *(const bf16x8*)&Bs[(wn * 64 + j * 16 + r16) * 32 + kq * 8];
#pragma unroll
    for (int i = 0; i < 4; i++)
#pragma unroll
      for (int j = 0; j < 4; j++)
        acc[i][j] = __builtin_amdgcn_mfma_f32_16x16x32_bf16(a[i], b[j], acc[i][j], 0, 0, 0);
  }
#pragma unroll
  for (int j = 0; j < 4; j++) {
    int col = n0 + wn * 64 + j * 16 + r16;
    float bv = bias[col];
#pragma unroll
    for (int i = 0; i < 4; i++) {
#pragma unroll
      for (int q = 0; q < 4; q++) {
        int row = m0 + wm * 64 + i * 16 + kq * 4 + q;
        float v = acc[i][j][q] + bv;
        if (OUT_F32)
          ((float*)Out)[(size_t)row * N + col] = v;
        else
          ((u16*)Out)[(size_t)row * N + col] = f2b(v);
      }
    }
  }
}

// ---------------- attn: softmax over heads of (q.k)/8 ----------------
__global__ __launch_bounds__(256) void attn_kernel(
    const u16* __restrict__ qb, const u16* __restrict__ kb,
    float* __restrict__ attn) {
  int lane = threadIdx.x & 63;
  int wid = threadIdx.x >> 6;
  size_t t = (size_t)blockIdx.x * 4 + wid;
  int4 qv = *(const int4*)(qb + t * INNER + lane * 8);
  int4 kv = *(const int4*)(kb + t * INNER + lane * 8);
  const u16* qu = (const u16*)&qv;
  const u16* ku = (const u16*)&kv;
  float s = 0.f;
#pragma unroll
  for (int j = 0; j < 8; j++) s += b2f(qu[j]) * b2f(ku[j]);
  s += __shfl_xor(s, 1);
  s += __shfl_xor(s, 2);
  s += __shfl_xor(s, 4);
  s *= 0.125f;
  float mx = s;
  mx = fmaxf(mx, __shfl_xor(mx, 8));
  mx = fmaxf(mx, __shfl_xor(mx, 16));
  mx = fmaxf(mx, __shfl_xor(mx, 32));
  float e = __expf(s - mx);
  float sm = e;
  sm += __shfl_xor(sm, 8);
  sm += __shfl_xor(sm, 16);
  sm += __shfl_xor(sm, 32);
  float a = e / sm;
  if ((lane & 7) == 0) attn[t * HEADS + (lane >> 3)] = a;
}

// ---------------- scan ----------------
__global__ __launch_bounds__(512) void scan_phase1(
    const u16* __restrict__ vb, const float* __restrict__ attn,
    const float* __restrict__ alpha, float* __restrict__ ends) {
  int hd = threadIdx.x;
  int h = hd >> 6;
  int c = blockIdx.x, b = blockIdx.y;
  float decay = 1.f / (1.f + __expf(-alpha[hd]));
  float om = 1.f - decay;
  size_t base = (size_t)b * SEQ + (size_t)c * CHLEN;
  float st = 0.f;
#pragma unroll 8
  for (int i = 0; i < CHLEN; i++) {
    size_t t = base + i;
    float a = attn[t * HEADS + h];
    float v = b2f(vb[t * INNER + hd]);
    st = decay * st + om * a * v;
  }
  ends[((size_t)b * NCHUNK + c) * INNER + hd] = st;
}

__global__ __launch_bounds__(512) void scan_phase2(
    const float* __restrict__ ends, const float* __restrict__ alpha,
    float* __restrict__ carries) {
  int hd = threadIdx.x;
  int b = blockIdx.x;
  float decay = 1.f / (1.f + __expf(-alpha[hd]));
  float dL = __powf(decay, (float)CHLEN);
  float carry = 0.f;
#pragma unroll 8
  for (int c = 0; c < NCHUNK; c++) {
    size_t idx = ((size_t)b * NCHUNK + c) * INNER + hd;
    carries[idx] = carry;
    carry = dL * carry + ends[idx];
  }
}

__global__ __launch_bounds__(512) void scan_phase3(
    const u16* __restrict__ qb, const u16* __restrict__ vb,
    const float* __restrict__ attn, const float* __restrict__ alpha,
    const float* __restrict__ augp, const float* __restrict__ carries,
    u16* __restrict__ outpre) {
  int hd = threadIdx.x;
  int h = hd >> 6;
  int c = blockIdx.x, b = blockIdx.y;
  float decay = 1.f / (1.f + __expf(-alpha[hd]));
  float om = 1.f - decay;
  float ap = augp[hd];
  float st = carries[((size_t)b * NCHUNK + c) * INNER + hd];
  size_t base = (size_t)b * SEQ + (size_t)c * CHLEN;
#pragma unroll 4
  for (int i = 0; i < CHLEN; i++) {
    size_t t = base + i;
    float a = attn[t * HEADS + h];
    float v = b2f(vb[t * INNER + hd]);
    st = decay * st + om * a * v;
    float q = b2f(qb[t * INNER + hd]);
    float aug = 1.f / (1.f + __expf(-q * ap));
    outpre[t * INNER + hd] = f2b(q * st + aug);
  }
}

// ---------------- LayerNorm (in place) ----------------
__global__ __launch_bounds__(256) void ln_kernel(
    float* __restrict__ out, const float* __restrict__ lns,
    const float* __restrict__ lnb) {
  size_t row = blockIdx.x;
  int tid = threadIdx.x;
  float4 v = *(float4*)(out + row * HIDDEN + tid * 4);
  float s = v.x + v.y + v.z + v.w;
  float ss = v.x * v.x + v.y * v.y + v.z * v.z + v.w * v.w;
#pragma unroll
  for (int m = 1; m < 64; m <<= 1) {
    s += __shfl_xor(s, m);
    ss += __shfl_xor(ss, m);
  }
  __shared__ float sb[4], ssb[4];
  int lane = tid & 63, wid = tid >> 6;
  if (lane == 0) {
    sb[wid] = s;
    ssb[wid] = ss;
  }
  __syncthreads();
  s = sb[0] + sb[1] + sb[2] + sb[3];
  ss = ssb[0] + ssb[1] + ssb[2] + ssb[3];
  float mean = s * (1.f / HIDDEN);
  float var = ss * (1.f / HIDDEN) - mean * mean;
  float rstd = rsqrtf(var + 1e-6f);
  float4 sc = *(const float4*)(lns + tid * 4);
  float4 bi = *(const float4*)(lnb + tid * 4);
  v.x = (v.x - mean) * rstd * sc.x + bi.x;
  v.y = (v.y - mean) * rstd * sc.y + bi.y;
  v.z = (v.z - mean) * rstd * sc.z + bi.z;
  v.w = (v.w - mean) * rstd * sc.w + bi.w;
  *(float4*)(out + row * HIDDEN + tid * 4) = v;
}

extern "C" void kernel_launch(void* const* d_in, const int* in_sizes, int n_in,
                              void* d_out, int out_size, void* d_ws, size_t ws_size,
                              hipStream_t stream) {
  const float* x = (const float*)d_in[0];
  const float* Wq = (const float*)d_in[1];
  const float* bq = (const float*)d_in[2];
  const float* Wk = (const float*)d_in[3];
  const float* bk = (const float*)d_in[4];
  const float* Wv = (const float*)d_in[5];
  const float* bv = (const float*)d_in[6];
  const float* Wo = (const float*)d_in[7];
  const float* bo = (const float*)d_in[8];
  const float* alpha = (const float*)d_in[9];
  const float* augp = (const float*)d_in[10];
  const float* lns = (const float*)d_in[11];
  const float* lnb = (const float*)d_in[12];

  char* ws = (char*)d_ws;
  const bool fast = ws_size >= 175118336ull;

  if (fast) {
    u16* xb = (u16*)(ws + 0);                 // 67.1 MB
    u16* qb = (u16*)(ws + 67108864);          // 33.5 MB
    u16* kb = (u16*)(ws + 100663296);         // 33.5 MB (reused as outpre)
    u16* vb = (u16*)(ws + 134217728);         // 33.5 MB
    u16* Wt = (u16*)(ws + 167772160);         // 3 MB, [1536][1024]
    u16* Wot = (u16*)(ws + 170917888);        // 1 MB, [1024][512]
    float* bcat = (float*)(ws + 171966464);   // 6 KB
    float* attn = (float*)(ws + 171972608);   // 1 MB
    float* ends = (float*)(ws + 173021184);   // 1 MB
    float* car = (float*)(ws + 174069760);    // 1 MB
    u16* outpre = kb;

    prep_x<<<ROWS * HIDDEN / 8 / 256, 256, 0, stream>>>(x, xb);
    prep_w<<<8192, 256, 0, stream>>>(Wq, Wk, Wv, Wo, bq, bk, bv, Wt, Wot, bcat);

    // QKV: M=32768, N=1536 -> 128*6 = 768 blocks of 512 thr
    gemm_8ph<HIDDEN, false, true><<<768, 512, 0, stream>>>(
        xb, Wt, bcat, qb, kb, vb, 6);

    attn_kernel<<<ROWS / 4, 256, 0, stream>>>(qb, kb, attn);
    scan_phase1<<<dim3(NCHUNK, BATCH), 512, 0, stream>>>(vb, attn, alpha, ends);
    scan_phase2<<<BATCH, 512, 0, stream>>>(ends, alpha, car);
    scan_phase3<<<dim3(NCHUNK, BATCH), 512, 0, stream>>>(qb, vb, attn, alpha, augp, car, outpre);

    // out: M=32768, N=1024 -> 128*4 = 512 blocks
    gemm_8ph<INNER, true, false><<<512, 512, 0, stream>>>(
        outpre, Wot, bo, d_out, d_out, d_out, 4);

    ln_kernel<<<ROWS, 256, 0, stream>>>((float*)d_out, lns, lnb);
  } else {
    // round-1 proven layout (108 MB)
    u16* qb = (u16*)(ws + 0);
    u16* kb = (u16*)(ws + 33554432);
    u16* vb = (u16*)(ws + 67108864);
    u16* Wt = (u16*)(ws + 100663296);
    u16* Wot = (u16*)(ws + 103809024);
    float* bcat = (float*)(ws + 104845312);
    float* attn = (float*)(ws + 104857600);
    float* ends = (float*)(ws + 105906176);
    float* car = (float*)(ws + 106954752);
    u16* outpre = kb;

    prep_w<<<8192, 256, 0, stream>>>(Wq, Wk, Wv, Wo, bq, bk, bv, Wt, Wot, bcat);
    gemm128<false, false><<<dim3(4, 256, 3), 256, 0, stream>>>(
        x, Wt, bq, bk, bv, qb, kb, vb, HIDDEN);
    attn_kernel<<<ROWS / 4, 256, 0, stream>>>(qb, kb, attn);
    scan_phase1<<<dim3(NCHUNK, BATCH), 512, 0, stream>>>(vb, attn, alpha, ends);
    scan_phase2<<<BATCH, 512, 0, stream>>>(ends, alpha, car);
    scan_phase3<<<dim3(NCHUNK, BATCH), 512, 0, stream>>>(qb, vb, attn, alpha, augp, car, outpre);
    gemm_8ph<INNER, true, false><<<512, 512, 0, stream>>>(
        outpre, Wot, bo, d_out, d_out, d_out, 4);
    ln_kernel<<<ROWS, 256, 0, stream>>>((float*)d_out, lns, lnb);
  }
}

// Round 7
// 278.769 us; speedup vs baseline: 1.5127x; 1.1491x over previous
//
#include <hip/hip_runtime.h>
#include <hip/hip_bf16.h>

// MetaLA fused pipeline, round 7.
//  gemm_8ph: 256x256 tile, BK=32, 4-slot LDS ring, fine 2-phase/tile schedule with
//            counted vmcnt (unchanged K-loop from R6). NEW: LDS-transpose epilogue ->
//            sector-dense coalesced bf16 stores (fixes ~2x HBM write amplification).
//  out-proj now writes bf16 (outln = dead xb); ln_kernel reads bf16, writes fp32 d_out.

#define HIDDEN 1024
#define HEADS 8
#define HDIM 64
#define INNER 512
#define BATCH 4
#define SEQ 8192
#define ROWS (BATCH*SEQ)
#define NCHUNK 128
#define CHLEN 64

typedef unsigned short u16;
typedef unsigned int u32;
typedef __attribute__((ext_vector_type(8))) short bf16x8;
typedef __attribute__((ext_vector_type(4))) float f32x4;

__device__ __forceinline__ float b2f(u16 u) { return __uint_as_float(((u32)u) << 16); }
__device__ __forceinline__ u16 f2b(float f) {
  u32 u = __float_as_uint(f);
  u32 r = u + 0x7fffu + ((u >> 16) & 1u);  // RNE
  return (u16)(r >> 16);
}
__device__ __forceinline__ u32 pack2(float a, float b) {
  return (u32)f2b(a) | ((u32)f2b(b) << 16);
}

#define GLOAD_LDS16(gp, lp)                                                  \
  __builtin_amdgcn_global_load_lds(                                          \
      (const __attribute__((address_space(1))) u32*)(gp),                    \
      (__attribute__((address_space(3))) u32*)(lp), 16, 0, 0)

// ---------------- prep_x: fp32 -> bf16 ----------------
__global__ __launch_bounds__(256) void prep_x(const float* __restrict__ x,
                                              u16* __restrict__ xb) {
  size_t i = ((size_t)blockIdx.x * 256 + threadIdx.x) * 8;
  float4 a = *(const float4*)(x + i);
  float4 b = *(const float4*)(x + i + 4);
  uint4 w = {pack2(a.x, a.y), pack2(a.z, a.w), pack2(b.x, b.y), pack2(b.z, b.w)};
  *(uint4*)(xb + i) = w;
}

// ---------------- prep_w: weight transpose/convert + bias concat ----------------
__global__ __launch_bounds__(256) void prep_w(
    const float* __restrict__ Wq, const float* __restrict__ Wk,
    const float* __restrict__ Wv, const float* __restrict__ Wo,
    const float* __restrict__ bq, const float* __restrict__ bk,
    const float* __restrict__ bv,
    u16* __restrict__ Wt, u16* __restrict__ Wot, float* __restrict__ bcat) {
  const int WELEM = HIDDEN * INNER;  // 524288
  int idx = blockIdx.x * 256 + threadIdx.x;
  if (idx < 3 * WELEM) {
    int z = idx / WELEM;
    int rem = idx - z * WELEM;  // n*1024 + k
    int n = rem >> 10;
    int k = rem & 1023;
    const float* W = (z == 0) ? Wq : (z == 1) ? Wk : Wv;
    Wt[idx] = f2b(W[k * INNER + n]);
  } else {
    int rem = idx - 3 * WELEM;  // n*512 + k
    int n = rem >> 9;
    int k = rem & 511;
    Wot[rem] = f2b(Wo[k * HIDDEN + n]);
  }
  if (idx < 3 * INNER) {
    int z = idx >> 9;
    int n = idx & 511;
    bcat[idx] = (z == 0) ? bq[n] : (z == 1) ? bk[n] : bv[n];
  }
}

// ---------------- gemm_8ph: 256x256, BK=32, 4-slot ring, fine phases ----------------
// A: [M][K] bf16, Bt: [N][K] bf16 (row n = output col), out = A@Bt^T + bias (bf16 out).
// SPLIT3: N=1536, route 512-col groups to out0/1/2 ([M][512] bf16); else out0 [M][N] bf16.
template <int K, bool SPLIT3>
__global__ __launch_bounds__(512, 2) void gemm_8ph(
    const u16* __restrict__ A, const u16* __restrict__ Bt,
    const float* __restrict__ bias,
    void* __restrict__ out0, void* __restrict__ out1, void* __restrict__ out2,
    int nTilesN) {
  constexpr int NT = K / 32;  // K-tiles; >= 4
  // slot: A 256x32 swizzled (8192 u16) | B 256x32 swizzled (8192 u16) = 32KB
  __shared__ u16 lds[4][16384];

  // bijective XCD-chunked swizzle (nwg % 8 == 0); consecutive lin share A-panel
  const int nwg = gridDim.x;
  const int chunk = nwg >> 3;
  const int bid = blockIdx.x;
  const int lin = (bid & 7) * chunk + (bid >> 3);
  const int nt = lin % nTilesN;
  const int mt = lin / nTilesN;
  const int m0 = mt * 256, n0 = nt * 256;
  const int N = nTilesN * 256;

  const int tid = threadIdx.x;
  const int lane = tid & 63;
  const int w = tid >> 6;   // 0..7
  const int wm = w >> 2;    // 0..1  (M half: 128 rows)
  const int wn = w & 3;     // 0..3  (N quarter: 64 cols)
  const int r16 = lane & 15, kq = lane >> 4;

  // ---- staging geometry (pre-swizzled global source, linear LDS dest) ----
  const int rt = tid >> 2;                            // row within round
  const int cg = (((tid & 3) << 3)) ^ (((rt >> 1) & 3) << 3);
  const u16* Ag = A + (size_t)(m0 + rt) * K + cg;
  const u16* Bg = Bt + (size_t)(n0 + rt) * K + cg;
  const int ldst = w * 512;  // wave-uniform; HW adds lane*16B

#define STAGE_A(slot, kt)                                                     \
  {                                                                           \
    GLOAD_LDS16(Ag + (size_t)(kt) * 32, &lds[slot][ldst]);                    \
    GLOAD_LDS16(Ag + (size_t)(kt) * 32 + (size_t)128 * K,                     \
                &lds[slot][4096 + ldst]);                                     \
  }
#define STAGE_B(slot, kt)                                                     \
  {                                                                           \
    GLOAD_LDS16(Bg + (size_t)(kt) * 32, &lds[slot][8192 + ldst]);             \
    GLOAD_LDS16(Bg + (size_t)(kt) * 32 + (size_t)128 * K,                     \
                &lds[slot][12288 + ldst]);                                    \
  }

  // ---- read-side swizzled offsets: elem (row,c) at row*32 + (c ^ (((row>>1)&3)<<3)) ----
  const int xk = (kq << 3) ^ (((r16 >> 1) & 3) << 3);
  const int aO = (wm * 128 + r16) * 32 + xk;          // + i*512
  const int bO = 8192 + (wn * 64 + r16) * 32 + xk;    // + j*512

  f32x4 acc[8][4] = {};
  bf16x8 af[4], bfv[4];

#define PH0(t_, STG)                                                           \
  {                                                                            \
    const u16* sl = &lds[(t_) & 3][0];                                         \
    _Pragma("unroll") for (int i = 0; i < 4; i++)                              \
        af[i] = *(const bf16x8*)&sl[aO + i * 512];                             \
    _Pragma("unroll") for (int j = 0; j < 4; j++)                              \
        bfv[j] = *(const bf16x8*)&sl[bO + j * 512];                            \
    STG;                                                                       \
    __builtin_amdgcn_sched_barrier(0);                                         \
    __builtin_amdgcn_s_barrier();                                              \
    asm volatile("s_waitcnt lgkmcnt(0)" ::: "memory");                         \
    __builtin_amdgcn_sched_barrier(0);                                         \
    __builtin_amdgcn_s_setprio(1);                                             \
    _Pragma("unroll") for (int i = 0; i < 4; i++)                              \
        _Pragma("unroll") for (int j = 0; j < 4; j++)                          \
            acc[i][j] =                                                        \
        __builtin_amdgcn_mfma_f32_16x16x32_bf16(af[i], bfv[j], acc[i][j], 0, 0, 0); \
    __builtin_amdgcn_s_setprio(0);                                             \
    __builtin_amdgcn_sched_barrier(0);                                         \
    __builtin_amdgcn_s_barrier();                                              \
  }

#define PH1(t_, STG, VM)                                                       \
  {                                                                            \
    const u16* sl = &lds[(t_) & 3][0];                                         \
    _Pragma("unroll") for (int i = 0; i < 4; i++)                              \
        af[i] = *(const bf16x8*)&sl[aO + (i + 4) * 512];                       \
    STG;                                                                       \
    asm volatile("s_waitcnt vmcnt(" #VM ")" ::: "memory");                     \
    __builtin_amdgcn_sched_barrier(0);                                         \
    __builtin_amdgcn_s_barrier();                                              \
    asm volatile("s_waitcnt lgkmcnt(0)" ::: "memory");                         \
    __builtin_amdgcn_sched_barrier(0);                                         \
    __builtin_amdgcn_s_setprio(1);                                             \
    _Pragma("unroll") for (int i = 0; i < 4; i++)                              \
        _Pragma("unroll") for (int j = 0; j < 4; j++)                          \
            acc[i + 4][j] =                                                    \
        __builtin_amdgcn_mfma_f32_16x16x32_bf16(af[i], bfv[j], acc[i + 4][j], 0, 0, 0); \
    __builtin_amdgcn_s_setprio(0);                                             \
    __builtin_amdgcn_sched_barrier(0);                                         \
    __builtin_amdgcn_s_barrier();                                              \
  }

#define NOSTG ((void)0)

  // prologue: stage tiles 0,1,2 (12 loads); ensure tile 0 landed (8 newest remain)
  STAGE_A(0, 0); STAGE_B(0, 0);
  STAGE_A(1, 1); STAGE_B(1, 1);
  STAGE_A(2, 2); STAGE_B(2, 2);
  asm volatile("s_waitcnt vmcnt(8)" ::: "memory");
  __builtin_amdgcn_sched_barrier(0);
  __builtin_amdgcn_s_barrier();

  for (int t = 0; t < NT - 3; ++t) {
    PH0(t, STAGE_A((t + 3) & 3, t + 3));
    PH1(t, STAGE_B((t + 3) & 3, t + 3), 8);
  }
  PH0(NT - 3, NOSTG);
  PH1(NT - 3, NOSTG, 4);
  PH0(NT - 2, NOSTG);
  PH1(NT - 2, NOSTG, 0);
  PH0(NT - 1, NOSTG);
  PH1(NT - 1, NOSTG, 0);
#undef PH0
#undef PH1
#undef NOSTG
#undef STAGE_A
#undef STAGE_B

  // ---- epilogue: wave-local LDS transpose -> sector-dense coalesced bf16 stores ----
  // Final PH1 ends with s_barrier, so all LDS tile reads are complete; each wave now
  // owns a disjoint 16KB region (w*4096 floats). [32][68] f32 padded: 16B-aligned rows,
  // <=2-way bank aliasing on both sides (free, m136).
  float* fl = (float*)(&lds[0][0]) + w * 4096;
  const int zsel = SPLIT3 ? ((n0 + wn * 64) >> 9) : 0;
  u16* ob = SPLIT3 ? (u16*)((zsel == 0) ? out0 : (zsel == 1) ? out1 : out2)
                   : (u16*)out0;
  const int OC = SPLIT3 ? INNER : N;
  const int colloc = (lane & 7) * 8;
  const int gcol = (SPLIT3 ? ((n0 + wn * 64) & 511) : (n0 + wn * 64)) + colloc;
  const int lrowr = lane >> 3;
  float bvj[4];
#pragma unroll
  for (int j = 0; j < 4; j++) bvj[j] = bias[n0 + wn * 64 + j * 16 + r16];

#pragma unroll
  for (int pass = 0; pass < 4; ++pass) {
#pragma unroll
    for (int ii = 0; ii < 2; ++ii) {
#pragma unroll
      for (int j = 0; j < 4; ++j) {
#pragma unroll
        for (int q = 0; q < 4; ++q)
          fl[(ii * 16 + kq * 4 + q) * 68 + j * 16 + r16] =
              acc[pass * 2 + ii][j][q] + bvj[j];
      }
    }
#pragma unroll
    for (int inst = 0; inst < 4; ++inst) {
      int lr = inst * 8 + lrowr;
      float4 f0 = *(float4*)&fl[lr * 68 + colloc];
      float4 f1 = *(float4*)&fl[lr * 68 + colloc + 4];
      uint4 wv = {pack2(f0.x, f0.y), pack2(f0.z, f0.w),
                  pack2(f1.x, f1.y), pack2(f1.z, f1.w)};
      size_t grow = (size_t)(m0 + wm * 128 + pass * 32 + lr);
      *(uint4*)&ob[grow * OC + gcol] = wv;
    }
  }
}

// ---------------- legacy 128^2 GEMM (fp32 A staging) — small-ws fallback ----------------
template <bool A_BF16>
__global__ __launch_bounds__(256) void gemm128(
    const void* __restrict__ Aany, const u16* __restrict__ BtBase,
    const float* __restrict__ bias0, const float* __restrict__ bias1,
    const float* __restrict__ bias2,
    void* __restrict__ out0, void* __restrict__ out1, void* __restrict__ out2,
    int K) {
  __shared__ u16 As[128 * 32];
  __shared__ u16 Bs[128 * 32];
  const int N = gridDim.x * 128;
  const int z = blockIdx.z;
  const u16* Bt = BtBase + (size_t)z * N * K;
  const float* bias = (z == 0) ? bias0 : (z == 1) ? bias1 : bias2;
  void* Out = (z == 0) ? out0 : (z == 1) ? out1 : out2;
  const int tid = threadIdx.x;
  const int m0 = blockIdx.y * 128;
  const int n0 = blockIdx.x * 128;
  const int lane = tid & 63;
  const int wid = tid >> 6;
  const int wm = wid >> 1, wn = wid & 1;
  const int r16 = lane & 15, kq = lane >> 4;
  const int r = tid >> 1;
  const int half = tid & 1;
  f32x4 acc[4][4] = {};
  for (int k0 = 0; k0 < K; k0 += 32) {
    __syncthreads();
    if (A_BF16) {
      const u16* Ab = (const u16*)Aany;
      const int4* src = (const int4*)(Ab + (size_t)(m0 + r) * K + k0 + half * 16);
      int4 v0 = src[0];
      int4 v1 = src[1];
      *(int4*)&As[r * 32 + half * 16] = v0;
      *(int4*)&As[r * 32 + half * 16 + 8] = v1;
    } else {
      const float* Af = (const float*)Aany;
      const float4* src = (const float4*)(Af + (size_t)(m0 + r) * K + k0 + half * 16);
      float4 f0 = src[0], f1 = src[1], f2 = src[2], f3 = src[3];
      uint4 w0 = {pack2(f0.x, f0.y), pack2(f0.z, f0.w), pack2(f1.x, f1.y), pack2(f1.z, f1.w)};
      uint4 w1 = {pack2(f2.x, f2.y), pack2(f2.z, f2.w), pack2(f3.x, f3.y), pack2(f3.z, f3.w)};
      *(uint4*)&As[r * 32 + half * 16] = w0;
      *(uint4*)&As[r * 32 + half * 16 + 8] = w1;
    }
    {
      const int4* src = (const int4*)(Bt + (size_t)(n0 + r) * K + k0 + half * 16);
      int4 v0 = src[0];
      int4 v1 = src[1];
      *(int4*)&Bs[r * 32 + half * 16] = v0;
      *(int4*)&Bs[r * 32 + half * 16 + 8] = v1;
    }
    __syncthreads();
    bf16x8 a[4], b[4];
#pragma unroll
    for (int i = 0; i < 4; i++)
      a[i] = *(const bf16x8*)&As[(wm * 64 + i * 16 + r16) * 32 + kq * 8];
#pragma unroll
    for (int j = 0; j < 4; j++)
      b[j] = *(const bf16x8*)&Bs[(wn * 64 + j * 16 + r16) * 32 + kq * 8];
#pragma unroll
    for (int i = 0; i < 4; i++)
#pragma unroll
      for (int j = 0; j < 4; j++)
        acc[i][j] = __builtin_amdgcn_mfma_f32_16x16x32_bf16(a[i], b[j], acc[i][j], 0, 0, 0);
  }
#pragma unroll
  for (int j = 0; j < 4; j++) {
    int col = n0 + wn * 64 + j * 16 + r16;
    float bv = bias[col];
#pragma unroll
    for (int i = 0; i < 4; i++) {
#pragma unroll
      for (int q = 0; q < 4; q++) {
        int row = m0 + wm * 64 + i * 16 + kq * 4 + q;
        float v = acc[i][j][q] + bv;
        ((u16*)Out)[(size_t)row * N + col] = f2b(v);
      }
    }
  }
}

// ---------------- attn: softmax over heads of (q.k)/8 ----------------
__global__ __launch_bounds__(256) void attn_kernel(
    const u16* __restrict__ qb, const u16* __restrict__ kb,
    float* __restrict__ attn) {
  int lane = threadIdx.x & 63;
  int wid = threadIdx.x >> 6;
  size_t t = (size_t)blockIdx.x * 4 + wid;
  int4 qv = *(const int4*)(qb + t * INNER + lane * 8);
  int4 kv = *(const int4*)(kb + t * INNER + lane * 8);
  const u16* qu = (const u16*)&qv;
  const u16* ku = (const u16*)&kv;
  float s = 0.f;
#pragma unroll
  for (int j = 0; j < 8; j++) s += b2f(qu[j]) * b2f(ku[j]);
  s += __shfl_xor(s, 1);
  s += __shfl_xor(s, 2);
  s += __shfl_xor(s, 4);
  s *= 0.125f;
  float mx = s;
  mx = fmaxf(mx, __shfl_xor(mx, 8));
  mx = fmaxf(mx, __shfl_xor(mx, 16));
  mx = fmaxf(mx, __shfl_xor(mx, 32));
  float e = __expf(s - mx);
  float sm = e;
  sm += __shfl_xor(sm, 8);
  sm += __shfl_xor(sm, 16);
  sm += __shfl_xor(sm, 32);
  float a = e / sm;
  if ((lane & 7) == 0) attn[t * HEADS + (lane >> 3)] = a;
}

// ---------------- scan ----------------
__global__ __launch_bounds__(512) void scan_phase1(
    const u16* __restrict__ vb, const float* __restrict__ attn,
    const float* __restrict__ alpha, float* __restrict__ ends) {
  int hd = threadIdx.x;
  int h = hd >> 6;
  int c = blockIdx.x, b = blockIdx.y;
  float decay = 1.f / (1.f + __expf(-alpha[hd]));
  float om = 1.f - decay;
  size_t base = (size_t)b * SEQ + (size_t)c * CHLEN;
  float st = 0.f;
#pragma unroll 8
  for (int i = 0; i < CHLEN; i++) {
    size_t t = base + i;
    float a = attn[t * HEADS + h];
    float v = b2f(vb[t * INNER + hd]);
    st = decay * st + om * a * v;
  }
  ends[((size_t)b * NCHUNK + c) * INNER + hd] = st;
}

__global__ __launch_bounds__(512) void scan_phase2(
    const float* __restrict__ ends, const float* __restrict__ alpha,
    float* __restrict__ carries) {
  int hd = threadIdx.x;
  int b = blockIdx.x;
  float decay = 1.f / (1.f + __expf(-alpha[hd]));
  float dL = __powf(decay, (float)CHLEN);
  float carry = 0.f;
#pragma unroll 8
  for (int c = 0; c < NCHUNK; c++) {
    size_t idx = ((size_t)b * NCHUNK + c) * INNER + hd;
    carries[idx] = carry;
    carry = dL * carry + ends[idx];
  }
}

__global__ __launch_bounds__(512) void scan_phase3(
    const u16* __restrict__ qb, const u16* __restrict__ vb,
    const float* __restrict__ attn, const float* __restrict__ alpha,
    const float* __restrict__ augp, const float* __restrict__ carries,
    u16* __restrict__ outpre) {
  int hd = threadIdx.x;
  int h = hd >> 6;
  int c = blockIdx.x, b = blockIdx.y;
  float decay = 1.f / (1.f + __expf(-alpha[hd]));
  float om = 1.f - decay;
  float ap = augp[hd];
  float st = carries[((size_t)b * NCHUNK + c) * INNER + hd];
  size_t base = (size_t)b * SEQ + (size_t)c * CHLEN;
#pragma unroll 4
  for (int i = 0; i < CHLEN; i++) {
    size_t t = base + i;
    float a = attn[t * HEADS + h];
    float v = b2f(vb[t * INNER + hd]);
    st = decay * st + om * a * v;
    float q = b2f(qb[t * INNER + hd]);
    float aug = 1.f / (1.f + __expf(-q * ap));
    outpre[t * INNER + hd] = f2b(q * st + aug);
  }
}

// ---------------- LayerNorm: bf16 in -> fp32 out ----------------
__global__ __launch_bounds__(256) void ln_kernel(
    const u16* __restrict__ outln, float* __restrict__ out,
    const float* __restrict__ lns, const float* __restrict__ lnb) {
  size_t row = blockIdx.x;
  int tid = threadIdx.x;
  uint2 rv = *(const uint2*)(outln + row * HIDDEN + tid * 4);
  const u16* p = (const u16*)&rv;
  float v0 = b2f(p[0]), v1 = b2f(p[1]), v2 = b2f(p[2]), v3 = b2f(p[3]);
  float s = v0 + v1 + v2 + v3;
  float ss = v0 * v0 + v1 * v1 + v2 * v2 + v3 * v3;
#pragma unroll
  for (int m = 1; m < 64; m <<= 1) {
    s += __shfl_xor(s, m);
    ss += __shfl_xor(ss, m);
  }
  __shared__ float sb[4], ssb[4];
  int lane = tid & 63, wid = tid >> 6;
  if (lane == 0) {
    sb[wid] = s;
    ssb[wid] = ss;
  }
  __syncthreads();
  s = sb[0] + sb[1] + sb[2] + sb[3];
  ss = ssb[0] + ssb[1] + ssb[2] + ssb[3];
  float mean = s * (1.f / HIDDEN);
  float var = ss * (1.f / HIDDEN) - mean * mean;
  float rstd = rsqrtf(var + 1e-6f);
  float4 sc = *(const float4*)(lns + tid * 4);
  float4 bi = *(const float4*)(lnb + tid * 4);
  float4 o;
  o.x = (v0 - mean) * rstd * sc.x + bi.x;
  o.y = (v1 - mean) * rstd * sc.y + bi.y;
  o.z = (v2 - mean) * rstd * sc.z + bi.z;
  o.w = (v3 - mean) * rstd * sc.w + bi.w;
  *(float4*)(out + row * HIDDEN + tid * 4) = o;
}

extern "C" void kernel_launch(void* const* d_in, const int* in_sizes, int n_in,
                              void* d_out, int out_size, void* d_ws, size_t ws_size,
                              hipStream_t stream) {
  const float* x = (const float*)d_in[0];
  const float* Wq = (const float*)d_in[1];
  const float* bq = (const float*)d_in[2];
  const float* Wk = (const float*)d_in[3];
  const float* bk = (const float*)d_in[4];
  const float* Wv = (const float*)d_in[5];
  const float* bv = (const float*)d_in[6];
  const float* Wo = (const float*)d_in[7];
  const float* bo = (const float*)d_in[8];
  const float* alpha = (const float*)d_in[9];
  const float* augp = (const float*)d_in[10];
  const float* lns = (const float*)d_in[11];
  const float* lnb = (const float*)d_in[12];

  char* ws = (char*)d_ws;
  const bool fast = ws_size >= 175118336ull;

  if (fast) {
    u16* xb = (u16*)(ws + 0);                 // 67.1 MB (reused as outln)
    u16* qb = (u16*)(ws + 67108864);          // 33.5 MB
    u16* kb = (u16*)(ws + 100663296);         // 33.5 MB (reused as outpre)
    u16* vb = (u16*)(ws + 134217728);         // 33.5 MB
    u16* Wt = (u16*)(ws + 167772160);         // 3 MB, [1536][1024]
    u16* Wot = (u16*)(ws + 170917888);        // 1 MB, [1024][512]
    float* bcat = (float*)(ws + 171966464);   // 6 KB
    float* attn = (float*)(ws + 171972608);   // 1 MB
    float* ends = (float*)(ws + 173021184);   // 1 MB
    float* car = (float*)(ws + 174069760);    // 1 MB
    u16* outpre = kb;
    u16* outln = xb;  // xb dead after QKV gemm

    prep_x<<<ROWS * HIDDEN / 8 / 256, 256, 0, stream>>>(x, xb);
    prep_w<<<8192, 256, 0, stream>>>(Wq, Wk, Wv, Wo, bq, bk, bv, Wt, Wot, bcat);

    // QKV: M=32768, N=1536 -> 128*6 = 768 blocks of 512 thr
    gemm_8ph<HIDDEN, true><<<768, 512, 0, stream>>>(
        xb, Wt, bcat, qb, kb, vb, 6);

    attn_kernel<<<ROWS / 4, 256, 0, stream>>>(qb, kb, attn);
    scan_phase1<<<dim3(NCHUNK, BATCH), 512, 0, stream>>>(vb, attn, alpha, ends);
    scan_phase2<<<BATCH, 512, 0, stream>>>(ends, alpha, car);
    scan_phase3<<<dim3(NCHUNK, BATCH), 512, 0, stream>>>(qb, vb, attn, alpha, augp, car, outpre);

    // out: M=32768, N=1024 -> 128*4 = 512 blocks, bf16 -> outln
    gemm_8ph<INNER, false><<<512, 512, 0, stream>>>(
        outpre, Wot, bo, outln, outln, outln, 4);

    ln_kernel<<<ROWS, 256, 0, stream>>>(outln, (float*)d_out, lns, lnb);
  } else {
    // fallback layout (108 MB): qb@0, vb@33.5, kb@67 (outpre); outln spans qb+vb
    u16* qb = (u16*)(ws + 0);
    u16* vb = (u16*)(ws + 33554432);
    u16* kb = (u16*)(ws + 67108864);
    u16* Wt = (u16*)(ws + 100663296);
    u16* Wot = (u16*)(ws + 103809024);
    float* bcat = (float*)(ws + 104845312);
    float* attn = (float*)(ws + 104857600);
    float* ends = (float*)(ws + 105906176);
    float* car = (float*)(ws + 106954752);
    u16* outpre = kb;
    u16* outln = (u16*)(ws + 0);  // qb+vb dead after scan3

    prep_w<<<8192, 256, 0, stream>>>(Wq, Wk, Wv, Wo, bq, bk, bv, Wt, Wot, bcat);
    gemm128<false><<<dim3(4, 256, 3), 256, 0, stream>>>(
        x, Wt, bq, bk, bv, qb, kb, vb, HIDDEN);
    attn_kernel<<<ROWS / 4, 256, 0, stream>>>(qb, kb, attn);
    scan_phase1<<<dim3(NCHUNK, BATCH), 512, 0, stream>>>(vb, attn, alpha, ends);
    scan_phase2<<<BATCH, 512, 0, stream>>>(ends, alpha, car);
    scan_phase3<<<dim3(NCHUNK, BATCH), 512, 0, stream>>>(qb, vb, attn, alpha, augp, car, outpre);
    gemm_8ph<INNER, false><<<512, 512, 0, stream>>>(
        outpre, Wot, bo, outln, outln, outln, 4);
    ln_kernel<<<ROWS, 256, 0, stream>>>(outln, (float*)d_out, lns, lnb);
  }
}

// Round 8
// 275.057 us; speedup vs baseline: 1.5331x; 1.0135x over previous
//
#include <hip/hip_runtime.h>
#include <hip/hip_bf16.h>

// MetaLA fused pipeline, round 8.
//  gemm_8ph: 256x256 tile, BK=32, 4-slot LDS ring, counted vmcnt(8). NEW: single
//            barrier per K-tile + within-tile read/MFMA overlap (issue all 12
//            ds_reads, compiler waits lgkmcnt(4) for batch-1 MFMA while the 4
//            af1 reads drain under MFMA). LDS-transpose sector-dense epilogue.
//  out-proj bf16 -> outln; ln_kernel reads bf16, writes fp32 d_out.

#define HIDDEN 1024
#define HEADS 8
#define HDIM 64
#define INNER 512
#define BATCH 4
#define SEQ 8192
#define ROWS (BATCH*SEQ)
#define NCHUNK 128
#define CHLEN 64

typedef unsigned short u16;
typedef unsigned int u32;
typedef __attribute__((ext_vector_type(8))) short bf16x8;
typedef __attribute__((ext_vector_type(4))) float f32x4;

__device__ __forceinline__ float b2f(u16 u) { return __uint_as_float(((u32)u) << 16); }
__device__ __forceinline__ u16 f2b(float f) {
  u32 u = __float_as_uint(f);
  u32 r = u + 0x7fffu + ((u >> 16) & 1u);  // RNE
  return (u16)(r >> 16);
}
__device__ __forceinline__ u32 pack2(float a, float b) {
  return (u32)f2b(a) | ((u32)f2b(b) << 16);
}

#define GLOAD_LDS16(gp, lp)                                                  \
  __builtin_amdgcn_global_load_lds(                                          \
      (const __attribute__((address_space(1))) u32*)(gp),                    \
      (__attribute__((address_space(3))) u32*)(lp), 16, 0, 0)

// ---------------- prep_x: fp32 -> bf16 ----------------
__global__ __launch_bounds__(256) void prep_x(const float* __restrict__ x,
                                              u16* __restrict__ xb) {
  size_t i = ((size_t)blockIdx.x * 256 + threadIdx.x) * 8;
  float4 a = *(const float4*)(x + i);
  float4 b = *(const float4*)(x + i + 4);
  uint4 w = {pack2(a.x, a.y), pack2(a.z, a.w), pack2(b.x, b.y), pack2(b.z, b.w)};
  *(uint4*)(xb + i) = w;
}

// ---------------- prep_w: weight transpose/convert + bias concat ----------------
__global__ __launch_bounds__(256) void prep_w(
    const float* __restrict__ Wq, const float* __restrict__ Wk,
    const float* __restrict__ Wv, const float* __restrict__ Wo,
    const float* __restrict__ bq, const float* __restrict__ bk,
    const float* __restrict__ bv,
    u16* __restrict__ Wt, u16* __restrict__ Wot, float* __restrict__ bcat) {
  const int WELEM = HIDDEN * INNER;  // 524288
  int idx = blockIdx.x * 256 + threadIdx.x;
  if (idx < 3 * WELEM) {
    int z = idx / WELEM;
    int rem = idx - z * WELEM;  // n*1024 + k
    int n = rem >> 10;
    int k = rem & 1023;
    const float* W = (z == 0) ? Wq : (z == 1) ? Wk : Wv;
    Wt[idx] = f2b(W[k * INNER + n]);
  } else {
    int rem = idx - 3 * WELEM;  // n*512 + k
    int n = rem >> 9;
    int k = rem & 511;
    Wot[rem] = f2b(Wo[k * HIDDEN + n]);
  }
  if (idx < 3 * INNER) {
    int z = idx >> 9;
    int n = idx & 511;
    bcat[idx] = (z == 0) ? bq[n] : (z == 1) ? bk[n] : bv[n];
  }
}

// ---------------- gemm_8ph: 256x256, BK=32, 4-slot ring, 1 barrier/tile ----------------
// A: [M][K] bf16, Bt: [N][K] bf16 (row n = output col), out = A@Bt^T + bias (bf16 out).
// SPLIT3: N=1536, route 512-col groups to out0/1/2 ([M][512] bf16); else out0 [M][N] bf16.
template <int K, bool SPLIT3>
__global__ __launch_bounds__(512, 2) void gemm_8ph(
    const u16* __restrict__ A, const u16* __restrict__ Bt,
    const float* __restrict__ bias,
    void* __restrict__ out0, void* __restrict__ out1, void* __restrict__ out2,
    int nTilesN) {
  constexpr int NT = K / 32;  // K-tiles; >= 4
  // slot: A 256x32 swizzled (8192 u16) | B 256x32 swizzled (8192 u16) = 32KB
  __shared__ u16 lds[4][16384];

  // bijective XCD-chunked swizzle (nwg % 8 == 0); consecutive lin share A-panel
  const int nwg = gridDim.x;
  const int chunk = nwg >> 3;
  const int bid = blockIdx.x;
  const int lin = (bid & 7) * chunk + (bid >> 3);
  const int nt = lin % nTilesN;
  const int mt = lin / nTilesN;
  const int m0 = mt * 256, n0 = nt * 256;
  const int N = nTilesN * 256;

  const int tid = threadIdx.x;
  const int lane = tid & 63;
  const int w = tid >> 6;   // 0..7
  const int wm = w >> 2;    // 0..1  (M half: 128 rows)
  const int wn = w & 3;     // 0..3  (N quarter: 64 cols)
  const int r16 = lane & 15, kq = lane >> 4;

  // ---- staging geometry (pre-swizzled global source, linear LDS dest) ----
  const int rt = tid >> 2;                            // row within round
  const int cg = (((tid & 3) << 3)) ^ (((rt >> 1) & 3) << 3);
  const u16* Ag = A + (size_t)(m0 + rt) * K + cg;
  const u16* Bg = Bt + (size_t)(n0 + rt) * K + cg;
  const int ldst = w * 512;  // wave-uniform; HW adds lane*16B

#define STAGE_AB(slot, kt)                                                    \
  {                                                                           \
    GLOAD_LDS16(Ag + (size_t)(kt) * 32, &lds[slot][ldst]);                    \
    GLOAD_LDS16(Ag + (size_t)(kt) * 32 + (size_t)128 * K,                     \
                &lds[slot][4096 + ldst]);                                     \
    GLOAD_LDS16(Bg + (size_t)(kt) * 32, &lds[slot][8192 + ldst]);             \
    GLOAD_LDS16(Bg + (size_t)(kt) * 32 + (size_t)128 * K,                     \
                &lds[slot][12288 + ldst]);                                    \
  }

  // ---- read-side swizzled offsets: elem (row,c) at row*32 + (c ^ (((row>>1)&3)<<3)) ----
  const int xk = (kq << 3) ^ (((r16 >> 1) & 3) << 3);
  const int aO = (wm * 128 + r16) * 32 + xk;          // + i*512
  const int bO = 8192 + (wn * 64 + r16) * 32 + xk;    // + j*512

  f32x4 acc[8][4] = {};

  // one barrier per K-tile; reads for the whole tile issued up-front so the
  // af1 group drains in the LDS pipe UNDER MFMA batch 1 (compiler emits the
  // fine-grained lgkmcnt(4) before batch 1 and lgkmcnt(0) before batch 2).
#define TILE(t_, STG, VMW)                                                     \
  {                                                                            \
    STG;                                                                       \
    const u16* sl = &lds[(t_) & 3][0];                                         \
    bf16x8 af0[4], af1[4], bfv4[4];                                            \
    _Pragma("unroll") for (int i = 0; i < 4; i++)                              \
        af0[i] = *(const bf16x8*)&sl[aO + i * 512];                            \
    _Pragma("unroll") for (int j = 0; j < 4; j++)                              \
        bfv4[j] = *(const bf16x8*)&sl[bO + j * 512];                           \
    __builtin_amdgcn_sched_barrier(0);                                         \
    _Pragma("unroll") for (int i = 0; i < 4; i++)                              \
        af1[i] = *(const bf16x8*)&sl[aO + (i + 4) * 512];                      \
    __builtin_amdgcn_sched_barrier(0);                                         \
    __builtin_amdgcn_s_setprio(1);                                             \
    _Pragma("unroll") for (int i = 0; i < 4; i++)                              \
        _Pragma("unroll") for (int j = 0; j < 4; j++)                          \
            acc[i][j] =                                                        \
        __builtin_amdgcn_mfma_f32_16x16x32_bf16(af0[i], bfv4[j], acc[i][j], 0, 0, 0); \
    __builtin_amdgcn_s_setprio(0);                                             \
    __builtin_amdgcn_sched_barrier(0);                                         \
    __builtin_amdgcn_s_setprio(1);                                             \
    _Pragma("unroll") for (int i = 0; i < 4; i++)                              \
        _Pragma("unroll") for (int j = 0; j < 4; j++)                          \
            acc[i + 4][j] =                                                    \
        __builtin_amdgcn_mfma_f32_16x16x32_bf16(af1[i], bfv4[j], acc[i + 4][j], 0, 0, 0); \
    __builtin_amdgcn_s_setprio(0);                                             \
    VMW;                                                                       \
    __builtin_amdgcn_sched_barrier(0);                                         \
    __builtin_amdgcn_s_barrier();                                              \
  }

#define VM8 asm volatile("s_waitcnt vmcnt(8)" ::: "memory")
#define VM4 asm volatile("s_waitcnt vmcnt(4)" ::: "memory")
#define VM0 asm volatile("s_waitcnt vmcnt(0)" ::: "memory")
#define NOSTG ((void)0)
#define NOVM ((void)0)

  // prologue: stage tiles 0,1,2 (12 loads); ensure tile 0 landed (8 newest remain)
  STAGE_AB(0, 0);
  STAGE_AB(1, 1);
  STAGE_AB(2, 2);
  VM8;
  __builtin_amdgcn_sched_barrier(0);
  __builtin_amdgcn_s_barrier();

  // steady state: stage t+3 into slot (t-1)&3 (freed by the entry barrier);
  // end-of-tile vmcnt(8) confirms tile t+1 landed (t+2,t+3 stay in flight).
  for (int t = 0; t < NT - 3; ++t) {
    TILE(t, STAGE_AB((t + 3) & 3, t + 3), VM8);
  }
  TILE(NT - 3, NOSTG, VM4);
  TILE(NT - 2, NOSTG, VM0);
  TILE(NT - 1, NOSTG, NOVM);  // final barrier frees LDS for the epilogue
#undef TILE
#undef STAGE_AB
#undef VM8
#undef VM4
#undef VM0
#undef NOSTG
#undef NOVM

  // ---- epilogue: wave-local LDS transpose -> sector-dense coalesced bf16 stores ----
  float* fl = (float*)(&lds[0][0]) + w * 4096;
  const int zsel = SPLIT3 ? ((n0 + wn * 64) >> 9) : 0;
  u16* ob = SPLIT3 ? (u16*)((zsel == 0) ? out0 : (zsel == 1) ? out1 : out2)
                   : (u16*)out0;
  const int OC = SPLIT3 ? INNER : N;
  const int colloc = (lane & 7) * 8;
  const int gcol = (SPLIT3 ? ((n0 + wn * 64) & 511) : (n0 + wn * 64)) + colloc;
  const int lrowr = lane >> 3;
  float bvj[4];
#pragma unroll
  for (int j = 0; j < 4; j++) bvj[j] = bias[n0 + wn * 64 + j * 16 + r16];

#pragma unroll
  for (int pass = 0; pass < 4; ++pass) {
#pragma unroll
    for (int ii = 0; ii < 2; ++ii) {
#pragma unroll
      for (int j = 0; j < 4; ++j) {
#pragma unroll
        for (int q = 0; q < 4; ++q)
          fl[(ii * 16 + kq * 4 + q) * 68 + j * 16 + r16] =
              acc[pass * 2 + ii][j][q] + bvj[j];
      }
    }
#pragma unroll
    for (int inst = 0; inst < 4; ++inst) {
      int lr = inst * 8 + lrowr;
      float4 f0 = *(float4*)&fl[lr * 68 + colloc];
      float4 f1 = *(float4*)&fl[lr * 68 + colloc + 4];
      uint4 wv = {pack2(f0.x, f0.y), pack2(f0.z, f0.w),
                  pack2(f1.x, f1.y), pack2(f1.z, f1.w)};
      size_t grow = (size_t)(m0 + wm * 128 + pass * 32 + lr);
      *(uint4*)&ob[grow * OC + gcol] = wv;
    }
  }
}

// ---------------- legacy 128^2 GEMM (fp32 A staging) — small-ws fallback ----------------
template <bool A_BF16>
__global__ __launch_bounds__(256) void gemm128(
    const void* __restrict__ Aany, const u16* __restrict__ BtBase,
    const float* __restrict__ bias0, const float* __restrict__ bias1,
    const float* __restrict__ bias2,
    void* __restrict__ out0, void* __restrict__ out1, void* __restrict__ out2,
    int K) {
  __shared__ u16 As[128 * 32];
  __shared__ u16 Bs[128 * 32];
  const int N = gridDim.x * 128;
  const int z = blockIdx.z;
  const u16* Bt = BtBase + (size_t)z * N * K;
  const float* bias = (z == 0) ? bias0 : (z == 1) ? bias1 : bias2;
  void* Out = (z == 0) ? out0 : (z == 1) ? out1 : out2;
  const int tid = threadIdx.x;
  const int m0 = blockIdx.y * 128;
  const int n0 = blockIdx.x * 128;
  const int lane = tid & 63;
  const int wid = tid >> 6;
  const int wm = wid >> 1, wn = wid & 1;
  const int r16 = lane & 15, kq = lane >> 4;
  const int r = tid >> 1;
  const int half = tid & 1;
  f32x4 acc[4][4] = {};
  for (int k0 = 0; k0 < K; k0 += 32) {
    __syncthreads();
    if (A_BF16) {
      const u16* Ab = (const u16*)Aany;
      const int4* src = (const int4*)(Ab + (size_t)(m0 + r) * K + k0 + half * 16);
      int4 v0 = src[0];
      int4 v1 = src[1];
      *(int4*)&As[r * 32 + half * 16] = v0;
      *(int4*)&As[r * 32 + half * 16 + 8] = v1;
    } else {
      const float* Af = (const float*)Aany;
      const float4* src = (const float4*)(Af + (size_t)(m0 + r) * K + k0 + half * 16);
      float4 f0 = src[0], f1 = src[1], f2 = src[2], f3 = src[3];
      uint4 w0 = {pack2(f0.x, f0.y), pack2(f0.z, f0.w), pack2(f1.x, f1.y), pack2(f1.z, f1.w)};
      uint4 w1 = {pack2(f2.x, f2.y), pack2(f2.z, f2.w), pack2(f3.x, f3.y), pack2(f3.z, f3.w)};
      *(uint4*)&As[r * 32 + half * 16] = w0;
      *(uint4*)&As[r * 32 + half * 16 + 8] = w1;
    }
    {
      const int4* src = (const int4*)(Bt + (size_t)(n0 + r) * K + k0 + half * 16);
      int4 v0 = src[0];
      int4 v1 = src[1];
      *(int4*)&Bs[r * 32 + half * 16] = v0;
      *(int4*)&Bs[r * 32 + half * 16 + 8] = v1;
    }
    __syncthreads();
    bf16x8 a[4], b[4];
#pragma unroll
    for (int i = 0; i < 4; i++)
      a[i] = *(const bf16x8*)&As[(wm * 64 + i * 16 + r16) * 32 + kq * 8];
#pragma unroll
    for (int j = 0; j < 4; j++)
      b[j] = *(const bf16x8*)&Bs[(wn * 64 + j * 16 + r16) * 32 + kq * 8];
#pragma unroll
    for (int i = 0; i < 4; i++)
#pragma unroll
      for (int j = 0; j < 4; j++)
        acc[i][j] = __builtin_amdgcn_mfma_f32_16x16x32_bf16(a[i], b[j], acc[i][j], 0, 0, 0);
  }
#pragma unroll
  for (int j = 0; j < 4; j++) {
    int col = n0 + wn * 64 + j * 16 + r16;
    float bv = bias[col];
#pragma unroll
    for (int i = 0; i < 4; i++) {
#pragma unroll
      for (int q = 0; q < 4; q++) {
        int row = m0 + wm * 64 + i * 16 + kq * 4 + q;
        float v = acc[i][j][q] + bv;
        ((u16*)Out)[(size_t)row * N + col] = f2b(v);
      }
    }
  }
}

// ---------------- attn: softmax over heads of (q.k)/8 ----------------
__global__ __launch_bounds__(256) void attn_kernel(
    const u16* __restrict__ qb, const u16* __restrict__ kb,
    float* __restrict__ attn) {
  int lane = threadIdx.x & 63;
  int wid = threadIdx.x >> 6;
  size_t t = (size_t)blockIdx.x * 4 + wid;
  int4 qv = *(const int4*)(qb + t * INNER + lane * 8);
  int4 kv = *(const int4*)(kb + t * INNER + lane * 8);
  const u16* qu = (const u16*)&qv;
  const u16* ku = (const u16*)&kv;
  float s = 0.f;
#pragma unroll
  for (int j = 0; j < 8; j++) s += b2f(qu[j]) * b2f(ku[j]);
  s += __shfl_xor(s, 1);
  s += __shfl_xor(s, 2);
  s += __shfl_xor(s, 4);
  s *= 0.125f;
  float mx = s;
  mx = fmaxf(mx, __shfl_xor(mx, 8));
  mx = fmaxf(mx, __shfl_xor(mx, 16));
  mx = fmaxf(mx, __shfl_xor(mx, 32));
  float e = __expf(s - mx);
  float sm = e;
  sm += __shfl_xor(sm, 8);
  sm += __shfl_xor(sm, 16);
  sm += __shfl_xor(sm, 32);
  float a = e / sm;
  if ((lane & 7) == 0) attn[t * HEADS + (lane >> 3)] = a;
}

// ---------------- scan ----------------
__global__ __launch_bounds__(512) void scan_phase1(
    const u16* __restrict__ vb, const float* __restrict__ attn,
    const float* __restrict__ alpha, float* __restrict__ ends) {
  int hd = threadIdx.x;
  int h = hd >> 6;
  int c = blockIdx.x, b = blockIdx.y;
  float decay = 1.f / (1.f + __expf(-alpha[hd]));
  float om = 1.f - decay;
  size_t base = (size_t)b * SEQ + (size_t)c * CHLEN;
  float st = 0.f;
#pragma unroll 8
  for (int i = 0; i < CHLEN; i++) {
    size_t t = base + i;
    float a = attn[t * HEADS + h];
    float v = b2f(vb[t * INNER + hd]);
    st = decay * st + om * a * v;
  }
  ends[((size_t)b * NCHUNK + c) * INNER + hd] = st;
}

__global__ __launch_bounds__(512) void scan_phase2(
    const float* __restrict__ ends, const float* __restrict__ alpha,
    float* __restrict__ carries) {
  int hd = threadIdx.x;
  int b = blockIdx.x;
  float decay = 1.f / (1.f + __expf(-alpha[hd]));
  float dL = __powf(decay, (float)CHLEN);
  float carry = 0.f;
#pragma unroll 8
  for (int c = 0; c < NCHUNK; c++) {
    size_t idx = ((size_t)b * NCHUNK + c) * INNER + hd;
    carries[idx] = carry;
    carry = dL * carry + ends[idx];
  }
}

__global__ __launch_bounds__(512) void scan_phase3(
    const u16* __restrict__ qb, const u16* __restrict__ vb,
    const float* __restrict__ attn, const float* __restrict__ alpha,
    const float* __restrict__ augp, const float* __restrict__ carries,
    u16* __restrict__ outpre) {
  int hd = threadIdx.x;
  int h = hd >> 6;
  int c = blockIdx.x, b = blockIdx.y;
  float decay = 1.f / (1.f + __expf(-alpha[hd]));
  float om = 1.f - decay;
  float ap = augp[hd];
  float st = carries[((size_t)b * NCHUNK + c) * INNER + hd];
  size_t base = (size_t)b * SEQ + (size_t)c * CHLEN;
#pragma unroll 4
  for (int i = 0; i < CHLEN; i++) {
    size_t t = base + i;
    float a = attn[t * HEADS + h];
    float v = b2f(vb[t * INNER + hd]);
    st = decay * st + om * a * v;
    float q = b2f(qb[t * INNER + hd]);
    float aug = 1.f / (1.f + __expf(-q * ap));
    outpre[t * INNER + hd] = f2b(q * st + aug);
  }
}

// ---------------- LayerNorm: bf16 in -> fp32 out ----------------
__global__ __launch_bounds__(256) void ln_kernel(
    const u16* __restrict__ outln, float* __restrict__ out,
    const float* __restrict__ lns, const float* __restrict__ lnb) {
  size_t row = blockIdx.x;
  int tid = threadIdx.x;
  uint2 rv = *(const uint2*)(outln + row * HIDDEN + tid * 4);
  const u16* p = (const u16*)&rv;
  float v0 = b2f(p[0]), v1 = b2f(p[1]), v2 = b2f(p[2]), v3 = b2f(p[3]);
  float s = v0 + v1 + v2 + v3;
  float ss = v0 * v0 + v1 * v1 + v2 * v2 + v3 * v3;
#pragma unroll
  for (int m = 1; m < 64; m <<= 1) {
    s += __shfl_xor(s, m);
    ss += __shfl_xor(ss, m);
  }
  __shared__ float sb[4], ssb[4];
  int lane = tid & 63, wid = tid >> 6;
  if (lane == 0) {
    sb[wid] = s;
    ssb[wid] = ss;
  }
  __syncthreads();
  s = sb[0] + sb[1] + sb[2] + sb[3];
  ss = ssb[0] + ssb[1] + ssb[2] + ssb[3];
  float mean = s * (1.f / HIDDEN);
  float var = ss * (1.f / HIDDEN) - mean * mean;
  float rstd = rsqrtf(var + 1e-6f);
  float4 sc = *(const float4*)(lns + tid * 4);
  float4 bi = *(const float4*)(lnb + tid * 4);
  float4 o;
  o.x = (v0 - mean) * rstd * sc.x + bi.x;
  o.y = (v1 - mean) * rstd * sc.y + bi.y;
  o.z = (v2 - mean) * rstd * sc.z + bi.z;
  o.w = (v3 - mean) * rstd * sc.w + bi.w;
  *(float4*)(out + row * HIDDEN + tid * 4) = o;
}

extern "C" void kernel_launch(void* const* d_in, const int* in_sizes, int n_in,
                              void* d_out, int out_size, void* d_ws, size_t ws_size,
                              hipStream_t stream) {
  const float* x = (const float*)d_in[0];
  const float* Wq = (const float*)d_in[1];
  const float* bq = (const float*)d_in[2];
  const float* Wk = (const float*)d_in[3];
  const float* bk = (const float*)d_in[4];
  const float* Wv = (const float*)d_in[5];
  const float* bv = (const float*)d_in[6];
  const float* Wo = (const float*)d_in[7];
  const float* bo = (const float*)d_in[8];
  const float* alpha = (const float*)d_in[9];
  const float* augp = (const float*)d_in[10];
  const float* lns = (const float*)d_in[11];
  const float* lnb = (const float*)d_in[12];

  char* ws = (char*)d_ws;
  const bool fast = ws_size >= 175118336ull;

  if (fast) {
    u16* xb = (u16*)(ws + 0);                 // 67.1 MB (reused as outln)
    u16* qb = (u16*)(ws + 67108864);          // 33.5 MB
    u16* kb = (u16*)(ws + 100663296);         // 33.5 MB (reused as outpre)
    u16* vb = (u16*)(ws + 134217728);         // 33.5 MB
    u16* Wt = (u16*)(ws + 167772160);         // 3 MB, [1536][1024]
    u16* Wot = (u16*)(ws + 170917888);        // 1 MB, [1024][512]
    float* bcat = (float*)(ws + 171966464);   // 6 KB
    float* attn = (float*)(ws + 171972608);   // 1 MB
    float* ends = (float*)(ws + 173021184);   // 1 MB
    float* car = (float*)(ws + 174069760);    // 1 MB
    u16* outpre = kb;
    u16* outln = xb;  // xb dead after QKV gemm

    prep_x<<<ROWS * HIDDEN / 8 / 256, 256, 0, stream>>>(x, xb);
    prep_w<<<8192, 256, 0, stream>>>(Wq, Wk, Wv, Wo, bq, bk, bv, Wt, Wot, bcat);

    // QKV: M=32768, N=1536 -> 128*6 = 768 blocks of 512 thr
    gemm_8ph<HIDDEN, true><<<768, 512, 0, stream>>>(
        xb, Wt, bcat, qb, kb, vb, 6);

    attn_kernel<<<ROWS / 4, 256, 0, stream>>>(qb, kb, attn);
    scan_phase1<<<dim3(NCHUNK, BATCH), 512, 0, stream>>>(vb, attn, alpha, ends);
    scan_phase2<<<BATCH, 512, 0, stream>>>(ends, alpha, car);
    scan_phase3<<<dim3(NCHUNK, BATCH), 512, 0, stream>>>(qb, vb, attn, alpha, augp, car, outpre);

    // out: M=32768, N=1024 -> 128*4 = 512 blocks, bf16 -> outln
    gemm_8ph<INNER, false><<<512, 512, 0, stream>>>(
        outpre, Wot, bo, outln, outln, outln, 4);

    ln_kernel<<<ROWS, 256, 0, stream>>>(outln, (float*)d_out, lns, lnb);
  } else {
    // fallback layout (108 MB): qb@0, vb@33.5, kb@67 (outpre); outln spans qb+vb
    u16* qb = (u16*)(ws + 0);
    u16* vb = (u16*)(ws + 33554432);
    u16* kb = (u16*)(ws + 67108864);
    u16* Wt = (u16*)(ws + 100663296);
    u16* Wot = (u16*)(ws + 103809024);
    float* bcat = (float*)(ws + 104845312);
    float* attn = (float*)(ws + 104857600);
    float* ends = (float*)(ws + 105906176);
    float* car = (float*)(ws + 106954752);
    u16* outpre = kb;
    u16* outln = (u16*)(ws + 0);  // qb+vb dead after scan3

    prep_w<<<8192, 256, 0, stream>>>(Wq, Wk, Wv, Wo, bq, bk, bv, Wt, Wot, bcat);
    gemm128<false><<<dim3(4, 256, 3), 256, 0, stream>>>(
        x, Wt, bq, bk, bv, qb, kb, vb, HIDDEN);
    attn_kernel<<<ROWS / 4, 256, 0, stream>>>(qb, kb, attn);
    scan_phase1<<<dim3(NCHUNK, BATCH), 512, 0, stream>>>(vb, attn, alpha, ends);
    scan_phase2<<<BATCH, 512, 0, stream>>>(ends, alpha, car);
    scan_phase3<<<dim3(NCHUNK, BATCH), 512, 0, stream>>>(qb, vb, attn, alpha, augp, car, outpre);
    gemm_8ph<INNER, false><<<512, 512, 0, stream>>>(
        outpre, Wot, bo, outln, outln, outln, 4);
    ln_kernel<<<ROWS, 256, 0, stream>>>(outln, (float*)d_out, lns, lnb);
  }
}

// Round 9
// 273.271 us; speedup vs baseline: 1.5431x; 1.0065x over previous
//
#include <hip/hip_runtime.h>
#include <hip/hip_bf16.h>

// MetaLA fused pipeline, round 9.
//  gemm_rp : 256x256 tile, BK=32, 4-slot LDS ring, counted vmcnt(4). NEW: register
//            read-ahead pipeline — ds_read tile t+1 into the alternate named register
//            set while MFMA-ing tile t from the current set (MFMA never waits on
//            this-tile lgkm). One barrier per tile. LDS-transpose sector-dense epilogue.
//  out-proj bf16 -> outln; ln_kernel reads bf16, writes fp32 d_out.

#define HIDDEN 1024
#define HEADS 8
#define HDIM 64
#define INNER 512
#define BATCH 4
#define SEQ 8192
#define ROWS (BATCH*SEQ)
#define NCHUNK 128
#define CHLEN 64

typedef unsigned short u16;
typedef unsigned int u32;
typedef __attribute__((ext_vector_type(8))) short bf16x8;
typedef __attribute__((ext_vector_type(4))) float f32x4;

__device__ __forceinline__ float b2f(u16 u) { return __uint_as_float(((u32)u) << 16); }
__device__ __forceinline__ u16 f2b(float f) {
  u32 u = __float_as_uint(f);
  u32 r = u + 0x7fffu + ((u >> 16) & 1u);  // RNE
  return (u16)(r >> 16);
}
__device__ __forceinline__ u32 pack2(float a, float b) {
  return (u32)f2b(a) | ((u32)f2b(b) << 16);
}

#define GLOAD_LDS16(gp, lp)                                                  \
  __builtin_amdgcn_global_load_lds(                                          \
      (const __attribute__((address_space(1))) u32*)(gp),                    \
      (__attribute__((address_space(3))) u32*)(lp), 16, 0, 0)

// ---------------- prep_x: fp32 -> bf16 ----------------
__global__ __launch_bounds__(256) void prep_x(const float* __restrict__ x,
                                              u16* __restrict__ xb) {
  size_t i = ((size_t)blockIdx.x * 256 + threadIdx.x) * 8;
  float4 a = *(const float4*)(x + i);
  float4 b = *(const float4*)(x + i + 4);
  uint4 w = {pack2(a.x, a.y), pack2(a.z, a.w), pack2(b.x, b.y), pack2(b.z, b.w)};
  *(uint4*)(xb + i) = w;
}

// ---------------- prep_w: weight transpose/convert + bias concat ----------------
__global__ __launch_bounds__(256) void prep_w(
    const float* __restrict__ Wq, const float* __restrict__ Wk,
    const float* __restrict__ Wv, const float* __restrict__ Wo,
    const float* __restrict__ bq, const float* __restrict__ bk,
    const float* __restrict__ bv,
    u16* __restrict__ Wt, u16* __restrict__ Wot, float* __restrict__ bcat) {
  const int WELEM = HIDDEN * INNER;  // 524288
  int idx = blockIdx.x * 256 + threadIdx.x;
  if (idx < 3 * WELEM) {
    int z = idx / WELEM;
    int rem = idx - z * WELEM;  // n*1024 + k
    int n = rem >> 10;
    int k = rem & 1023;
    const float* W = (z == 0) ? Wq : (z == 1) ? Wk : Wv;
    Wt[idx] = f2b(W[k * INNER + n]);
  } else {
    int rem = idx - 3 * WELEM;  // n*512 + k
    int n = rem >> 9;
    int k = rem & 511;
    Wot[rem] = f2b(Wo[k * HIDDEN + n]);
  }
  if (idx < 3 * INNER) {
    int z = idx >> 9;
    int n = idx & 511;
    bcat[idx] = (z == 0) ? bq[n] : (z == 1) ? bk[n] : bv[n];
  }
}

// ---------------- gemm_rp: 256x256, BK=32, 4-slot ring, register read-ahead ----------------
// A: [M][K] bf16, Bt: [N][K] bf16 (row n = output col), out = A@Bt^T + bias (bf16 out).
// SPLIT3: N=1536, route 512-col groups to out0/1/2 ([M][512] bf16); else out0 [M][N] bf16.
template <int K, bool SPLIT3>
__global__ __launch_bounds__(512, 2) void gemm_rp(
    const u16* __restrict__ A, const u16* __restrict__ Bt,
    const float* __restrict__ bias,
    void* __restrict__ out0, void* __restrict__ out1, void* __restrict__ out2,
    int nTilesN) {
  constexpr int NT = K / 32;  // K-tiles; >= 8, even
  // slot: A 256x32 swizzled (8192 u16) | B 256x32 swizzled (8192 u16) = 32KB
  __shared__ u16 lds[4][16384];

  // bijective XCD-chunked swizzle (nwg % 8 == 0); consecutive lin share A-panel
  const int nwg = gridDim.x;
  const int chunk = nwg >> 3;
  const int bid = blockIdx.x;
  const int lin = (bid & 7) * chunk + (bid >> 3);
  const int nt = lin % nTilesN;
  const int mt = lin / nTilesN;
  const int m0 = mt * 256, n0 = nt * 256;
  const int N = nTilesN * 256;

  const int tid = threadIdx.x;
  const int lane = tid & 63;
  const int w = tid >> 6;   // 0..7
  const int wm = w >> 2;    // 0..1  (M half: 128 rows)
  const int wn = w & 3;     // 0..3  (N quarter: 64 cols)
  const int r16 = lane & 15, kq = lane >> 4;

  // ---- staging geometry (pre-swizzled global source, linear LDS dest) ----
  const int rt = tid >> 2;                            // row within round
  const int cg = (((tid & 3) << 3)) ^ (((rt >> 1) & 3) << 3);
  const u16* Ag = A + (size_t)(m0 + rt) * K + cg;
  const u16* Bg = Bt + (size_t)(n0 + rt) * K + cg;
  const int ldst = w * 512;  // wave-uniform; HW adds lane*16B

#define STAGE_AB(slot, kt)                                                    \
  {                                                                           \
    GLOAD_LDS16(Ag + (size_t)(kt) * 32, &lds[slot][ldst]);                    \
    GLOAD_LDS16(Ag + (size_t)(kt) * 32 + (size_t)128 * K,                     \
                &lds[slot][4096 + ldst]);                                     \
    GLOAD_LDS16(Bg + (size_t)(kt) * 32, &lds[slot][8192 + ldst]);             \
    GLOAD_LDS16(Bg + (size_t)(kt) * 32 + (size_t)128 * K,                     \
                &lds[slot][12288 + ldst]);                                    \
  }

  // ---- read-side swizzled offsets: elem (row,c) at row*32 + (c ^ (((row>>1)&3)<<3)) ----
  const int xk = (kq << 3) ^ (((r16 >> 1) & 3) << 3);
  const int aO = (wm * 128 + r16) * 32 + xk;          // + i*512
  const int bO = 8192 + (wn * 64 + r16) * 32 + xk;    // + j*512

  f32x4 acc[8][4] = {};
  bf16x8 r0_a[8], r0_b[4], r1_a[8], r1_b[4];  // two named operand sets (rule #20)

#define DSREAD(da, db, slot)                                                   \
  {                                                                            \
    const u16* sl = &lds[slot][0];                                             \
    _Pragma("unroll") for (int i = 0; i < 8; i++)                              \
        da[i] = *(const bf16x8*)&sl[aO + i * 512];                             \
    _Pragma("unroll") for (int j = 0; j < 4; j++)                              \
        db[j] = *(const bf16x8*)&sl[bO + j * 512];                             \
  }

#define MFMA_SET(sa, sb)                                                       \
  {                                                                            \
    __builtin_amdgcn_s_setprio(1);                                             \
    _Pragma("unroll") for (int i = 0; i < 8; i++)                              \
        _Pragma("unroll") for (int j = 0; j < 4; j++)                          \
            acc[i][j] = __builtin_amdgcn_mfma_f32_16x16x32_bf16(               \
                sa[i], sb[j], acc[i][j], 0, 0, 0);                             \
    __builtin_amdgcn_s_setprio(0);                                             \
  }

#define SYNCB                                                                  \
  {                                                                            \
    __builtin_amdgcn_sched_barrier(0);                                         \
    __builtin_amdgcn_s_barrier();                                              \
    __builtin_amdgcn_sched_barrier(0);                                         \
  }

#define VM4 asm volatile("s_waitcnt vmcnt(4)" ::: "memory")
#define VM0 asm volatile("s_waitcnt vmcnt(0)" ::: "memory")

  // prologue: stage tiles 0,1,2; vmcnt(4) -> tiles 0,1 landed (tile2 in flight);
  // barrier; read tile0 into set0.
  STAGE_AB(0, 0);
  STAGE_AB(1, 1);
  STAGE_AB(2, 2);
  VM4;
  SYNCB;
  DSREAD(r0_a, r0_b, 0);

  // steady state, pairs (t, t+1), t <= NT-6:
  //   half A: STAGE(t+3); read t+1 -> set1; MFMA set0 (tile t);  VM4 (t+2 landed); barrier
  //   half B: STAGE(t+4); read t+2 -> set0; MFMA set1 (tile t+1);VM4 (t+3 landed); barrier
  for (int t = 0; t + 6 <= NT; t += 2) {
    STAGE_AB((t + 3) & 3, t + 3);
    DSREAD(r1_a, r1_b, (t + 1) & 3);
    MFMA_SET(r0_a, r0_b);
    VM4;
    SYNCB;
    STAGE_AB((t + 4) & 3, t + 4);
    DSREAD(r0_a, r0_b, (t + 2) & 3);
    MFMA_SET(r1_a, r1_b);
    VM4;
    SYNCB;
  }
  // tail: tiles NT-4 .. NT-1
  STAGE_AB((NT - 1) & 3, NT - 1);          // last stage
  DSREAD(r1_a, r1_b, (NT - 3) & 3);
  MFMA_SET(r0_a, r0_b);                    // tile NT-4
  VM4;                                     // tile NT-2 landed (only NT-1 in flight)
  SYNCB;
  DSREAD(r0_a, r0_b, (NT - 2) & 3);
  MFMA_SET(r1_a, r1_b);                    // tile NT-3
  VM0;                                     // tile NT-1 landed
  SYNCB;
  DSREAD(r1_a, r1_b, (NT - 1) & 3);
  MFMA_SET(r0_a, r0_b);                    // tile NT-2
  MFMA_SET(r1_a, r1_b);                    // tile NT-1
  SYNCB;                                   // all lgkm done per-wave before their MFMA;
                                           // barrier frees LDS for the epilogue
#undef DSREAD
#undef MFMA_SET
#undef SYNCB
#undef VM4
#undef VM0
#undef STAGE_AB

  // ---- epilogue: wave-local LDS transpose -> sector-dense coalesced bf16 stores ----
  float* fl = (float*)(&lds[0][0]) + w * 4096;
  const int zsel = SPLIT3 ? ((n0 + wn * 64) >> 9) : 0;
  u16* ob = SPLIT3 ? (u16*)((zsel == 0) ? out0 : (zsel == 1) ? out1 : out2)
                   : (u16*)out0;
  const int OC = SPLIT3 ? INNER : N;
  const int colloc = (lane & 7) * 8;
  const int gcol = (SPLIT3 ? ((n0 + wn * 64) & 511) : (n0 + wn * 64)) + colloc;
  const int lrowr = lane >> 3;
  float bvj[4];
#pragma unroll
  for (int j = 0; j < 4; j++) bvj[j] = bias[n0 + wn * 64 + j * 16 + r16];

#pragma unroll
  for (int pass = 0; pass < 4; ++pass) {
#pragma unroll
    for (int ii = 0; ii < 2; ++ii) {
#pragma unroll
      for (int j = 0; j < 4; ++j) {
#pragma unroll
        for (int q = 0; q < 4; ++q)
          fl[(ii * 16 + kq * 4 + q) * 68 + j * 16 + r16] =
              acc[pass * 2 + ii][j][q] + bvj[j];
      }
    }
#pragma unroll
    for (int inst = 0; inst < 4; ++inst) {
      int lr = inst * 8 + lrowr;
      float4 f0 = *(float4*)&fl[lr * 68 + colloc];
      float4 f1 = *(float4*)&fl[lr * 68 + colloc + 4];
      uint4 wv = {pack2(f0.x, f0.y), pack2(f0.z, f0.w),
                  pack2(f1.x, f1.y), pack2(f1.z, f1.w)};
      size_t grow = (size_t)(m0 + wm * 128 + pass * 32 + lr);
      *(uint4*)&ob[grow * OC + gcol] = wv;
    }
  }
}

// ---------------- legacy 128^2 GEMM (fp32 A staging) — small-ws fallback ----------------
template <bool A_BF16>
__global__ __launch_bounds__(256) void gemm128(
    const void* __restrict__ Aany, const u16* __restrict__ BtBase,
    const float* __restrict__ bias0, const float* __restrict__ bias1,
    const float* __restrict__ bias2,
    void* __restrict__ out0, void* __restrict__ out1, void* __restrict__ out2,
    int K) {
  __shared__ u16 As[128 * 32];
  __shared__ u16 Bs[128 * 32];
  const int N = gridDim.x * 128;
  const int z = blockIdx.z;
  const u16* Bt = BtBase + (size_t)z * N * K;
  const float* bias = (z == 0) ? bias0 : (z == 1) ? bias1 : bias2;
  void* Out = (z == 0) ? out0 : (z == 1) ? out1 : out2;
  const int tid = threadIdx.x;
  const int m0 = blockIdx.y * 128;
  const int n0 = blockIdx.x * 128;
  const int lane = tid & 63;
  const int wid = tid >> 6;
  const int wm = wid >> 1, wn = wid & 1;
  const int r16 = lane & 15, kq = lane >> 4;
  const int r = tid >> 1;
  const int half = tid & 1;
  f32x4 acc[4][4] = {};
  for (int k0 = 0; k0 < K; k0 += 32) {
    __syncthreads();
    if (A_BF16) {
      const u16* Ab = (const u16*)Aany;
      const int4* src = (const int4*)(Ab + (size_t)(m0 + r) * K + k0 + half * 16);
      int4 v0 = src[0];
      int4 v1 = src[1];
      *(int4*)&As[r * 32 + half * 16] = v0;
      *(int4*)&As[r * 32 + half * 16 + 8] = v1;
    } else {
      const float* Af = (const float*)Aany;
      const float4* src = (const float4*)(Af + (size_t)(m0 + r) * K + k0 + half * 16);
      float4 f0 = src[0], f1 = src[1], f2 = src[2], f3 = src[3];
      uint4 w0 = {pack2(f0.x, f0.y), pack2(f0.z, f0.w), pack2(f1.x, f1.y), pack2(f1.z, f1.w)};
      uint4 w1 = {pack2(f2.x, f2.y), pack2(f2.z, f2.w), pack2(f3.x, f3.y), pack2(f3.z, f3.w)};
      *(uint4*)&As[r * 32 + half * 16] = w0;
      *(uint4*)&As[r * 32 + half * 16 + 8] = w1;
    }
    {
      const int4* src = (const int4*)(Bt + (size_t)(n0 + r) * K + k0 + half * 16);
      int4 v0 = src[0];
      int4 v1 = src[1];
      *(int4*)&Bs[r * 32 + half * 16] = v0;
      *(int4*)&Bs[r * 32 + half * 16 + 8] = v1;
    }
    __syncthreads();
    bf16x8 a[4], b[4];
#pragma unroll
    for (int i = 0; i < 4; i++)
      a[i] = *(const bf16x8*)&As[(wm * 64 + i * 16 + r16) * 32 + kq * 8];
#pragma unroll
    for (int j = 0; j < 4; j++)
      b[j] = *(const bf16x8*)&Bs[(wn * 64 + j * 16 + r16) * 32 + kq * 8];
#pragma unroll
    for (int i = 0; i < 4; i++)
#pragma unroll
      for (int j = 0; j < 4; j++)
        acc[i][j] = __builtin_amdgcn_mfma_f32_16x16x32_bf16(a[i], b[j], acc[i][j], 0, 0, 0);
  }
#pragma unroll
  for (int j = 0; j < 4; j++) {
    int col = n0 + wn * 64 + j * 16 + r16;
    float bv = bias[col];
#pragma unroll
    for (int i = 0; i < 4; i++) {
#pragma unroll
      for (int q = 0; q < 4; q++) {
        int row = m0 + wm * 64 + i * 16 + kq * 4 + q;
        float v = acc[i][j][q] + bv;
        ((u16*)Out)[(size_t)row * N + col] = f2b(v);
      }
    }
  }
}

// ---------------- attn: softmax over heads of (q.k)/8 ----------------
__global__ __launch_bounds__(256) void attn_kernel(
    const u16* __restrict__ qb, const u16* __restrict__ kb,
    float* __restrict__ attn) {
  int lane = threadIdx.x & 63;
  int wid = threadIdx.x >> 6;
  size_t t = (size_t)blockIdx.x * 4 + wid;
  int4 qv = *(const int4*)(qb + t * INNER + lane * 8);
  int4 kv = *(const int4*)(kb + t * INNER + lane * 8);
  const u16* qu = (const u16*)&qv;
  const u16* ku = (const u16*)&kv;
  float s = 0.f;
#pragma unroll
  for (int j = 0; j < 8; j++) s += b2f(qu[j]) * b2f(ku[j]);
  s += __shfl_xor(s, 1);
  s += __shfl_xor(s, 2);
  s += __shfl_xor(s, 4);
  s *= 0.125f;
  float mx = s;
  mx = fmaxf(mx, __shfl_xor(mx, 8));
  mx = fmaxf(mx, __shfl_xor(mx, 16));
  mx = fmaxf(mx, __shfl_xor(mx, 32));
  float e = __expf(s - mx);
  float sm = e;
  sm += __shfl_xor(sm, 8);
  sm += __shfl_xor(sm, 16);
  sm += __shfl_xor(sm, 32);
  float a = e / sm;
  if ((lane & 7) == 0) attn[t * HEADS + (lane >> 3)] = a;
}

// ---------------- scan ----------------
__global__ __launch_bounds__(512) void scan_phase1(
    const u16* __restrict__ vb, const float* __restrict__ attn,
    const float* __restrict__ alpha, float* __restrict__ ends) {
  int hd = threadIdx.x;
  int h = hd >> 6;
  int c = blockIdx.x, b = blockIdx.y;
  float decay = 1.f / (1.f + __expf(-alpha[hd]));
  float om = 1.f - decay;
  size_t base = (size_t)b * SEQ + (size_t)c * CHLEN;
  float st = 0.f;
#pragma unroll 8
  for (int i = 0; i < CHLEN; i++) {
    size_t t = base + i;
    float a = attn[t * HEADS + h];
    float v = b2f(vb[t * INNER + hd]);
    st = decay * st + om * a * v;
  }
  ends[((size_t)b * NCHUNK + c) * INNER + hd] = st;
}

__global__ __launch_bounds__(512) void scan_phase2(
    const float* __restrict__ ends, const float* __restrict__ alpha,
    float* __restrict__ carries) {
  int hd = threadIdx.x;
  int b = blockIdx.x;
  float decay = 1.f / (1.f + __expf(-alpha[hd]));
  float dL = __powf(decay, (float)CHLEN);
  float carry = 0.f;
#pragma unroll 8
  for (int c = 0; c < NCHUNK; c++) {
    size_t idx = ((size_t)b * NCHUNK + c) * INNER + hd;
    carries[idx] = carry;
    carry = dL * carry + ends[idx];
  }
}

__global__ __launch_bounds__(512) void scan_phase3(
    const u16* __restrict__ qb, const u16* __restrict__ vb,
    const float* __restrict__ attn, const float* __restrict__ alpha,
    const float* __restrict__ augp, const float* __restrict__ carries,
    u16* __restrict__ outpre) {
  int hd = threadIdx.x;
  int h = hd >> 6;
  int c = blockIdx.x, b = blockIdx.y;
  float decay = 1.f / (1.f + __expf(-alpha[hd]));
  float om = 1.f - decay;
  float ap = augp[hd];
  float st = carries[((size_t)b * NCHUNK + c) * INNER + hd];
  size_t base = (size_t)b * SEQ + (size_t)c * CHLEN;
#pragma unroll 4
  for (int i = 0; i < CHLEN; i++) {
    size_t t = base + i;
    float a = attn[t * HEADS + h];
    float v = b2f(vb[t * INNER + hd]);
    st = decay * st + om * a * v;
    float q = b2f(qb[t * INNER + hd]);
    float aug = 1.f / (1.f + __expf(-q * ap));
    outpre[t * INNER + hd] = f2b(q * st + aug);
  }
}

// ---------------- LayerNorm: bf16 in -> fp32 out ----------------
__global__ __launch_bounds__(256) void ln_kernel(
    const u16* __restrict__ outln, float* __restrict__ out,
    const float* __restrict__ lns, const float* __restrict__ lnb) {
  size_t row = blockIdx.x;
  int tid = threadIdx.x;
  uint2 rv = *(const uint2*)(outln + row * HIDDEN + tid * 4);
  const u16* p = (const u16*)&rv;
  float v0 = b2f(p[0]), v1 = b2f(p[1]), v2 = b2f(p[2]), v3 = b2f(p[3]);
  float s = v0 + v1 + v2 + v3;
  float ss = v0 * v0 + v1 * v1 + v2 * v2 + v3 * v3;
#pragma unroll
  for (int m = 1; m < 64; m <<= 1) {
    s += __shfl_xor(s, m);
    ss += __shfl_xor(ss, m);
  }
  __shared__ float sb[4], ssb[4];
  int lane = tid & 63, wid = tid >> 6;
  if (lane == 0) {
    sb[wid] = s;
    ssb[wid] = ss;
  }
  __syncthreads();
  s = sb[0] + sb[1] + sb[2] + sb[3];
  ss = ssb[0] + ssb[1] + ssb[2] + ssb[3];
  float mean = s * (1.f / HIDDEN);
  float var = ss * (1.f / HIDDEN) - mean * mean;
  float rstd = rsqrtf(var + 1e-6f);
  float4 sc = *(const float4*)(lns + tid * 4);
  float4 bi = *(const float4*)(lnb + tid * 4);
  float4 o;
  o.x = (v0 - mean) * rstd * sc.x + bi.x;
  o.y = (v1 - mean) * rstd * sc.y + bi.y;
  o.z = (v2 - mean) * rstd * sc.z + bi.z;
  o.w = (v3 - mean) * rstd * sc.w + bi.w;
  *(float4*)(out + row * HIDDEN + tid * 4) = o;
}

extern "C" void kernel_launch(void* const* d_in, const int* in_sizes, int n_in,
                              void* d_out, int out_size, void* d_ws, size_t ws_size,
                              hipStream_t stream) {
  const float* x = (const float*)d_in[0];
  const float* Wq = (const float*)d_in[1];
  const float* bq = (const float*)d_in[2];
  const float* Wk = (const float*)d_in[3];
  const float* bk = (const float*)d_in[4];
  const float* Wv = (const float*)d_in[5];
  const float* bv = (const float*)d_in[6];
  const float* Wo = (const float*)d_in[7];
  const float* bo = (const float*)d_in[8];
  const float* alpha = (const float*)d_in[9];
  const float* augp = (const float*)d_in[10];
  const float* lns = (const float*)d_in[11];
  const float* lnb = (const float*)d_in[12];

  char* ws = (char*)d_ws;
  const bool fast = ws_size >= 175118336ull;

  if (fast) {
    u16* xb = (u16*)(ws + 0);                 // 67.1 MB (reused as outln)
    u16* qb = (u16*)(ws + 67108864);          // 33.5 MB
    u16* kb = (u16*)(ws + 100663296);         // 33.5 MB (reused as outpre)
    u16* vb = (u16*)(ws + 134217728);         // 33.5 MB
    u16* Wt = (u16*)(ws + 167772160);         // 3 MB, [1536][1024]
    u16* Wot = (u16*)(ws + 170917888);        // 1 MB, [1024][512]
    float* bcat = (float*)(ws + 171966464);   // 6 KB
    float* attn = (float*)(ws + 171972608);   // 1 MB
    float* ends = (float*)(ws + 173021184);   // 1 MB
    float* car = (float*)(ws + 174069760);    // 1 MB
    u16* outpre = kb;
    u16* outln = xb;  // xb dead after QKV gemm

    prep_x<<<ROWS * HIDDEN / 8 / 256, 256, 0, stream>>>(x, xb);
    prep_w<<<8192, 256, 0, stream>>>(Wq, Wk, Wv, Wo, bq, bk, bv, Wt, Wot, bcat);

    // QKV: M=32768, N=1536 -> 128*6 = 768 blocks of 512 thr
    gemm_rp<HIDDEN, true><<<768, 512, 0, stream>>>(
        xb, Wt, bcat, qb, kb, vb, 6);

    attn_kernel<<<ROWS / 4, 256, 0, stream>>>(qb, kb, attn);
    scan_phase1<<<dim3(NCHUNK, BATCH), 512, 0, stream>>>(vb, attn, alpha, ends);
    scan_phase2<<<BATCH, 512, 0, stream>>>(ends, alpha, car);
    scan_phase3<<<dim3(NCHUNK, BATCH), 512, 0, stream>>>(qb, vb, attn, alpha, augp, car, outpre);

    // out: M=32768, N=1024 -> 128*4 = 512 blocks, bf16 -> outln
    gemm_rp<INNER, false><<<512, 512, 0, stream>>>(
        outpre, Wot, bo, outln, outln, outln, 4);

    ln_kernel<<<ROWS, 256, 0, stream>>>(outln, (float*)d_out, lns, lnb);
  } else {
    // fallback layout (108 MB): qb@0, vb@33.5, kb@67 (outpre); outln spans qb+vb
    u16* qb = (u16*)(ws + 0);
    u16* vb = (u16*)(ws + 33554432);
    u16* kb = (u16*)(ws + 67108864);
    u16* Wt = (u16*)(ws + 100663296);
    u16* Wot = (u16*)(ws + 103809024);
    float* bcat = (float*)(ws + 104845312);
    float* attn = (float*)(ws + 104857600);
    float* ends = (float*)(ws + 105906176);
    float* car = (float*)(ws + 106954752);
    u16* outpre = kb;
    u16* outln = (u16*)(ws + 0);  // qb+vb dead after scan3

    prep_w<<<8192, 256, 0, stream>>>(Wq, Wk, Wv, Wo, bq, bk, bv, Wt, Wot, bcat);
    gemm128<false><<<dim3(4, 256, 3), 256, 0, stream>>>(
        x, Wt, bq, bk, bv, qb, kb, vb, HIDDEN);
    attn_kernel<<<ROWS / 4, 256, 0, stream>>>(qb, kb, attn);
    scan_phase1<<<dim3(NCHUNK, BATCH), 512, 0, stream>>>(vb, attn, alpha, ends);
    scan_phase2<<<BATCH, 512, 0, stream>>>(ends, alpha, car);
    scan_phase3<<<dim3(NCHUNK, BATCH), 512, 0, stream>>>(qb, vb, attn, alpha, augp, car, outpre);
    gemm_rp<INNER, false><<<512, 512, 0, stream>>>(
        outpre, Wot, bo, outln, outln, outln, 4);
    ln_kernel<<<ROWS, 256, 0, stream>>>(outln, (float*)d_out, lns, lnb);
  }
}